// Round 1
// baseline (1287.255 us; speedup 1.0000x reference)
//
#include <hip/hip_runtime.h>
#include <hip/hip_bf16.h>
#include <float.h>

// Problem constants
constexpr int Bc = 4;
constexpr int Lc = 2048;
constexpr int Dc = 512;
constexpr int Hc = 8;
constexpr int Ec = 64;
constexpr int Sc = 40;   // sample_k
constexpr int Uc = 40;   // u_q (top-k queries)
constexpr int LEc = Lc * Ec;      // 131072
constexpr int BHc = Bc * Hc;      // 32
constexpr int Mrows = Bc * Lc;    // 8192 rows per GEMM

// ---------------------------------------------------------------------------
// Kernel 1: three projection GEMMs, f32.  (8192 x 512) @ (512 x 512)
// 128x128 tile, 256 threads, 8x8 micro-tile, BK=16.
// blockIdx.z selects {q@Wq, k@Wk, v@Wv}.
// ---------------------------------------------------------------------------
__global__ __launch_bounds__(256) void gemm3_f32(
    const float* __restrict__ q, const float* __restrict__ k, const float* __restrict__ v,
    const float* __restrict__ Wq, const float* __restrict__ Wk, const float* __restrict__ Wv,
    float* __restrict__ qp, float* __restrict__ kp, float* __restrict__ vp)
{
    const float* A;
    const float* W;
    float* O;
    int z = blockIdx.z;
    if (z == 0)      { A = q; W = Wq; O = qp; }
    else if (z == 1) { A = k; W = Wk; O = kp; }
    else             { A = v; W = Wv; O = vp; }

    // +4 pad keeps 16B alignment (132*4B = 528 = 33*16) and spreads banks.
    __shared__ float As[16][132];   // As[k][m]
    __shared__ float Bs[16][132];   // Bs[k][n]

    const int t  = threadIdx.x;
    const int tx = t & 15;          // n-dir micro position
    const int ty = t >> 4;          // m-dir micro position
    const int row0 = blockIdx.x * 128;
    const int col0 = blockIdx.y * 128;

    float acc[8][8];
    #pragma unroll
    for (int i = 0; i < 8; ++i)
        #pragma unroll
        for (int j = 0; j < 8; ++j) acc[i][j] = 0.f;

    const int ar  = t >> 2;   // 0..63 (A tile row)
    const int ac4 = t & 3;    // 0..3  (A tile col group of 4)
    const int bk  = t >> 5;   // 0..7  (B tile row)
    const int bc  = t & 31;   // 0..31 (B tile col group of 4)

    for (int k0 = 0; k0 < Dc; k0 += 16) {
        float4 a0 = *(const float4*)(A + (size_t)(row0 + ar)      * Dc + k0 + ac4 * 4);
        float4 a1 = *(const float4*)(A + (size_t)(row0 + ar + 64) * Dc + k0 + ac4 * 4);
        float4 b0 = *(const float4*)(W + (size_t)(k0 + bk)     * Dc + col0 + bc * 4);
        float4 b1 = *(const float4*)(W + (size_t)(k0 + bk + 8) * Dc + col0 + bc * 4);
        __syncthreads();  // previous iteration's reads done before overwrite
        As[ac4 * 4 + 0][ar] = a0.x;
        As[ac4 * 4 + 1][ar] = a0.y;
        As[ac4 * 4 + 2][ar] = a0.z;
        As[ac4 * 4 + 3][ar] = a0.w;
        As[ac4 * 4 + 0][ar + 64] = a1.x;
        As[ac4 * 4 + 1][ar + 64] = a1.y;
        As[ac4 * 4 + 2][ar + 64] = a1.z;
        As[ac4 * 4 + 3][ar + 64] = a1.w;
        *(float4*)&Bs[bk][bc * 4]     = b0;
        *(float4*)&Bs[bk + 8][bc * 4] = b1;
        __syncthreads();

        #pragma unroll
        for (int kk = 0; kk < 16; ++kk) {
            float4 av0 = *(const float4*)&As[kk][ty * 8];
            float4 av1 = *(const float4*)&As[kk][ty * 8 + 4];
            float4 bv0 = *(const float4*)&Bs[kk][tx * 8];
            float4 bv1 = *(const float4*)&Bs[kk][tx * 8 + 4];
            float a[8] = {av0.x, av0.y, av0.z, av0.w, av1.x, av1.y, av1.z, av1.w};
            float b[8] = {bv0.x, bv0.y, bv0.z, bv0.w, bv1.x, bv1.y, bv1.z, bv1.w};
            #pragma unroll
            for (int i = 0; i < 8; ++i)
                #pragma unroll
                for (int j = 0; j < 8; ++j)
                    acc[i][j] = fmaf(a[i], b[j], acc[i][j]);
        }
    }

    #pragma unroll
    for (int i = 0; i < 8; ++i) {
        int row = row0 + ty * 8 + i;
        float4 o0 = {acc[i][0], acc[i][1], acc[i][2], acc[i][3]};
        float4 o1 = {acc[i][4], acc[i][5], acc[i][6], acc[i][7]};
        *(float4*)(O + (size_t)row * Dc + col0 + tx * 8)     = o0;
        *(float4*)(O + (size_t)row * Dc + col0 + tx * 8 + 4) = o1;
    }
}

// ---------------------------------------------------------------------------
// Kernel 2: sampled scores -> m[bh, l] = max_s(dot) - sum_s(dot)/L
// One wave per (bh, l); lane = e.
// ---------------------------------------------------------------------------
__global__ __launch_bounds__(256) void compute_m(
    const float* __restrict__ qp, const float* __restrict__ kp,
    const int* __restrict__ ksi, float* __restrict__ m_out)
{
    int wid  = blockIdx.x * 4 + (threadIdx.x >> 6);
    int lane = threadIdx.x & 63;
    int l  = wid & (Lc - 1);
    int bh = wid >> 11;          // Lc = 2048 = 2^11
    const float* qrow  = qp + (size_t)bh * LEc + l * Ec;
    const float* kbase = kp + (size_t)bh * LEc;
    float qv = qrow[lane];
    float mx = -FLT_MAX, sm = 0.f;
    for (int s = 0; s < Sc; ++s) {
        int j = ksi[l * Sc + s];
        float p = qv * kbase[j * Ec + lane];
        #pragma unroll
        for (int o = 1; o < 64; o <<= 1) p += __shfl_xor(p, o);
        mx = fmaxf(mx, p);
        sm += p;
    }
    if (lane == 0) m_out[bh * Lc + l] = mx - sm * (1.0f / Lc);
}

// ---------------------------------------------------------------------------
// Kernel 3: top-40 indices per (bh). Iterative extract-max, tie -> lower idx
// (matches jax.lax.top_k tie rule).
// ---------------------------------------------------------------------------
__global__ __launch_bounds__(256) void topk40(
    const float* __restrict__ m_in, int* __restrict__ mtop)
{
    __shared__ float vals[Lc];
    __shared__ float bv[256];
    __shared__ int   bi[256];
    int bh = blockIdx.x, t = threadIdx.x;
    for (int i = t; i < Lc; i += 256) vals[i] = m_in[bh * Lc + i];
    __syncthreads();
    for (int it = 0; it < Uc; ++it) {
        float lv = -FLT_MAX; int li = 0x7fffffff;
        for (int i = t; i < Lc; i += 256) {
            float v = vals[i];
            if (v > lv) { lv = v; li = i; }   // increasing i: strict > keeps lowest idx
        }
        bv[t] = lv; bi[t] = li;
        __syncthreads();
        if (t == 0) {
            float Bv = -FLT_MAX; int Bi = 0x7fffffff;
            for (int i = 0; i < 256; ++i) {
                float v = bv[i];
                if (v > Bv || (v == Bv && bi[i] < Bi)) { Bv = v; Bi = bi[i]; }
            }
            mtop[bh * Uc + it] = Bi;
            vals[Bi] = -FLT_MAX;
        }
        __syncthreads();
    }
}

// ---------------------------------------------------------------------------
// Kernels 4-6: chunked inclusive cumsum of vp along l, per (bh, e) column.
// 64 chunks x 32 rows.
// ---------------------------------------------------------------------------
constexpr int CH = 64;  // chunks
constexpr int CR = 32;  // rows per chunk

__global__ __launch_bounds__(64) void cumsum_p1(
    const float* __restrict__ vp, float* __restrict__ psum)
{
    int bid = blockIdx.x;           // bh*64 + ch
    int e = threadIdx.x;
    int bh = bid >> 6, ch = bid & 63;
    const float* base = vp + (size_t)bh * LEc + (ch * CR) * Ec + e;
    float s = 0.f;
    #pragma unroll 8
    for (int r = 0; r < CR; ++r) s += base[r * Ec];
    psum[(size_t)bid * Ec + e] = s;
}

__global__ __launch_bounds__(64) void cumsum_p2(float* __restrict__ psum)
{
    int bh = blockIdx.x;
    int e = threadIdx.x;
    float off = 0.f;
    for (int c = 0; c < CH; ++c) {
        size_t idx = (size_t)(bh * CH + c) * Ec + e;
        float tv = psum[idx];
        psum[idx] = off;   // exclusive prefix
        off += tv;
    }
}

__global__ __launch_bounds__(64) void cumsum_p3(
    const float* __restrict__ vp, const float* __restrict__ psum,
    float* __restrict__ out)
{
    int bid = blockIdx.x;
    int e = threadIdx.x;
    int bh = bid >> 6, ch = bid & 63;
    const float* base = vp  + (size_t)bh * LEc + (ch * CR) * Ec + e;
    float*       ob   = out + (size_t)bh * LEc + (ch * CR) * Ec + e;
    float run = psum[(size_t)bid * Ec + e];
    #pragma unroll 8
    for (int r = 0; r < CR; ++r) { run += base[r * Ec]; ob[r * Ec] = run; }
}

// ---------------------------------------------------------------------------
// Kernel 7: for each selected query u: scores vs all l <= lsel, softmax,
// ctx = attn @ v_, overwrite out row lsel.  One block per (bh, u).
// ---------------------------------------------------------------------------
__global__ __launch_bounds__(256) void attn_update(
    const float* __restrict__ qp, const float* __restrict__ kp,
    const float* __restrict__ vp, const int* __restrict__ mtop,
    float* __restrict__ out)
{
    __shared__ float sc[Lc];
    __shared__ float qs[Ec];
    __shared__ float red[256];
    int bh = blockIdx.x / Uc, u = blockIdx.x % Uc;
    int t = threadIdx.x;
    int lsel = mtop[bh * Uc + u];
    const float* kb = kp + (size_t)bh * LEc;
    const float* vb = vp + (size_t)bh * LEc;
    if (t < Ec) qs[t] = qp[(size_t)bh * LEc + lsel * Ec + t];
    __syncthreads();

    // scores (scaled), tracking local max
    float lmax = -FLT_MAX;
    for (int l = t; l <= lsel; l += 256) {
        const float4* kr = (const float4*)(kb + (size_t)l * Ec);
        float dot = 0.f;
        #pragma unroll
        for (int e4 = 0; e4 < 16; ++e4) {
            float4 kv = kr[e4];
            float4 qv = *(const float4*)&qs[e4 * 4];
            dot += kv.x * qv.x + kv.y * qv.y + kv.z * qv.z + kv.w * qv.w;
        }
        dot *= 0.125f;   // 1/sqrt(64)
        sc[l] = dot;
        lmax = fmaxf(lmax, dot);
    }
    red[t] = lmax;
    __syncthreads();
    for (int s = 128; s > 0; s >>= 1) {
        if (t < s) red[t] = fmaxf(red[t], red[t + s]);
        __syncthreads();
    }
    float mx = red[0];
    __syncthreads();

    float lsum = 0.f;
    for (int l = t; l <= lsel; l += 256) {
        float ex = __expf(sc[l] - mx);
        sc[l] = ex;
        lsum += ex;
    }
    red[t] = lsum;
    __syncthreads();
    for (int s = 128; s > 0; s >>= 1) {
        if (t < s) red[t] += red[t + s];
        __syncthreads();
    }
    float inv = 1.0f / red[0];
    __syncthreads();

    // ctx_upd[e] = sum_l p[l] * v[l][e]; 4 l-partitions x 64 e-lanes
    int e = t & 63, part = t >> 6;
    float acc = 0.f;
    for (int l = part; l <= lsel; l += 4)
        acc = fmaf(sc[l], vb[(size_t)l * Ec + e], acc);
    red[part * Ec + e] = acc;
    __syncthreads();
    if (t < Ec) {
        float c = (red[t] + red[Ec + t] + red[2 * Ec + t] + red[3 * Ec + t]) * inv;
        out[(size_t)bh * LEc + lsel * Ec + t] = c;
    }
}

// ---------------------------------------------------------------------------
extern "C" void kernel_launch(void* const* d_in, const int* in_sizes, int n_in,
                              void* d_out, int out_size, void* d_ws, size_t ws_size,
                              hipStream_t stream)
{
    const float* q   = (const float*)d_in[0];
    const float* k   = (const float*)d_in[1];
    const float* v   = (const float*)d_in[2];
    const float* Wq  = (const float*)d_in[3];
    const float* Wk  = (const float*)d_in[4];
    const float* Wv  = (const float*)d_in[5];
    const int*   ksi = (const int*)d_in[6];
    float* out = (float*)d_out;

    // workspace layout (floats)
    float* wsf  = (float*)d_ws;
    float* qp   = wsf;                           // 4,194,304
    float* kp   = qp + (size_t)Mrows * Dc;       // 4,194,304
    float* vp   = kp + (size_t)Mrows * Dc;       // 4,194,304
    float* psum = vp + (size_t)Mrows * Dc;       // 32*64*64 = 131,072
    float* m_ws = psum + (size_t)BHc * CH * Ec;  // 65,536
    int*   mtop = (int*)(m_ws + (size_t)BHc * Lc); // 1,280 ints

    dim3 g1(Mrows / 128, Dc / 128, 3);
    gemm3_f32<<<g1, 256, 0, stream>>>(q, k, v, Wq, Wk, Wv, qp, kp, vp);

    compute_m<<<(BHc * Lc) / 4, 256, 0, stream>>>(qp, kp, ksi, m_ws);

    topk40<<<BHc, 256, 0, stream>>>(m_ws, mtop);

    cumsum_p1<<<BHc * CH, 64, 0, stream>>>(vp, psum);
    cumsum_p2<<<BHc, 64, 0, stream>>>(psum);
    cumsum_p3<<<BHc * CH, 64, 0, stream>>>(vp, psum, out);

    attn_update<<<BHc * Uc, 256, 0, stream>>>(qp, kp, vp, mtop, out);
}

// Round 2
// 601.842 us; speedup vs baseline: 2.1389x; 2.1389x over previous
//
#include <hip/hip_runtime.h>
#include <hip/hip_bf16.h>
#include <float.h>

// Problem constants
constexpr int Bc = 4;
constexpr int Lc = 2048;
constexpr int Dc = 512;
constexpr int Hc = 8;
constexpr int Ec = 64;
constexpr int Sc = 40;   // sample_k
constexpr int Uc = 40;   // u_q (top-k queries)
constexpr int LEc = Lc * Ec;      // 131072
constexpr int BHc = Bc * Hc;      // 32
constexpr int Mrows = Bc * Lc;    // 8192 rows per GEMM

// ---------------------------------------------------------------------------
// Kernel 1: three projection GEMMs, f32.  (8192 x 512) @ (512 x 512)
// 128x128 tile, 256 threads, 8x8 micro-tile, BK=16.
// blockIdx.z selects {q@Wq, k@Wk, v@Wv}.
// ---------------------------------------------------------------------------
__global__ __launch_bounds__(256) void gemm3_f32(
    const float* __restrict__ q, const float* __restrict__ k, const float* __restrict__ v,
    const float* __restrict__ Wq, const float* __restrict__ Wk, const float* __restrict__ Wv,
    float* __restrict__ qp, float* __restrict__ kp, float* __restrict__ vp)
{
    const float* A;
    const float* W;
    float* O;
    int z = blockIdx.z;
    if (z == 0)      { A = q; W = Wq; O = qp; }
    else if (z == 1) { A = k; W = Wk; O = kp; }
    else             { A = v; W = Wv; O = vp; }

    // +4 pad keeps 16B alignment (132*4B = 528 = 33*16) and spreads banks.
    __shared__ float As[16][132];   // As[k][m]
    __shared__ float Bs[16][132];   // Bs[k][n]

    const int t  = threadIdx.x;
    const int tx = t & 15;          // n-dir micro position
    const int ty = t >> 4;          // m-dir micro position
    const int row0 = blockIdx.x * 128;
    const int col0 = blockIdx.y * 128;

    float acc[8][8];
    #pragma unroll
    for (int i = 0; i < 8; ++i)
        #pragma unroll
        for (int j = 0; j < 8; ++j) acc[i][j] = 0.f;

    const int ar  = t >> 2;   // 0..63 (A tile row)
    const int ac4 = t & 3;    // 0..3  (A tile col group of 4)
    const int bk  = t >> 5;   // 0..7  (B tile row)
    const int bc  = t & 31;   // 0..31 (B tile col group of 4)

    for (int k0 = 0; k0 < Dc; k0 += 16) {
        float4 a0 = *(const float4*)(A + (size_t)(row0 + ar)      * Dc + k0 + ac4 * 4);
        float4 a1 = *(const float4*)(A + (size_t)(row0 + ar + 64) * Dc + k0 + ac4 * 4);
        float4 b0 = *(const float4*)(W + (size_t)(k0 + bk)     * Dc + col0 + bc * 4);
        float4 b1 = *(const float4*)(W + (size_t)(k0 + bk + 8) * Dc + col0 + bc * 4);
        __syncthreads();  // previous iteration's reads done before overwrite
        As[ac4 * 4 + 0][ar] = a0.x;
        As[ac4 * 4 + 1][ar] = a0.y;
        As[ac4 * 4 + 2][ar] = a0.z;
        As[ac4 * 4 + 3][ar] = a0.w;
        As[ac4 * 4 + 0][ar + 64] = a1.x;
        As[ac4 * 4 + 1][ar + 64] = a1.y;
        As[ac4 * 4 + 2][ar + 64] = a1.z;
        As[ac4 * 4 + 3][ar + 64] = a1.w;
        *(float4*)&Bs[bk][bc * 4]     = b0;
        *(float4*)&Bs[bk + 8][bc * 4] = b1;
        __syncthreads();

        #pragma unroll
        for (int kk = 0; kk < 16; ++kk) {
            float4 av0 = *(const float4*)&As[kk][ty * 8];
            float4 av1 = *(const float4*)&As[kk][ty * 8 + 4];
            float4 bv0 = *(const float4*)&Bs[kk][tx * 8];
            float4 bv1 = *(const float4*)&Bs[kk][tx * 8 + 4];
            float a[8] = {av0.x, av0.y, av0.z, av0.w, av1.x, av1.y, av1.z, av1.w};
            float b[8] = {bv0.x, bv0.y, bv0.z, bv0.w, bv1.x, bv1.y, bv1.z, bv1.w};
            #pragma unroll
            for (int i = 0; i < 8; ++i)
                #pragma unroll
                for (int j = 0; j < 8; ++j)
                    acc[i][j] = fmaf(a[i], b[j], acc[i][j]);
        }
    }

    #pragma unroll
    for (int i = 0; i < 8; ++i) {
        int row = row0 + ty * 8 + i;
        float4 o0 = {acc[i][0], acc[i][1], acc[i][2], acc[i][3]};
        float4 o1 = {acc[i][4], acc[i][5], acc[i][6], acc[i][7]};
        *(float4*)(O + (size_t)row * Dc + col0 + tx * 8)     = o0;
        *(float4*)(O + (size_t)row * Dc + col0 + tx * 8 + 4) = o1;
    }
}

// ---------------------------------------------------------------------------
// Kernel 2: sampled scores -> m[bh, l] = max_s(dot) - sum_s(dot)/L
// One wave per (bh, l); lane = e.
// ---------------------------------------------------------------------------
__global__ __launch_bounds__(256) void compute_m(
    const float* __restrict__ qp, const float* __restrict__ kp,
    const int* __restrict__ ksi, float* __restrict__ m_out)
{
    int wid  = blockIdx.x * 4 + (threadIdx.x >> 6);
    int lane = threadIdx.x & 63;
    int l  = wid & (Lc - 1);
    int bh = wid >> 11;          // Lc = 2048 = 2^11
    const float* qrow  = qp + (size_t)bh * LEc + l * Ec;
    const float* kbase = kp + (size_t)bh * LEc;
    float qv = qrow[lane];
    float mx = -FLT_MAX, sm = 0.f;
    for (int s = 0; s < Sc; ++s) {
        int j = ksi[l * Sc + s];
        float p = qv * kbase[j * Ec + lane];
        #pragma unroll
        for (int o = 1; o < 64; o <<= 1) p += __shfl_xor(p, o);
        mx = fmaxf(mx, p);
        sm += p;
    }
    if (lane == 0) m_out[bh * Lc + l] = mx - sm * (1.0f / Lc);
}

// ---------------------------------------------------------------------------
// Kernel 3: top-40 indices per (bh). Iterative extract-max with wave-parallel
// (value,index) reduction. Tie -> lower idx (matches jax.lax.top_k).
// ---------------------------------------------------------------------------
__global__ __launch_bounds__(256) void topk40(
    const float* __restrict__ m_in, int* __restrict__ mtop)
{
    __shared__ float vals[Lc];
    __shared__ float wv[4];
    __shared__ int   wi[4];
    int bh = blockIdx.x, t = threadIdx.x;
    int lane = t & 63, w = t >> 6;
    for (int i = t; i < Lc; i += 256) vals[i] = m_in[bh * Lc + i];
    __syncthreads();
    for (int it = 0; it < Uc; ++it) {
        float lv = -FLT_MAX; int li = 0x7fffffff;
        #pragma unroll
        for (int rep = 0; rep < Lc / 256; ++rep) {
            int i = rep * 256 + t;
            float v = vals[i];
            if (v > lv) { lv = v; li = i; }   // visits increasing i per thread
        }
        // 64-lane butterfly reduce: max value, lower index on tie
        #pragma unroll
        for (int o = 1; o < 64; o <<= 1) {
            float ov = __shfl_xor(lv, o);
            int   oi = __shfl_xor(li, o);
            if (ov > lv || (ov == lv && oi < li)) { lv = ov; li = oi; }
        }
        if (lane == 0) { wv[w] = lv; wi[w] = li; }
        __syncthreads();
        if (t == 0) {
            float Bv = wv[0]; int Bi = wi[0];
            #pragma unroll
            for (int j = 1; j < 4; ++j) {
                if (wv[j] > Bv || (wv[j] == Bv && wi[j] < Bi)) { Bv = wv[j]; Bi = wi[j]; }
            }
            mtop[bh * Uc + it] = Bi;
            vals[Bi] = -FLT_MAX;
        }
        __syncthreads();
    }
}

// ---------------------------------------------------------------------------
// Kernels 4-6: chunked inclusive cumsum of vp along l, per (bh, e) column.
// 64 chunks x 32 rows.
// ---------------------------------------------------------------------------
constexpr int CH = 64;  // chunks
constexpr int CR = 32;  // rows per chunk

__global__ __launch_bounds__(64) void cumsum_p1(
    const float* __restrict__ vp, float* __restrict__ psum)
{
    int bid = blockIdx.x;           // bh*64 + ch
    int e = threadIdx.x;
    int bh = bid >> 6, ch = bid & 63;
    const float* base = vp + (size_t)bh * LEc + (ch * CR) * Ec + e;
    float s = 0.f;
    #pragma unroll 8
    for (int r = 0; r < CR; ++r) s += base[r * Ec];
    psum[(size_t)bid * Ec + e] = s;
}

__global__ __launch_bounds__(64) void cumsum_p2(float* __restrict__ psum)
{
    int bh = blockIdx.x;
    int e = threadIdx.x;
    float off = 0.f;
    for (int c = 0; c < CH; ++c) {
        size_t idx = (size_t)(bh * CH + c) * Ec + e;
        float tv = psum[idx];
        psum[idx] = off;   // exclusive prefix
        off += tv;
    }
}

__global__ __launch_bounds__(64) void cumsum_p3(
    const float* __restrict__ vp, const float* __restrict__ psum,
    float* __restrict__ out)
{
    int bid = blockIdx.x;
    int e = threadIdx.x;
    int bh = bid >> 6, ch = bid & 63;
    const float* base = vp  + (size_t)bh * LEc + (ch * CR) * Ec + e;
    float*       ob   = out + (size_t)bh * LEc + (ch * CR) * Ec + e;
    float run = psum[(size_t)bid * Ec + e];
    #pragma unroll 8
    for (int r = 0; r < CR; ++r) { run += base[r * Ec]; ob[r * Ec] = run; }
}

// ---------------------------------------------------------------------------
// Kernel 7: for each selected query u: scores vs all l <= lsel, softmax,
// ctx = attn @ v_, overwrite out row lsel.  One block per (bh, u).
// ---------------------------------------------------------------------------
__global__ __launch_bounds__(256) void attn_update(
    const float* __restrict__ qp, const float* __restrict__ kp,
    const float* __restrict__ vp, const int* __restrict__ mtop,
    float* __restrict__ out)
{
    __shared__ float sc[Lc];
    __shared__ float qs[Ec];
    __shared__ float red[256];
    int bh = blockIdx.x / Uc, u = blockIdx.x % Uc;
    int t = threadIdx.x;
    int lsel = mtop[bh * Uc + u];
    const float* kb = kp + (size_t)bh * LEc;
    const float* vb = vp + (size_t)bh * LEc;
    if (t < Ec) qs[t] = qp[(size_t)bh * LEc + lsel * Ec + t];
    __syncthreads();

    // scores (scaled), tracking local max
    float lmax = -FLT_MAX;
    for (int l = t; l <= lsel; l += 256) {
        const float4* kr = (const float4*)(kb + (size_t)l * Ec);
        float dot = 0.f;
        #pragma unroll
        for (int e4 = 0; e4 < 16; ++e4) {
            float4 kv = kr[e4];
            float4 qv = *(const float4*)&qs[e4 * 4];
            dot += kv.x * qv.x + kv.y * qv.y + kv.z * qv.z + kv.w * qv.w;
        }
        dot *= 0.125f;   // 1/sqrt(64)
        sc[l] = dot;
        lmax = fmaxf(lmax, dot);
    }
    red[t] = lmax;
    __syncthreads();
    for (int s = 128; s > 0; s >>= 1) {
        if (t < s) red[t] = fmaxf(red[t], red[t + s]);
        __syncthreads();
    }
    float mx = red[0];
    __syncthreads();

    float lsum = 0.f;
    for (int l = t; l <= lsel; l += 256) {
        float ex = __expf(sc[l] - mx);
        sc[l] = ex;
        lsum += ex;
    }
    red[t] = lsum;
    __syncthreads();
    for (int s = 128; s > 0; s >>= 1) {
        if (t < s) red[t] += red[t + s];
        __syncthreads();
    }
    float inv = 1.0f / red[0];
    __syncthreads();

    // ctx_upd[e] = sum_l p[l] * v[l][e]; 4 l-partitions x 64 e-lanes
    int e = t & 63, part = t >> 6;
    float acc = 0.f;
    for (int l = part; l <= lsel; l += 4)
        acc = fmaf(sc[l], vb[(size_t)l * Ec + e], acc);
    red[part * Ec + e] = acc;
    __syncthreads();
    if (t < Ec) {
        float c = (red[t] + red[Ec + t] + red[2 * Ec + t] + red[3 * Ec + t]) * inv;
        out[(size_t)bh * LEc + lsel * Ec + t] = c;
    }
}

// ---------------------------------------------------------------------------
extern "C" void kernel_launch(void* const* d_in, const int* in_sizes, int n_in,
                              void* d_out, int out_size, void* d_ws, size_t ws_size,
                              hipStream_t stream)
{
    const float* q   = (const float*)d_in[0];
    const float* k   = (const float*)d_in[1];
    const float* v   = (const float*)d_in[2];
    const float* Wq  = (const float*)d_in[3];
    const float* Wk  = (const float*)d_in[4];
    const float* Wv  = (const float*)d_in[5];
    const int*   ksi = (const int*)d_in[6];
    float* out = (float*)d_out;

    // workspace layout (floats)
    float* wsf  = (float*)d_ws;
    float* qp   = wsf;                           // 4,194,304
    float* kp   = qp + (size_t)Mrows * Dc;       // 4,194,304
    float* vp   = kp + (size_t)Mrows * Dc;       // 4,194,304
    float* psum = vp + (size_t)Mrows * Dc;       // 32*64*64 = 131,072
    float* m_ws = psum + (size_t)BHc * CH * Ec;  // 65,536
    int*   mtop = (int*)(m_ws + (size_t)BHc * Lc); // 1,280 ints

    dim3 g1(Mrows / 128, Dc / 128, 3);
    gemm3_f32<<<g1, 256, 0, stream>>>(q, k, v, Wq, Wk, Wv, qp, kp, vp);

    compute_m<<<(BHc * Lc) / 4, 256, 0, stream>>>(qp, kp, ksi, m_ws);

    topk40<<<BHc, 256, 0, stream>>>(m_ws, mtop);

    cumsum_p1<<<BHc * CH, 64, 0, stream>>>(vp, psum);
    cumsum_p2<<<BHc, 64, 0, stream>>>(psum);
    cumsum_p3<<<BHc * CH, 64, 0, stream>>>(vp, psum, out);

    attn_update<<<BHc * Uc, 256, 0, stream>>>(qp, kp, vp, mtop, out);
}

// Round 3
// 460.330 us; speedup vs baseline: 2.7964x; 1.3074x over previous
//
#include <hip/hip_runtime.h>
#include <hip/hip_bf16.h>
#include <float.h>

// Problem constants
constexpr int Bc = 4;
constexpr int Lc = 2048;
constexpr int Dc = 512;
constexpr int Hc = 8;
constexpr int Ec = 64;
constexpr int Sc = 40;   // sample_k
constexpr int Uc = 40;   // u_q (top-k queries)
constexpr int LEc = Lc * Ec;      // 131072
constexpr int BHc = Bc * Hc;      // 32
constexpr int Mrows = Bc * Lc;    // 8192 rows per GEMM

// ---------------------------------------------------------------------------
// Kernel 1: three projection GEMMs, f32.  (8192 x 512) @ (512 x 512)
// 128x128 tile, 256 threads, 8x8 micro-tile, BK=16.
// blockIdx.z selects {q@Wq, k@Wk, v@Wv}.
// ---------------------------------------------------------------------------
__global__ __launch_bounds__(256) void gemm3_f32(
    const float* __restrict__ q, const float* __restrict__ k, const float* __restrict__ v,
    const float* __restrict__ Wq, const float* __restrict__ Wk, const float* __restrict__ Wv,
    float* __restrict__ qp, float* __restrict__ kp, float* __restrict__ vp)
{
    const float* A;
    const float* W;
    float* O;
    int z = blockIdx.z;
    if (z == 0)      { A = q; W = Wq; O = qp; }
    else if (z == 1) { A = k; W = Wk; O = kp; }
    else             { A = v; W = Wv; O = vp; }

    // +4 pad keeps 16B alignment (132*4B = 528 = 33*16) and spreads banks.
    __shared__ float As[16][132];   // As[k][m]
    __shared__ float Bs[16][132];   // Bs[k][n]

    const int t  = threadIdx.x;
    const int tx = t & 15;          // n-dir micro position
    const int ty = t >> 4;          // m-dir micro position
    const int row0 = blockIdx.x * 128;
    const int col0 = blockIdx.y * 128;

    float acc[8][8];
    #pragma unroll
    for (int i = 0; i < 8; ++i)
        #pragma unroll
        for (int j = 0; j < 8; ++j) acc[i][j] = 0.f;

    const int ar  = t >> 2;   // 0..63 (A tile row)
    const int ac4 = t & 3;    // 0..3  (A tile col group of 4)
    const int bk  = t >> 5;   // 0..7  (B tile row)
    const int bc  = t & 31;   // 0..31 (B tile col group of 4)

    for (int k0 = 0; k0 < Dc; k0 += 16) {
        float4 a0 = *(const float4*)(A + (size_t)(row0 + ar)      * Dc + k0 + ac4 * 4);
        float4 a1 = *(const float4*)(A + (size_t)(row0 + ar + 64) * Dc + k0 + ac4 * 4);
        float4 b0 = *(const float4*)(W + (size_t)(k0 + bk)     * Dc + col0 + bc * 4);
        float4 b1 = *(const float4*)(W + (size_t)(k0 + bk + 8) * Dc + col0 + bc * 4);
        __syncthreads();  // previous iteration's reads done before overwrite
        As[ac4 * 4 + 0][ar] = a0.x;
        As[ac4 * 4 + 1][ar] = a0.y;
        As[ac4 * 4 + 2][ar] = a0.z;
        As[ac4 * 4 + 3][ar] = a0.w;
        As[ac4 * 4 + 0][ar + 64] = a1.x;
        As[ac4 * 4 + 1][ar + 64] = a1.y;
        As[ac4 * 4 + 2][ar + 64] = a1.z;
        As[ac4 * 4 + 3][ar + 64] = a1.w;
        *(float4*)&Bs[bk][bc * 4]     = b0;
        *(float4*)&Bs[bk + 8][bc * 4] = b1;
        __syncthreads();

        #pragma unroll
        for (int kk = 0; kk < 16; ++kk) {
            float4 av0 = *(const float4*)&As[kk][ty * 8];
            float4 av1 = *(const float4*)&As[kk][ty * 8 + 4];
            float4 bv0 = *(const float4*)&Bs[kk][tx * 8];
            float4 bv1 = *(const float4*)&Bs[kk][tx * 8 + 4];
            float a[8] = {av0.x, av0.y, av0.z, av0.w, av1.x, av1.y, av1.z, av1.w};
            float b[8] = {bv0.x, bv0.y, bv0.z, bv0.w, bv1.x, bv1.y, bv1.z, bv1.w};
            #pragma unroll
            for (int i = 0; i < 8; ++i)
                #pragma unroll
                for (int j = 0; j < 8; ++j)
                    acc[i][j] = fmaf(a[i], b[j], acc[i][j]);
        }
    }

    #pragma unroll
    for (int i = 0; i < 8; ++i) {
        int row = row0 + ty * 8 + i;
        float4 o0 = {acc[i][0], acc[i][1], acc[i][2], acc[i][3]};
        float4 o1 = {acc[i][4], acc[i][5], acc[i][6], acc[i][7]};
        *(float4*)(O + (size_t)row * Dc + col0 + tx * 8)     = o0;
        *(float4*)(O + (size_t)row * Dc + col0 + tx * 8 + 4) = o1;
    }
}

// ---------------------------------------------------------------------------
// Kernel 2: sampled scores -> m[bh, l] = max_s(dot) - sum_s(dot)/L
// One wave per (bh, l); lane = e.
// ---------------------------------------------------------------------------
__global__ __launch_bounds__(256) void compute_m(
    const float* __restrict__ qp, const float* __restrict__ kp,
    const int* __restrict__ ksi, float* __restrict__ m_out)
{
    int wid  = blockIdx.x * 4 + (threadIdx.x >> 6);
    int lane = threadIdx.x & 63;
    int l  = wid & (Lc - 1);
    int bh = wid >> 11;          // Lc = 2048 = 2^11
    const float* qrow  = qp + (size_t)bh * LEc + l * Ec;
    const float* kbase = kp + (size_t)bh * LEc;
    float qv = qrow[lane];
    float mx = -FLT_MAX, sm = 0.f;
    for (int s = 0; s < Sc; ++s) {
        int j = ksi[l * Sc + s];
        float p = qv * kbase[j * Ec + lane];
        #pragma unroll
        for (int o = 1; o < 64; o <<= 1) p += __shfl_xor(p, o);
        mx = fmaxf(mx, p);
        sm += p;
    }
    if (lane == 0) m_out[bh * Lc + l] = mx - sm * (1.0f / Lc);
}

// ---------------------------------------------------------------------------
// Kernel 3: top-40 indices per (bh). Iterative extract-max with wave-parallel
// (value,index) reduction. Tie -> lower idx (matches jax.lax.top_k).
// ---------------------------------------------------------------------------
__global__ __launch_bounds__(256) void topk40(
    const float* __restrict__ m_in, int* __restrict__ mtop)
{
    __shared__ float vals[Lc];
    __shared__ float wv[4];
    __shared__ int   wi[4];
    int bh = blockIdx.x, t = threadIdx.x;
    int lane = t & 63, w = t >> 6;
    for (int i = t; i < Lc; i += 256) vals[i] = m_in[bh * Lc + i];
    __syncthreads();
    for (int it = 0; it < Uc; ++it) {
        float lv = -FLT_MAX; int li = 0x7fffffff;
        #pragma unroll
        for (int rep = 0; rep < Lc / 256; ++rep) {
            int i = rep * 256 + t;
            float v = vals[i];
            if (v > lv) { lv = v; li = i; }   // visits increasing i per thread
        }
        // 64-lane butterfly reduce: max value, lower index on tie
        #pragma unroll
        for (int o = 1; o < 64; o <<= 1) {
            float ov = __shfl_xor(lv, o);
            int   oi = __shfl_xor(li, o);
            if (ov > lv || (ov == lv && oi < li)) { lv = ov; li = oi; }
        }
        if (lane == 0) { wv[w] = lv; wi[w] = li; }
        __syncthreads();
        if (t == 0) {
            float Bv = wv[0]; int Bi = wi[0];
            #pragma unroll
            for (int j = 1; j < 4; ++j) {
                if (wv[j] > Bv || (wv[j] == Bv && wi[j] < Bi)) { Bv = wv[j]; Bi = wi[j]; }
            }
            mtop[bh * Uc + it] = Bi;
            vals[Bi] = -FLT_MAX;
        }
        __syncthreads();
    }
}

// ---------------------------------------------------------------------------
// Kernels 4-6: chunked inclusive cumsum of vp along l, per (bh, e) column.
// 64 chunks x 32 rows.
// ---------------------------------------------------------------------------
constexpr int CH = 64;  // chunks
constexpr int CR = 32;  // rows per chunk

__global__ __launch_bounds__(64) void cumsum_p1(
    const float* __restrict__ vp, float* __restrict__ psum)
{
    int bid = blockIdx.x;           // bh*64 + ch
    int e = threadIdx.x;
    int bh = bid >> 6, ch = bid & 63;
    const float* base = vp + (size_t)bh * LEc + (ch * CR) * Ec + e;
    float s = 0.f;
    #pragma unroll 8
    for (int r = 0; r < CR; ++r) s += base[r * Ec];
    psum[(size_t)bid * Ec + e] = s;
}

__global__ __launch_bounds__(64) void cumsum_p2(float* __restrict__ psum)
{
    int bh = blockIdx.x;
    int e = threadIdx.x;
    float off = 0.f;
    for (int c = 0; c < CH; ++c) {
        size_t idx = (size_t)(bh * CH + c) * Ec + e;
        float tv = psum[idx];
        psum[idx] = off;   // exclusive prefix
        off += tv;
    }
}

__global__ __launch_bounds__(64) void cumsum_p3(
    const float* __restrict__ vp, const float* __restrict__ psum,
    float* __restrict__ out)
{
    int bid = blockIdx.x;
    int e = threadIdx.x;
    int bh = bid >> 6, ch = bid & 63;
    const float* base = vp  + (size_t)bh * LEc + (ch * CR) * Ec + e;
    float*       ob   = out + (size_t)bh * LEc + (ch * CR) * Ec + e;
    float run = psum[(size_t)bid * Ec + e];
    #pragma unroll 8
    for (int r = 0; r < CR; ++r) { run += base[r * Ec]; ob[r * Ec] = run; }
}

// ---------------------------------------------------------------------------
// Kernel 7: flash-style attention update. One block per (bh, u) with
// bh = blockIdx.x % 32 (so all 40 u-blocks of a bh share XCD = bh%8, whose
// 4 bh x 1MB K/V working set fits the 4MB per-XCD L2).
// K/V staged in LDS via coalesced float4 tile loads (64 rows x 64e, pad 65).
// ---------------------------------------------------------------------------
constexpr int TR = 64;   // tile rows

__global__ __launch_bounds__(256) void attn_update(
    const float* __restrict__ qp, const float* __restrict__ kp,
    const float* __restrict__ vp, const int* __restrict__ mtop,
    float* __restrict__ out)
{
    __shared__ float tile[TR][Ec + 1];  // K then V staging (16.6 KB)
    __shared__ float sc[Lc];            // 8 KB
    __shared__ float qs[Ec];
    __shared__ float red[256];

    int bh = blockIdx.x & 31, u = blockIdx.x >> 5;
    int t = threadIdx.x;
    int lsel = mtop[bh * Uc + u];
    const float* kb = kp + (size_t)bh * LEc;
    const float* vb = vp + (size_t)bh * LEc;
    if (t < Ec) qs[t] = qp[(size_t)bh * LEc + lsel * Ec + t];

    int ntiles = (lsel + TR) / TR;      // ceil((lsel+1)/TR)

    // ---- phase 1: scores ----
    const int r4 = t >> 2;      // row within tile (4 threads per row)
    const int qd = t & 3;       // quarter of the dot
    float lmax = -FLT_MAX;
    for (int tt = 0; tt < ntiles; ++tt) {
        int l0 = tt * TR;
        __syncthreads();  // protect tile reuse
        // coalesced load: TR*Ec floats = 1024 float4, 256 threads -> 4 each
        #pragma unroll
        for (int i = 0; i < 4; ++i) {
            int f = i * 256 + t;            // float4 index
            int row = f >> 4, cg = f & 15;  // 16 float4 per row
            float4 d = *(const float4*)(kb + (size_t)(l0 + row) * Ec + cg * 4);
            tile[row][cg * 4 + 0] = d.x;
            tile[row][cg * 4 + 1] = d.y;
            tile[row][cg * 4 + 2] = d.z;
            tile[row][cg * 4 + 3] = d.w;
        }
        __syncthreads();
        int l = l0 + r4;
        float dot = 0.f;
        #pragma unroll
        for (int i = 0; i < 16; ++i)
            dot = fmaf(tile[r4][qd * 16 + i], qs[qd * 16 + i], dot);
        dot += __shfl_xor(dot, 1);
        dot += __shfl_xor(dot, 2);
        dot *= 0.125f;   // 1/sqrt(64)
        if (l <= lsel) {
            if (qd == 0) sc[l] = dot;
            lmax = fmaxf(lmax, dot);
        }
    }
    red[t] = lmax;
    __syncthreads();
    for (int s = 128; s > 0; s >>= 1) {
        if (t < s) red[t] = fmaxf(red[t], red[t + s]);
        __syncthreads();
    }
    float mx = red[0];
    __syncthreads();

    // ---- phase 2: exp + sum ----
    float lsum = 0.f;
    for (int l = t; l <= lsel; l += 256) {
        float ex = __expf(sc[l] - mx);
        sc[l] = ex;
        lsum += ex;
    }
    red[t] = lsum;
    __syncthreads();
    for (int s = 128; s > 0; s >>= 1) {
        if (t < s) red[t] += red[t + s];
        __syncthreads();
    }
    float inv = 1.0f / red[0];

    // ---- phase 3: PV ----
    int e = t & 63, part = t >> 6;   // 4 row-partitions x 64 e-lanes
    float acc = 0.f;
    for (int tt = 0; tt < ntiles; ++tt) {
        int l0 = tt * TR;
        __syncthreads();
        #pragma unroll
        for (int i = 0; i < 4; ++i) {
            int f = i * 256 + t;
            int row = f >> 4, cg = f & 15;
            float4 d = *(const float4*)(vb + (size_t)(l0 + row) * Ec + cg * 4);
            tile[row][cg * 4 + 0] = d.x;
            tile[row][cg * 4 + 1] = d.y;
            tile[row][cg * 4 + 2] = d.z;
            tile[row][cg * 4 + 3] = d.w;
        }
        __syncthreads();
        int rmax = min(TR, lsel + 1 - l0);
        for (int r = part; r < rmax; r += 4)
            acc = fmaf(sc[l0 + r], tile[r][e], acc);
    }
    __syncthreads();
    red[part * Ec + e] = acc;
    __syncthreads();
    if (t < Ec) {
        float c = (red[t] + red[Ec + t] + red[2 * Ec + t] + red[3 * Ec + t]) * inv;
        out[(size_t)bh * LEc + lsel * Ec + t] = c;
    }
}

// ---------------------------------------------------------------------------
extern "C" void kernel_launch(void* const* d_in, const int* in_sizes, int n_in,
                              void* d_out, int out_size, void* d_ws, size_t ws_size,
                              hipStream_t stream)
{
    const float* q   = (const float*)d_in[0];
    const float* k   = (const float*)d_in[1];
    const float* v   = (const float*)d_in[2];
    const float* Wq  = (const float*)d_in[3];
    const float* Wk  = (const float*)d_in[4];
    const float* Wv  = (const float*)d_in[5];
    const int*   ksi = (const int*)d_in[6];
    float* out = (float*)d_out;

    // workspace layout (floats)
    float* wsf  = (float*)d_ws;
    float* qp   = wsf;                           // 4,194,304
    float* kp   = qp + (size_t)Mrows * Dc;       // 4,194,304
    float* vp   = kp + (size_t)Mrows * Dc;       // 4,194,304
    float* psum = vp + (size_t)Mrows * Dc;       // 32*64*64 = 131,072
    float* m_ws = psum + (size_t)BHc * CH * Ec;  // 65,536
    int*   mtop = (int*)(m_ws + (size_t)BHc * Lc); // 1,280 ints

    dim3 g1(Mrows / 128, Dc / 128, 3);
    gemm3_f32<<<g1, 256, 0, stream>>>(q, k, v, Wq, Wk, Wv, qp, kp, vp);

    compute_m<<<(BHc * Lc) / 4, 256, 0, stream>>>(qp, kp, ksi, m_ws);

    topk40<<<BHc, 256, 0, stream>>>(m_ws, mtop);

    cumsum_p1<<<BHc * CH, 64, 0, stream>>>(vp, psum);
    cumsum_p2<<<BHc, 64, 0, stream>>>(psum);
    cumsum_p3<<<BHc * CH, 64, 0, stream>>>(vp, psum, out);

    attn_update<<<BHc * Uc, 256, 0, stream>>>(qp, kp, vp, mtop, out);
}

// Round 4
// 388.855 us; speedup vs baseline: 3.3104x; 1.1838x over previous
//
#include <hip/hip_runtime.h>
#include <hip/hip_bf16.h>
#include <float.h>

// Problem constants
constexpr int Bc = 4;
constexpr int Lc = 2048;
constexpr int Dc = 512;
constexpr int Hc = 8;
constexpr int Ec = 64;
constexpr int Sc = 40;   // sample_k
constexpr int Uc = 40;   // u_q (top-k queries)
constexpr int LEc = Lc * Ec;      // 131072
constexpr int BHc = Bc * Hc;      // 32
constexpr int Mrows = Bc * Lc;    // 8192 rows per GEMM

// ---------------------------------------------------------------------------
// Kernel 1: three projection GEMMs, f32.  (8192 x 512) @ (512 x 512)
// 128x128 tile, 256 threads, 8x8 micro-tile, BK=16.
// blockIdx.z selects {q@Wq, k@Wk, v@Wv}.
// ---------------------------------------------------------------------------
__global__ __launch_bounds__(256) void gemm3_f32(
    const float* __restrict__ q, const float* __restrict__ k, const float* __restrict__ v,
    const float* __restrict__ Wq, const float* __restrict__ Wk, const float* __restrict__ Wv,
    float* __restrict__ qp, float* __restrict__ kp, float* __restrict__ vp)
{
    const float* A;
    const float* W;
    float* O;
    int z = blockIdx.z;
    if (z == 0)      { A = q; W = Wq; O = qp; }
    else if (z == 1) { A = k; W = Wk; O = kp; }
    else             { A = v; W = Wv; O = vp; }

    // +4 pad keeps 16B alignment (132*4B = 528 = 33*16) and spreads banks.
    __shared__ float As[16][132];   // As[k][m]
    __shared__ float Bs[16][132];   // Bs[k][n]

    const int t  = threadIdx.x;
    const int tx = t & 15;          // n-dir micro position
    const int ty = t >> 4;          // m-dir micro position
    const int row0 = blockIdx.x * 128;
    const int col0 = blockIdx.y * 128;

    float acc[8][8];
    #pragma unroll
    for (int i = 0; i < 8; ++i)
        #pragma unroll
        for (int j = 0; j < 8; ++j) acc[i][j] = 0.f;

    const int ar  = t >> 2;   // 0..63 (A tile row)
    const int ac4 = t & 3;    // 0..3  (A tile col group of 4)
    const int bk  = t >> 5;   // 0..7  (B tile row)
    const int bc  = t & 31;   // 0..31 (B tile col group of 4)

    for (int k0 = 0; k0 < Dc; k0 += 16) {
        float4 a0 = *(const float4*)(A + (size_t)(row0 + ar)      * Dc + k0 + ac4 * 4);
        float4 a1 = *(const float4*)(A + (size_t)(row0 + ar + 64) * Dc + k0 + ac4 * 4);
        float4 b0 = *(const float4*)(W + (size_t)(k0 + bk)     * Dc + col0 + bc * 4);
        float4 b1 = *(const float4*)(W + (size_t)(k0 + bk + 8) * Dc + col0 + bc * 4);
        __syncthreads();  // previous iteration's reads done before overwrite
        As[ac4 * 4 + 0][ar] = a0.x;
        As[ac4 * 4 + 1][ar] = a0.y;
        As[ac4 * 4 + 2][ar] = a0.z;
        As[ac4 * 4 + 3][ar] = a0.w;
        As[ac4 * 4 + 0][ar + 64] = a1.x;
        As[ac4 * 4 + 1][ar + 64] = a1.y;
        As[ac4 * 4 + 2][ar + 64] = a1.z;
        As[ac4 * 4 + 3][ar + 64] = a1.w;
        *(float4*)&Bs[bk][bc * 4]     = b0;
        *(float4*)&Bs[bk + 8][bc * 4] = b1;
        __syncthreads();

        #pragma unroll
        for (int kk = 0; kk < 16; ++kk) {
            float4 av0 = *(const float4*)&As[kk][ty * 8];
            float4 av1 = *(const float4*)&As[kk][ty * 8 + 4];
            float4 bv0 = *(const float4*)&Bs[kk][tx * 8];
            float4 bv1 = *(const float4*)&Bs[kk][tx * 8 + 4];
            float a[8] = {av0.x, av0.y, av0.z, av0.w, av1.x, av1.y, av1.z, av1.w};
            float b[8] = {bv0.x, bv0.y, bv0.z, bv0.w, bv1.x, bv1.y, bv1.z, bv1.w};
            #pragma unroll
            for (int i = 0; i < 8; ++i)
                #pragma unroll
                for (int j = 0; j < 8; ++j)
                    acc[i][j] = fmaf(a[i], b[j], acc[i][j]);
        }
    }

    #pragma unroll
    for (int i = 0; i < 8; ++i) {
        int row = row0 + ty * 8 + i;
        float4 o0 = {acc[i][0], acc[i][1], acc[i][2], acc[i][3]};
        float4 o1 = {acc[i][4], acc[i][5], acc[i][6], acc[i][7]};
        *(float4*)(O + (size_t)row * Dc + col0 + tx * 8)     = o0;
        *(float4*)(O + (size_t)row * Dc + col0 + tx * 8 + 4) = o1;
    }
}

// ---------------------------------------------------------------------------
// Kernel 2: sampled scores -> m[bh, l] = max_s(dot) - sum_s(dot)/L
// One wave per (bh, l); LANE = SAMPLE. Each lane computes the full
// 64-element dot via float4 gathers (16 independent loads, no shuffles
// in the inner loop); q row staged in LDS (broadcast reads are free).
// One 6-step butterfly (max+sum fused) per l at the end.
// ---------------------------------------------------------------------------
__global__ __launch_bounds__(256) void compute_m(
    const float* __restrict__ qp, const float* __restrict__ kp,
    const int* __restrict__ ksi, float* __restrict__ m_out)
{
    __shared__ float qsh[4][Ec];
    int w    = threadIdx.x >> 6;
    int lane = threadIdx.x & 63;
    int wid  = blockIdx.x * 4 + w;
    int l  = wid & (Lc - 1);
    int bh = wid >> 11;          // Lc = 2048 = 2^11
    const float* kbase = kp + (size_t)bh * LEc;

    // stage q row (64 lanes x 1 float, coalesced)
    qsh[w][lane] = qp[(size_t)bh * LEc + l * Ec + lane];
    // per-lane sample index (coalesced 40-lane load)
    int j = (lane < Sc) ? ksi[l * Sc + lane] : 0;
    __syncthreads();

    float dot = 0.f;
    if (lane < Sc) {
        const float4* krow = (const float4*)(kbase + (size_t)j * Ec);
        const float4* qrow = (const float4*)&qsh[w][0];
        #pragma unroll
        for (int i = 0; i < 16; ++i) {
            float4 kv = krow[i];
            float4 qv = qrow[i];   // same addr across lanes -> LDS broadcast
            dot += kv.x * qv.x + kv.y * qv.y + kv.z * qv.z + kv.w * qv.w;
        }
    }
    float dmax = (lane < Sc) ? dot : -FLT_MAX;
    float dsum = (lane < Sc) ? dot : 0.f;
    #pragma unroll
    for (int o = 1; o < 64; o <<= 1) {
        dmax = fmaxf(dmax, __shfl_xor(dmax, o));
        dsum += __shfl_xor(dsum, o);
    }
    if (lane == 0) m_out[bh * Lc + l] = dmax - dsum * (1.0f / Lc);
}

// ---------------------------------------------------------------------------
// Kernel 3: top-40 indices per (bh). Iterative extract-max with wave-parallel
// (value,index) reduction. Tie -> lower idx (matches jax.lax.top_k).
// ---------------------------------------------------------------------------
__global__ __launch_bounds__(256) void topk40(
    const float* __restrict__ m_in, int* __restrict__ mtop)
{
    __shared__ float vals[Lc];
    __shared__ float wv[4];
    __shared__ int   wi[4];
    int bh = blockIdx.x, t = threadIdx.x;
    int lane = t & 63, w = t >> 6;
    for (int i = t; i < Lc; i += 256) vals[i] = m_in[bh * Lc + i];
    __syncthreads();
    for (int it = 0; it < Uc; ++it) {
        float lv = -FLT_MAX; int li = 0x7fffffff;
        #pragma unroll
        for (int rep = 0; rep < Lc / 256; ++rep) {
            int i = rep * 256 + t;
            float v = vals[i];
            if (v > lv) { lv = v; li = i; }   // visits increasing i per thread
        }
        // 64-lane butterfly reduce: max value, lower index on tie
        #pragma unroll
        for (int o = 1; o < 64; o <<= 1) {
            float ov = __shfl_xor(lv, o);
            int   oi = __shfl_xor(li, o);
            if (ov > lv || (ov == lv && oi < li)) { lv = ov; li = oi; }
        }
        if (lane == 0) { wv[w] = lv; wi[w] = li; }
        __syncthreads();
        if (t == 0) {
            float Bv = wv[0]; int Bi = wi[0];
            #pragma unroll
            for (int j = 1; j < 4; ++j) {
                if (wv[j] > Bv || (wv[j] == Bv && wi[j] < Bi)) { Bv = wv[j]; Bi = wi[j]; }
            }
            mtop[bh * Uc + it] = Bi;
            vals[Bi] = -FLT_MAX;
        }
        __syncthreads();
    }
}

// ---------------------------------------------------------------------------
// Kernels 4-6: chunked inclusive cumsum of vp along l, per (bh, e) column.
// 64 chunks x 32 rows.
// ---------------------------------------------------------------------------
constexpr int CH = 64;  // chunks
constexpr int CR = 32;  // rows per chunk

__global__ __launch_bounds__(64) void cumsum_p1(
    const float* __restrict__ vp, float* __restrict__ psum)
{
    int bid = blockIdx.x;           // bh*64 + ch
    int e = threadIdx.x;
    int bh = bid >> 6, ch = bid & 63;
    const float* base = vp + (size_t)bh * LEc + (ch * CR) * Ec + e;
    float s = 0.f;
    #pragma unroll 8
    for (int r = 0; r < CR; ++r) s += base[r * Ec];
    psum[(size_t)bid * Ec + e] = s;
}

__global__ __launch_bounds__(64) void cumsum_p2(float* __restrict__ psum)
{
    int bh = blockIdx.x;
    int e = threadIdx.x;
    float off = 0.f;
    for (int c = 0; c < CH; ++c) {
        size_t idx = (size_t)(bh * CH + c) * Ec + e;
        float tv = psum[idx];
        psum[idx] = off;   // exclusive prefix
        off += tv;
    }
}

__global__ __launch_bounds__(64) void cumsum_p3(
    const float* __restrict__ vp, const float* __restrict__ psum,
    float* __restrict__ out)
{
    int bid = blockIdx.x;
    int e = threadIdx.x;
    int bh = bid >> 6, ch = bid & 63;
    const float* base = vp  + (size_t)bh * LEc + (ch * CR) * Ec + e;
    float*       ob   = out + (size_t)bh * LEc + (ch * CR) * Ec + e;
    float run = psum[(size_t)bid * Ec + e];
    #pragma unroll 8
    for (int r = 0; r < CR; ++r) { run += base[r * Ec]; ob[r * Ec] = run; }
}

// ---------------------------------------------------------------------------
// Kernel 7: flash-style attention update. One block per (bh, u) with
// bh = blockIdx.x % 32 (so all 40 u-blocks of a bh share XCD = bh%8, whose
// 4 bh x 1MB K/V working set fits the 4MB per-XCD L2).
// K/V staged in LDS via coalesced float4 tile loads (64 rows x 64e, pad 65).
// ---------------------------------------------------------------------------
constexpr int TR = 64;   // tile rows

__global__ __launch_bounds__(256) void attn_update(
    const float* __restrict__ qp, const float* __restrict__ kp,
    const float* __restrict__ vp, const int* __restrict__ mtop,
    float* __restrict__ out)
{
    __shared__ float tile[TR][Ec + 1];  // K then V staging (16.6 KB)
    __shared__ float sc[Lc];            // 8 KB
    __shared__ float qs[Ec];
    __shared__ float red[256];

    int bh = blockIdx.x & 31, u = blockIdx.x >> 5;
    int t = threadIdx.x;
    int lsel = mtop[bh * Uc + u];
    const float* kb = kp + (size_t)bh * LEc;
    const float* vb = vp + (size_t)bh * LEc;
    if (t < Ec) qs[t] = qp[(size_t)bh * LEc + lsel * Ec + t];

    int ntiles = (lsel + TR) / TR;      // ceil((lsel+1)/TR)

    // ---- phase 1: scores ----
    const int r4 = t >> 2;      // row within tile (4 threads per row)
    const int qd = t & 3;       // quarter of the dot
    float lmax = -FLT_MAX;
    for (int tt = 0; tt < ntiles; ++tt) {
        int l0 = tt * TR;
        __syncthreads();  // protect tile reuse
        // coalesced load: TR*Ec floats = 1024 float4, 256 threads -> 4 each
        #pragma unroll
        for (int i = 0; i < 4; ++i) {
            int f = i * 256 + t;            // float4 index
            int row = f >> 4, cg = f & 15;  // 16 float4 per row
            float4 d = *(const float4*)(kb + (size_t)(l0 + row) * Ec + cg * 4);
            tile[row][cg * 4 + 0] = d.x;
            tile[row][cg * 4 + 1] = d.y;
            tile[row][cg * 4 + 2] = d.z;
            tile[row][cg * 4 + 3] = d.w;
        }
        __syncthreads();
        int l = l0 + r4;
        float dot = 0.f;
        #pragma unroll
        for (int i = 0; i < 16; ++i)
            dot = fmaf(tile[r4][qd * 16 + i], qs[qd * 16 + i], dot);
        dot += __shfl_xor(dot, 1);
        dot += __shfl_xor(dot, 2);
        dot *= 0.125f;   // 1/sqrt(64)
        if (l <= lsel) {
            if (qd == 0) sc[l] = dot;
            lmax = fmaxf(lmax, dot);
        }
    }
    red[t] = lmax;
    __syncthreads();
    for (int s = 128; s > 0; s >>= 1) {
        if (t < s) red[t] = fmaxf(red[t], red[t + s]);
        __syncthreads();
    }
    float mx = red[0];
    __syncthreads();

    // ---- phase 2: exp + sum ----
    float lsum = 0.f;
    for (int l = t; l <= lsel; l += 256) {
        float ex = __expf(sc[l] - mx);
        sc[l] = ex;
        lsum += ex;
    }
    red[t] = lsum;
    __syncthreads();
    for (int s = 128; s > 0; s >>= 1) {
        if (t < s) red[t] += red[t + s];
        __syncthreads();
    }
    float inv = 1.0f / red[0];

    // ---- phase 3: PV ----
    int e = t & 63, part = t >> 6;   // 4 row-partitions x 64 e-lanes
    float acc = 0.f;
    for (int tt = 0; tt < ntiles; ++tt) {
        int l0 = tt * TR;
        __syncthreads();
        #pragma unroll
        for (int i = 0; i < 4; ++i) {
            int f = i * 256 + t;
            int row = f >> 4, cg = f & 15;
            float4 d = *(const float4*)(vb + (size_t)(l0 + row) * Ec + cg * 4);
            tile[row][cg * 4 + 0] = d.x;
            tile[row][cg * 4 + 1] = d.y;
            tile[row][cg * 4 + 2] = d.z;
            tile[row][cg * 4 + 3] = d.w;
        }
        __syncthreads();
        int rmax = min(TR, lsel + 1 - l0);
        for (int r = part; r < rmax; r += 4)
            acc = fmaf(sc[l0 + r], tile[r][e], acc);
    }
    __syncthreads();
    red[part * Ec + e] = acc;
    __syncthreads();
    if (t < Ec) {
        float c = (red[t] + red[Ec + t] + red[2 * Ec + t] + red[3 * Ec + t]) * inv;
        out[(size_t)bh * LEc + lsel * Ec + t] = c;
    }
}

// ---------------------------------------------------------------------------
extern "C" void kernel_launch(void* const* d_in, const int* in_sizes, int n_in,
                              void* d_out, int out_size, void* d_ws, size_t ws_size,
                              hipStream_t stream)
{
    const float* q   = (const float*)d_in[0];
    const float* k   = (const float*)d_in[1];
    const float* v   = (const float*)d_in[2];
    const float* Wq  = (const float*)d_in[3];
    const float* Wk  = (const float*)d_in[4];
    const float* Wv  = (const float*)d_in[5];
    const int*   ksi = (const int*)d_in[6];
    float* out = (float*)d_out;

    // workspace layout (floats)
    float* wsf  = (float*)d_ws;
    float* qp   = wsf;                           // 4,194,304
    float* kp   = qp + (size_t)Mrows * Dc;       // 4,194,304
    float* vp   = kp + (size_t)Mrows * Dc;       // 4,194,304
    float* psum = vp + (size_t)Mrows * Dc;       // 32*64*64 = 131,072
    float* m_ws = psum + (size_t)BHc * CH * Ec;  // 65,536
    int*   mtop = (int*)(m_ws + (size_t)BHc * Lc); // 1,280 ints

    dim3 g1(Mrows / 128, Dc / 128, 3);
    gemm3_f32<<<g1, 256, 0, stream>>>(q, k, v, Wq, Wk, Wv, qp, kp, vp);

    compute_m<<<(BHc * Lc) / 4, 256, 0, stream>>>(qp, kp, ksi, m_ws);

    topk40<<<BHc, 256, 0, stream>>>(m_ws, mtop);

    cumsum_p1<<<BHc * CH, 64, 0, stream>>>(vp, psum);
    cumsum_p2<<<BHc, 64, 0, stream>>>(psum);
    cumsum_p3<<<BHc * CH, 64, 0, stream>>>(vp, psum, out);

    attn_update<<<BHc * Uc, 256, 0, stream>>>(qp, kp, vp, mtop, out);
}

// Round 5
// 332.846 us; speedup vs baseline: 3.8674x; 1.1683x over previous
//
#include <hip/hip_runtime.h>
#include <hip/hip_bf16.h>
#include <float.h>

// Problem constants
constexpr int Bc = 4;
constexpr int Lc = 2048;
constexpr int Dc = 512;
constexpr int Hc = 8;
constexpr int Ec = 64;
constexpr int Sc = 40;   // sample_k
constexpr int Uc = 40;   // u_q (top-k queries)
constexpr int LEc = Lc * Ec;      // 131072
constexpr int BHc = Bc * Hc;      // 32
constexpr int Mrows = Bc * Lc;    // 8192 rows per GEMM

typedef __attribute__((ext_vector_type(8))) short s16x8;
typedef __attribute__((ext_vector_type(4))) float f32x4;

// round-to-nearest-even f32 -> bf16 (bit pattern in a short)
__device__ __forceinline__ short f2bf(float x) {
    unsigned u = __float_as_uint(x);
    unsigned r = (u + 0x7fffu + ((u >> 16) & 1u)) >> 16;
    return (short)r;
}
__device__ __forceinline__ float bf2f(short s) {
    return __uint_as_float(((unsigned)(unsigned short)s) << 16);
}
__device__ __forceinline__ uint4 pack8(const short* s) {
    uint4 r;
    r.x = (unsigned)(unsigned short)s[0] | ((unsigned)(unsigned short)s[1] << 16);
    r.y = (unsigned)(unsigned short)s[2] | ((unsigned)(unsigned short)s[3] << 16);
    r.z = (unsigned)(unsigned short)s[4] | ((unsigned)(unsigned short)s[5] << 16);
    r.w = (unsigned)(unsigned short)s[6] | ((unsigned)(unsigned short)s[7] << 16);
    return r;
}

// ---------------------------------------------------------------------------
// Kernel 0: W prep — transpose + hi/lo bf16 split.
// Wt_hi[z][n][k] = bf16(W_z[k][n]); Wt_lo = bf16(residual) (z<2 only).
// grid (8,8,3), 256 threads, LDS-tiled transpose.
// ---------------------------------------------------------------------------
__global__ __launch_bounds__(256) void wprep(
    const float* __restrict__ Wq, const float* __restrict__ Wk,
    const float* __restrict__ Wv,
    short* __restrict__ Wt_hi, short* __restrict__ Wt_lo)
{
    __shared__ float tile[64][65];
    int z = blockIdx.z;
    const float* W = (z == 0) ? Wq : (z == 1) ? Wk : Wv;
    int k0 = blockIdx.x * 64, n0 = blockIdx.y * 64;
    int t = threadIdx.x;
    #pragma unroll
    for (int i = 0; i < 4; ++i) {
        int c = i * 256 + t, row = c >> 4, qq = c & 15;
        float4 d = *(const float4*)(W + (size_t)(k0 + row) * Dc + n0 + qq * 4);
        tile[row][qq * 4 + 0] = d.x; tile[row][qq * 4 + 1] = d.y;
        tile[row][qq * 4 + 2] = d.z; tile[row][qq * 4 + 3] = d.w;
    }
    __syncthreads();
    int n = t >> 2, ks = (t & 3) * 16;
    short hs[16], ls[16];
    #pragma unroll
    for (int j = 0; j < 16; ++j) {
        float x = tile[ks + j][n];
        short h = f2bf(x);
        hs[j] = h;
        ls[j] = f2bf(x - bf2f(h));
    }
    size_t base = (size_t)z * Dc * Dc + (size_t)(n0 + n) * Dc + k0 + ks;
    *(uint4*)(Wt_hi + base)     = pack8(hs);
    *(uint4*)(Wt_hi + base + 8) = pack8(hs + 8);
    if (z < 2) {
        *(uint4*)(Wt_lo + base)     = pack8(ls);
        *(uint4*)(Wt_lo + base + 8) = pack8(ls + 8);
    }
}

// ---------------------------------------------------------------------------
// Kernel 1: projection GEMMs via bf16 MFMA, split-precision.
// qp/kp: 3 terms (Ahi*Bhi + Ahi*Blo + Alo*Bhi) ~ f32 accuracy (needed for
// the top-40 selection on m). vp: 1 term (plain bf16) — error invisible
// at the comparison granularity.
// 128x128 tile, BK=32, 4 waves (each 64x64 out), mfma_f32_16x16x32_bf16.
// A converted f32->hi/lo on the fly during staging; B from pre-split Wt.
// LDS rows padded to 40 shorts (80 B) -> uniform bank spread on b128 reads.
// ---------------------------------------------------------------------------
__global__ __launch_bounds__(256) void gemm_mfma(
    const float* __restrict__ q, const float* __restrict__ k,
    const float* __restrict__ v,
    const short* __restrict__ Wt_hi, const short* __restrict__ Wt_lo,
    float* __restrict__ qp, float* __restrict__ kp, float* __restrict__ vp)
{
    int z = blockIdx.z;
    const float* A = (z == 0) ? q : (z == 1) ? k : v;
    float* O = (z == 0) ? qp : (z == 1) ? kp : vp;
    const short* Bhi_g = Wt_hi + (size_t)z * Dc * Dc;
    const short* Blo_g = Wt_lo + (size_t)z * Dc * Dc;
    const bool split = (z != 2);

    __shared__ short Ahi[128][40];
    __shared__ short Alo[128][40];
    __shared__ short Bhi[128][40];
    __shared__ short Blo[128][40];

    const int t = threadIdx.x;
    const int lane = t & 63, w = t >> 6;
    const int wm = w >> 1, wn = w & 1;          // wave -> 64x64 quadrant
    const int row0 = blockIdx.x * 128, col0 = blockIdx.y * 128;
    const int kg = lane >> 4, fr = lane & 15;

    f32x4 acc[4][4];
    #pragma unroll
    for (int i = 0; i < 4; ++i)
        #pragma unroll
        for (int j = 0; j < 4; ++j)
            acc[i][j] = (f32x4){0.f, 0.f, 0.f, 0.f};

    for (int k0 = 0; k0 < Dc; k0 += 32) {
        __syncthreads();
        // ---- stage A: 128 rows x 32 f32 -> hi/lo bf16 in LDS ----
        #pragma unroll
        for (int i = 0; i < 4; ++i) {
            int c = i * 256 + t, row = c >> 3, part = c & 7;
            float4 d = *(const float4*)(A + (size_t)(row0 + row) * Dc + k0 + part * 4);
            short h0 = f2bf(d.x), h1 = f2bf(d.y), h2 = f2bf(d.z), h3 = f2bf(d.w);
            *(short4*)&Ahi[row][part * 4] = make_short4(h0, h1, h2, h3);
            if (split) {
                short l0 = f2bf(d.x - bf2f(h0)), l1 = f2bf(d.y - bf2f(h1));
                short l2 = f2bf(d.z - bf2f(h2)), l3 = f2bf(d.w - bf2f(h3));
                *(short4*)&Alo[row][part * 4] = make_short4(l0, l1, l2, l3);
            }
        }
        // ---- stage B: 128 n-rows x 32 k bf16 from Wt ----
        #pragma unroll
        for (int i = 0; i < 2; ++i) {
            int c = i * 256 + t, row = c >> 2, part = c & 3;
            *(uint4*)&Bhi[row][part * 8] =
                *(const uint4*)(Bhi_g + (size_t)(col0 + row) * Dc + k0 + part * 8);
            if (split)
                *(uint4*)&Blo[row][part * 8] =
                    *(const uint4*)(Blo_g + (size_t)(col0 + row) * Dc + k0 + part * 8);
        }
        __syncthreads();

        // ---- fragments + MFMA ----
        s16x8 ah[4], al[4];
        #pragma unroll
        for (int mi = 0; mi < 4; ++mi) {
            int row = wm * 64 + mi * 16 + fr;
            ah[mi] = *(const s16x8*)&Ahi[row][kg * 8];
            if (split) al[mi] = *(const s16x8*)&Alo[row][kg * 8];
        }
        #pragma unroll
        for (int ni = 0; ni < 4; ++ni) {
            int row = wn * 64 + ni * 16 + fr;
            s16x8 bh = *(const s16x8*)&Bhi[row][kg * 8];
            if (split) {
                s16x8 bl = *(const s16x8*)&Blo[row][kg * 8];
                #pragma unroll
                for (int mi = 0; mi < 4; ++mi) {
                    acc[mi][ni] = __builtin_amdgcn_mfma_f32_16x16x32_bf16(ah[mi], bh, acc[mi][ni], 0, 0, 0);
                    acc[mi][ni] = __builtin_amdgcn_mfma_f32_16x16x32_bf16(ah[mi], bl, acc[mi][ni], 0, 0, 0);
                    acc[mi][ni] = __builtin_amdgcn_mfma_f32_16x16x32_bf16(al[mi], bh, acc[mi][ni], 0, 0, 0);
                }
            } else {
                #pragma unroll
                for (int mi = 0; mi < 4; ++mi)
                    acc[mi][ni] = __builtin_amdgcn_mfma_f32_16x16x32_bf16(ah[mi], bh, acc[mi][ni], 0, 0, 0);
            }
        }
    }

    // ---- epilogue: C/D layout col=lane&15, row=(lane>>4)*4+reg ----
    #pragma unroll
    for (int mi = 0; mi < 4; ++mi) {
        #pragma unroll
        for (int ni = 0; ni < 4; ++ni) {
            int row = row0 + wm * 64 + mi * 16 + (lane >> 4) * 4;
            int col = col0 + wn * 64 + ni * 16 + (lane & 15);
            #pragma unroll
            for (int r4 = 0; r4 < 4; ++r4)
                O[(size_t)(row + r4) * Dc + col] = acc[mi][ni][r4];
        }
    }
}

// ---------------------------------------------------------------------------
// Kernel 2: sampled scores -> m[bh, l] = max_s(dot) - sum_s(dot)/L
// One wave per (bh, l); LANE = SAMPLE.
// ---------------------------------------------------------------------------
__global__ __launch_bounds__(256) void compute_m(
    const float* __restrict__ qp, const float* __restrict__ kp,
    const int* __restrict__ ksi, float* __restrict__ m_out)
{
    __shared__ float qsh[4][Ec];
    int w    = threadIdx.x >> 6;
    int lane = threadIdx.x & 63;
    int wid  = blockIdx.x * 4 + w;
    int l  = wid & (Lc - 1);
    int bh = wid >> 11;          // Lc = 2048 = 2^11
    const float* kbase = kp + (size_t)bh * LEc;

    qsh[w][lane] = qp[(size_t)bh * LEc + l * Ec + lane];
    int j = (lane < Sc) ? ksi[l * Sc + lane] : 0;
    __syncthreads();

    float dot = 0.f;
    if (lane < Sc) {
        const float4* krow = (const float4*)(kbase + (size_t)j * Ec);
        const float4* qrow = (const float4*)&qsh[w][0];
        #pragma unroll
        for (int i = 0; i < 16; ++i) {
            float4 kv = krow[i];
            float4 qv = qrow[i];
            dot += kv.x * qv.x + kv.y * qv.y + kv.z * qv.z + kv.w * qv.w;
        }
    }
    float dmax = (lane < Sc) ? dot : -FLT_MAX;
    float dsum = (lane < Sc) ? dot : 0.f;
    #pragma unroll
    for (int o = 1; o < 64; o <<= 1) {
        dmax = fmaxf(dmax, __shfl_xor(dmax, o));
        dsum += __shfl_xor(dsum, o);
    }
    if (lane == 0) m_out[bh * Lc + l] = dmax - dsum * (1.0f / Lc);
}

// ---------------------------------------------------------------------------
// Kernel 3: top-40 indices per (bh). Wave-parallel extract-max.
// Tie -> lower idx (matches jax.lax.top_k).
// ---------------------------------------------------------------------------
__global__ __launch_bounds__(256) void topk40(
    const float* __restrict__ m_in, int* __restrict__ mtop)
{
    __shared__ float vals[Lc];
    __shared__ float wv[4];
    __shared__ int   wi[4];
    int bh = blockIdx.x, t = threadIdx.x;
    int lane = t & 63, w = t >> 6;
    for (int i = t; i < Lc; i += 256) vals[i] = m_in[bh * Lc + i];
    __syncthreads();
    for (int it = 0; it < Uc; ++it) {
        float lv = -FLT_MAX; int li = 0x7fffffff;
        #pragma unroll
        for (int rep = 0; rep < Lc / 256; ++rep) {
            int i = rep * 256 + t;
            float v = vals[i];
            if (v > lv) { lv = v; li = i; }
        }
        #pragma unroll
        for (int o = 1; o < 64; o <<= 1) {
            float ov = __shfl_xor(lv, o);
            int   oi = __shfl_xor(li, o);
            if (ov > lv || (ov == lv && oi < li)) { lv = ov; li = oi; }
        }
        if (lane == 0) { wv[w] = lv; wi[w] = li; }
        __syncthreads();
        if (t == 0) {
            float Bv = wv[0]; int Bi = wi[0];
            #pragma unroll
            for (int j = 1; j < 4; ++j) {
                if (wv[j] > Bv || (wv[j] == Bv && wi[j] < Bi)) { Bv = wv[j]; Bi = wi[j]; }
            }
            mtop[bh * Uc + it] = Bi;
            vals[Bi] = -FLT_MAX;
        }
        __syncthreads();
    }
}

// ---------------------------------------------------------------------------
// Kernels 4-6: chunked inclusive cumsum of vp along l, per (bh, e) column.
// ---------------------------------------------------------------------------
constexpr int CH = 64;  // chunks
constexpr int CR = 32;  // rows per chunk

__global__ __launch_bounds__(64) void cumsum_p1(
    const float* __restrict__ vp, float* __restrict__ psum)
{
    int bid = blockIdx.x;
    int e = threadIdx.x;
    int bh = bid >> 6, ch = bid & 63;
    const float* base = vp + (size_t)bh * LEc + (ch * CR) * Ec + e;
    float s = 0.f;
    #pragma unroll 8
    for (int r = 0; r < CR; ++r) s += base[r * Ec];
    psum[(size_t)bid * Ec + e] = s;
}

__global__ __launch_bounds__(64) void cumsum_p2(float* __restrict__ psum)
{
    int bh = blockIdx.x;
    int e = threadIdx.x;
    float off = 0.f;
    for (int c = 0; c < CH; ++c) {
        size_t idx = (size_t)(bh * CH + c) * Ec + e;
        float tv = psum[idx];
        psum[idx] = off;
        off += tv;
    }
}

__global__ __launch_bounds__(64) void cumsum_p3(
    const float* __restrict__ vp, const float* __restrict__ psum,
    float* __restrict__ out)
{
    int bid = blockIdx.x;
    int e = threadIdx.x;
    int bh = bid >> 6, ch = bid & 63;
    const float* base = vp  + (size_t)bh * LEc + (ch * CR) * Ec + e;
    float*       ob   = out + (size_t)bh * LEc + (ch * CR) * Ec + e;
    float run = psum[(size_t)bid * Ec + e];
    #pragma unroll 8
    for (int r = 0; r < CR; ++r) { run += base[r * Ec]; ob[r * Ec] = run; }
}

// ---------------------------------------------------------------------------
// Kernel 7: flash-style attention update. One block per (bh, u),
// bh = blockIdx.x & 31 so a bh's 40 blocks share one XCD's L2.
// ---------------------------------------------------------------------------
constexpr int TR = 64;   // tile rows

__global__ __launch_bounds__(256) void attn_update(
    const float* __restrict__ qp, const float* __restrict__ kp,
    const float* __restrict__ vp, const int* __restrict__ mtop,
    float* __restrict__ out)
{
    __shared__ float tile[TR][Ec + 1];
    __shared__ float sc[Lc];
    __shared__ float qs[Ec];
    __shared__ float red[256];

    int bh = blockIdx.x & 31, u = blockIdx.x >> 5;
    int t = threadIdx.x;
    int lsel = mtop[bh * Uc + u];
    const float* kb = kp + (size_t)bh * LEc;
    const float* vb = vp + (size_t)bh * LEc;
    if (t < Ec) qs[t] = qp[(size_t)bh * LEc + lsel * Ec + t];

    int ntiles = (lsel + TR) / TR;

    // ---- phase 1: scores ----
    const int r4 = t >> 2;
    const int qd = t & 3;
    float lmax = -FLT_MAX;
    for (int tt = 0; tt < ntiles; ++tt) {
        int l0 = tt * TR;
        __syncthreads();
        #pragma unroll
        for (int i = 0; i < 4; ++i) {
            int f = i * 256 + t;
            int row = f >> 4, cg = f & 15;
            float4 d = *(const float4*)(kb + (size_t)(l0 + row) * Ec + cg * 4);
            tile[row][cg * 4 + 0] = d.x;
            tile[row][cg * 4 + 1] = d.y;
            tile[row][cg * 4 + 2] = d.z;
            tile[row][cg * 4 + 3] = d.w;
        }
        __syncthreads();
        int l = l0 + r4;
        float dot = 0.f;
        #pragma unroll
        for (int i = 0; i < 16; ++i)
            dot = fmaf(tile[r4][qd * 16 + i], qs[qd * 16 + i], dot);
        dot += __shfl_xor(dot, 1);
        dot += __shfl_xor(dot, 2);
        dot *= 0.125f;
        if (l <= lsel) {
            if (qd == 0) sc[l] = dot;
            lmax = fmaxf(lmax, dot);
        }
    }
    red[t] = lmax;
    __syncthreads();
    for (int s = 128; s > 0; s >>= 1) {
        if (t < s) red[t] = fmaxf(red[t], red[t + s]);
        __syncthreads();
    }
    float mx = red[0];
    __syncthreads();

    // ---- phase 2: exp + sum ----
    float lsum = 0.f;
    for (int l = t; l <= lsel; l += 256) {
        float ex = __expf(sc[l] - mx);
        sc[l] = ex;
        lsum += ex;
    }
    red[t] = lsum;
    __syncthreads();
    for (int s = 128; s > 0; s >>= 1) {
        if (t < s) red[t] += red[t + s];
        __syncthreads();
    }
    float inv = 1.0f / red[0];

    // ---- phase 3: PV ----
    int e = t & 63, part = t >> 6;
    float acc = 0.f;
    for (int tt = 0; tt < ntiles; ++tt) {
        int l0 = tt * TR;
        __syncthreads();
        #pragma unroll
        for (int i = 0; i < 4; ++i) {
            int f = i * 256 + t;
            int row = f >> 4, cg = f & 15;
            float4 d = *(const float4*)(vb + (size_t)(l0 + row) * Ec + cg * 4);
            tile[row][cg * 4 + 0] = d.x;
            tile[row][cg * 4 + 1] = d.y;
            tile[row][cg * 4 + 2] = d.z;
            tile[row][cg * 4 + 3] = d.w;
        }
        __syncthreads();
        int rmax = min(TR, lsel + 1 - l0);
        for (int r = part; r < rmax; r += 4)
            acc = fmaf(sc[l0 + r], tile[r][e], acc);
    }
    __syncthreads();
    red[part * Ec + e] = acc;
    __syncthreads();
    if (t < Ec) {
        float c = (red[t] + red[Ec + t] + red[2 * Ec + t] + red[3 * Ec + t]) * inv;
        out[(size_t)bh * LEc + lsel * Ec + t] = c;
    }
}

// ---------------------------------------------------------------------------
extern "C" void kernel_launch(void* const* d_in, const int* in_sizes, int n_in,
                              void* d_out, int out_size, void* d_ws, size_t ws_size,
                              hipStream_t stream)
{
    const float* q   = (const float*)d_in[0];
    const float* k   = (const float*)d_in[1];
    const float* v   = (const float*)d_in[2];
    const float* Wq  = (const float*)d_in[3];
    const float* Wk  = (const float*)d_in[4];
    const float* Wv  = (const float*)d_in[5];
    const int*   ksi = (const int*)d_in[6];
    float* out = (float*)d_out;

    // workspace layout
    float* wsf  = (float*)d_ws;
    float* qp   = wsf;                            // 4,194,304 f
    float* kp   = qp + (size_t)Mrows * Dc;        // 4,194,304 f
    float* vp   = kp + (size_t)Mrows * Dc;        // 4,194,304 f
    float* psum = vp + (size_t)Mrows * Dc;        // 131,072 f
    float* m_ws = psum + (size_t)BHc * CH * Ec;   // 65,536 f
    int*   mtop = (int*)(m_ws + (size_t)BHc * Lc);      // 1,280 i
    short* Wt_hi = (short*)(mtop + BHc * Uc);           // 3*262144 s
    short* Wt_lo = Wt_hi + (size_t)3 * Dc * Dc;         // 3*262144 s

    wprep<<<dim3(8, 8, 3), 256, 0, stream>>>(Wq, Wk, Wv, Wt_hi, Wt_lo);

    dim3 g1(Mrows / 128, Dc / 128, 3);
    gemm_mfma<<<g1, 256, 0, stream>>>(q, k, v, Wt_hi, Wt_lo, qp, kp, vp);

    compute_m<<<(BHc * Lc) / 4, 256, 0, stream>>>(qp, kp, ksi, m_ws);

    topk40<<<BHc, 256, 0, stream>>>(m_ws, mtop);

    cumsum_p1<<<BHc * CH, 64, 0, stream>>>(vp, psum);
    cumsum_p2<<<BHc, 64, 0, stream>>>(psum);
    cumsum_p3<<<BHc * CH, 64, 0, stream>>>(vp, psum, out);

    attn_update<<<BHc * Uc, 256, 0, stream>>>(qp, kp, vp, mtop, out);
}

// Round 6
// 309.937 us; speedup vs baseline: 4.1533x; 1.0739x over previous
//
#include <hip/hip_runtime.h>
#include <hip/hip_bf16.h>
#include <float.h>

// Problem constants
constexpr int Bc = 4;
constexpr int Lc = 2048;
constexpr int Dc = 512;
constexpr int Hc = 8;
constexpr int Ec = 64;
constexpr int Sc = 40;   // sample_k
constexpr int Uc = 40;   // u_q (top-k queries)
constexpr int LEc = Lc * Ec;      // 131072
constexpr int BHc = Bc * Hc;      // 32
constexpr int Mrows = Bc * Lc;    // 8192 rows per GEMM

typedef __attribute__((ext_vector_type(8))) short s16x8;
typedef __attribute__((ext_vector_type(4))) float f32x4;
typedef unsigned int u32;

// round-to-nearest-even f32 -> bf16 (bit pattern in a short)
__device__ __forceinline__ short f2bf(float x) {
    unsigned u = __float_as_uint(x);
    unsigned r = (u + 0x7fffu + ((u >> 16) & 1u)) >> 16;
    return (short)r;
}
__device__ __forceinline__ float bf2f(short s) {
    return __uint_as_float(((unsigned)(unsigned short)s) << 16);
}
__device__ __forceinline__ uint4 pack8(const short* s) {
    uint4 r;
    r.x = (unsigned)(unsigned short)s[0] | ((unsigned)(unsigned short)s[1] << 16);
    r.y = (unsigned)(unsigned short)s[2] | ((unsigned)(unsigned short)s[3] << 16);
    r.z = (unsigned)(unsigned short)s[4] | ((unsigned)(unsigned short)s[5] << 16);
    r.w = (unsigned)(unsigned short)s[6] | ((unsigned)(unsigned short)s[7] << 16);
    return r;
}

// direct global->LDS DMA, 16 B per lane (dest = wave-uniform base + lane*16)
__device__ __forceinline__ void gld_lds16(const short* g, short* l) {
    __builtin_amdgcn_global_load_lds(
        (const __attribute__((address_space(1))) u32*)g,
        (__attribute__((address_space(3))) u32*)l, 16, 0, 0);
}

// ---------------------------------------------------------------------------
// Kernel 0a: split q,k -> (hi,lo) bf16; v -> hi bf16.  Pure memory pass.
// One float4 per thread; 2^20 float4 per tensor.
// ---------------------------------------------------------------------------
__global__ __launch_bounds__(256) void split_inputs(
    const float* __restrict__ q, const float* __restrict__ k, const float* __restrict__ v,
    short* __restrict__ qhi, short* __restrict__ qlo,
    short* __restrict__ khi, short* __restrict__ klo, short* __restrict__ vhi)
{
    int tid = blockIdx.x * 256 + threadIdx.x;
    int z  = tid >> 20;                 // 2^20 float4 per tensor
    int i4 = tid & ((1 << 20) - 1);
    const float* src = (z == 0) ? q : (z == 1) ? k : v;
    float4 d = ((const float4*)src)[i4];
    short h0 = f2bf(d.x), h1 = f2bf(d.y), h2 = f2bf(d.z), h3 = f2bf(d.w);
    short4 hh = make_short4(h0, h1, h2, h3);
    if (z == 2) { ((short4*)vhi)[i4] = hh; return; }
    short4 ll = make_short4(f2bf(d.x - bf2f(h0)), f2bf(d.y - bf2f(h1)),
                            f2bf(d.z - bf2f(h2)), f2bf(d.w - bf2f(h3)));
    if (z == 0) { ((short4*)qhi)[i4] = hh; ((short4*)qlo)[i4] = ll; }
    else        { ((short4*)khi)[i4] = hh; ((short4*)klo)[i4] = ll; }
}

// ---------------------------------------------------------------------------
// Kernel 0b: W prep — transpose + K-extended split layout.
// z<2: Bx[n][0:512]=hi, [512:1024]=lo, [1024:1536]=hi   (C = Ahi*Bhi + Ahi*Blo + Alo*Bhi)
// z=2: Bv[n][0:512]=hi
// ---------------------------------------------------------------------------
__global__ __launch_bounds__(256) void wprep(
    const float* __restrict__ Wq, const float* __restrict__ Wk,
    const float* __restrict__ Wv,
    short* __restrict__ Bq, short* __restrict__ Bk, short* __restrict__ Bv)
{
    __shared__ float tile[64][65];
    int z = blockIdx.z;
    const float* W = (z == 0) ? Wq : (z == 1) ? Wk : Wv;
    int k0 = blockIdx.x * 64, n0 = blockIdx.y * 64;
    int t = threadIdx.x;
    #pragma unroll
    for (int i = 0; i < 4; ++i) {
        int c = i * 256 + t, row = c >> 4, qq = c & 15;
        float4 d = *(const float4*)(W + (size_t)(k0 + row) * Dc + n0 + qq * 4);
        tile[row][qq * 4 + 0] = d.x; tile[row][qq * 4 + 1] = d.y;
        tile[row][qq * 4 + 2] = d.z; tile[row][qq * 4 + 3] = d.w;
    }
    __syncthreads();
    int n = t >> 2, ks = (t & 3) * 16;
    short hs[16], ls[16];
    #pragma unroll
    for (int j = 0; j < 16; ++j) {
        float x = tile[ks + j][n];
        short h = f2bf(x);
        hs[j] = h;
        ls[j] = f2bf(x - bf2f(h));
    }
    if (z < 2) {
        short* Bx = (z == 0) ? Bq : Bk;
        size_t b = (size_t)(n0 + n) * 1536 + k0 + ks;
        *(uint4*)(Bx + b)            = pack8(hs);
        *(uint4*)(Bx + b + 8)        = pack8(hs + 8);
        *(uint4*)(Bx + b + 512)      = pack8(ls);
        *(uint4*)(Bx + b + 520)      = pack8(ls + 8);
        *(uint4*)(Bx + b + 1024)     = pack8(hs);
        *(uint4*)(Bx + b + 1032)     = pack8(hs + 8);
    } else {
        size_t b = (size_t)(n0 + n) * 512 + k0 + ks;
        *(uint4*)(Bv + b)     = pack8(hs);
        *(uint4*)(Bv + b + 8) = pack8(hs + 8);
    }
}

// ---------------------------------------------------------------------------
// Kernel 1: projection GEMMs, m97 structure.
// 128x128 tile, BK=64, 4 waves (64x64 quadrant each), linear LDS [128][64],
// global_load_lds width-16 staging, mfma_f32_16x16x32_bf16.
// z<2: K=1536 over segments {Ahi,Ahi,Alo} x B_ext rows; z=2: K=512 plain.
// ---------------------------------------------------------------------------
__global__ __launch_bounds__(256) void gemm_mfma(
    const short* __restrict__ qhi, const short* __restrict__ qlo,
    const short* __restrict__ khi, const short* __restrict__ klo,
    const short* __restrict__ vhi,
    const short* __restrict__ Bq, const short* __restrict__ Bk,
    const short* __restrict__ Bv,
    float* __restrict__ qp, float* __restrict__ kp, float* __restrict__ vp)
{
    int z = blockIdx.z;
    const short* Ahi = (z == 0) ? qhi : (z == 1) ? khi : vhi;
    const short* Alo = (z == 0) ? qlo : (z == 1) ? klo : vhi;  // unused for z==2
    const short* Bx  = (z == 0) ? Bq  : (z == 1) ? Bk  : Bv;
    float* O = (z == 0) ? qp : (z == 1) ? kp : vp;
    const int Ktot = (z == 2) ? 512 : 1536;

    __shared__ short As[128 * 64];
    __shared__ short Bs[128 * 64];

    const int t = threadIdx.x;
    const int lane = t & 63, w = t >> 6;
    const int wm = w >> 1, wn = w & 1;
    const int row0 = blockIdx.x * 128, col0 = blockIdx.y * 128;
    const int kg = lane >> 4, fr = lane & 15;
    const int lrow = lane >> 3, lcol = (lane & 7) * 8;   // staging: 8 rows x 128B

    f32x4 acc[4][4];
    #pragma unroll
    for (int i = 0; i < 4; ++i)
        #pragma unroll
        for (int j = 0; j < 4; ++j)
            acc[i][j] = (f32x4){0.f, 0.f, 0.f, 0.f};

    for (int k0 = 0; k0 < Ktot; k0 += 64) {
        int seg = k0 >> 9, ks = k0 & 511;
        const short* Asrc = (seg == 2) ? Alo : Ahi;
        __syncthreads();   // prev iteration's LDS reads done before overwrite
        #pragma unroll
        for (int i = 0; i < 4; ++i) {
            int r = w * 32 + i * 8;
            gld_lds16(Asrc + (size_t)(row0 + r + lrow) * 512 + ks + lcol,
                      &As[r * 64]);
        }
        #pragma unroll
        for (int i = 0; i < 4; ++i) {
            int r = w * 32 + i * 8;
            gld_lds16(Bx + (size_t)(col0 + r + lrow) * Ktot + k0 + lcol,
                      &Bs[r * 64]);
        }
        __syncthreads();   // compiler drains vmcnt before barrier

        #pragma unroll
        for (int kk = 0; kk < 2; ++kk) {
            s16x8 a[4];
            #pragma unroll
            for (int mi = 0; mi < 4; ++mi)
                a[mi] = *(const s16x8*)&As[(wm * 64 + mi * 16 + fr) * 64 + kk * 32 + kg * 8];
            #pragma unroll
            for (int ni = 0; ni < 4; ++ni) {
                s16x8 b = *(const s16x8*)&Bs[(wn * 64 + ni * 16 + fr) * 64 + kk * 32 + kg * 8];
                #pragma unroll
                for (int mi = 0; mi < 4; ++mi)
                    acc[mi][ni] = __builtin_amdgcn_mfma_f32_16x16x32_bf16(a[mi], b, acc[mi][ni], 0, 0, 0);
            }
        }
    }

    // epilogue: C/D layout col=lane&15, row=(lane>>4)*4+reg
    #pragma unroll
    for (int mi = 0; mi < 4; ++mi) {
        #pragma unroll
        for (int ni = 0; ni < 4; ++ni) {
            int row = row0 + wm * 64 + mi * 16 + (lane >> 4) * 4;
            int col = col0 + wn * 64 + ni * 16 + (lane & 15);
            #pragma unroll
            for (int r4 = 0; r4 < 4; ++r4)
                O[(size_t)(row + r4) * Dc + col] = acc[mi][ni][r4];
        }
    }
}

// ---------------------------------------------------------------------------
// Kernel 2: sampled scores -> m[bh, l] = max_s(dot) - sum_s(dot)/L
// One wave per (bh, l); LANE = SAMPLE.
// ---------------------------------------------------------------------------
__global__ __launch_bounds__(256) void compute_m(
    const float* __restrict__ qp, const float* __restrict__ kp,
    const int* __restrict__ ksi, float* __restrict__ m_out)
{
    __shared__ float qsh[4][Ec];
    int w    = threadIdx.x >> 6;
    int lane = threadIdx.x & 63;
    int wid  = blockIdx.x * 4 + w;
    int l  = wid & (Lc - 1);
    int bh = wid >> 11;          // Lc = 2048 = 2^11
    const float* kbase = kp + (size_t)bh * LEc;

    qsh[w][lane] = qp[(size_t)bh * LEc + l * Ec + lane];
    int j = (lane < Sc) ? ksi[l * Sc + lane] : 0;
    __syncthreads();

    float dot = 0.f;
    if (lane < Sc) {
        const float4* krow = (const float4*)(kbase + (size_t)j * Ec);
        const float4* qrow = (const float4*)&qsh[w][0];
        #pragma unroll
        for (int i = 0; i < 16; ++i) {
            float4 kv = krow[i];
            float4 qv = qrow[i];
            dot += kv.x * qv.x + kv.y * qv.y + kv.z * qv.z + kv.w * qv.w;
        }
    }
    float dmax = (lane < Sc) ? dot : -FLT_MAX;
    float dsum = (lane < Sc) ? dot : 0.f;
    #pragma unroll
    for (int o = 1; o < 64; o <<= 1) {
        dmax = fmaxf(dmax, __shfl_xor(dmax, o));
        dsum += __shfl_xor(dsum, o);
    }
    if (lane == 0) m_out[bh * Lc + l] = dmax - dsum * (1.0f / Lc);
}

// ---------------------------------------------------------------------------
// Kernel 3: top-40 indices per (bh). Wave-parallel extract-max.
// Tie -> lower idx (matches jax.lax.top_k).
// ---------------------------------------------------------------------------
__global__ __launch_bounds__(256) void topk40(
    const float* __restrict__ m_in, int* __restrict__ mtop)
{
    __shared__ float vals[Lc];
    __shared__ float wv[4];
    __shared__ int   wi[4];
    int bh = blockIdx.x, t = threadIdx.x;
    int lane = t & 63, w = t >> 6;
    for (int i = t; i < Lc; i += 256) vals[i] = m_in[bh * Lc + i];
    __syncthreads();
    for (int it = 0; it < Uc; ++it) {
        float lv = -FLT_MAX; int li = 0x7fffffff;
        #pragma unroll
        for (int rep = 0; rep < Lc / 256; ++rep) {
            int i = rep * 256 + t;
            float v = vals[i];
            if (v > lv) { lv = v; li = i; }
        }
        #pragma unroll
        for (int o = 1; o < 64; o <<= 1) {
            float ov = __shfl_xor(lv, o);
            int   oi = __shfl_xor(li, o);
            if (ov > lv || (ov == lv && oi < li)) { lv = ov; li = oi; }
        }
        if (lane == 0) { wv[w] = lv; wi[w] = li; }
        __syncthreads();
        if (t == 0) {
            float Bv = wv[0]; int Bi = wi[0];
            #pragma unroll
            for (int j = 1; j < 4; ++j) {
                if (wv[j] > Bv || (wv[j] == Bv && wi[j] < Bi)) { Bv = wv[j]; Bi = wi[j]; }
            }
            mtop[bh * Uc + it] = Bi;
            vals[Bi] = -FLT_MAX;
        }
        __syncthreads();
    }
}

// ---------------------------------------------------------------------------
// Kernels 4-6: chunked inclusive cumsum of vp along l, per (bh, e) column.
// ---------------------------------------------------------------------------
constexpr int CH = 64;  // chunks
constexpr int CR = 32;  // rows per chunk

__global__ __launch_bounds__(64) void cumsum_p1(
    const float* __restrict__ vp, float* __restrict__ psum)
{
    int bid = blockIdx.x;
    int e = threadIdx.x;
    int bh = bid >> 6, ch = bid & 63;
    const float* base = vp + (size_t)bh * LEc + (ch * CR) * Ec + e;
    float s = 0.f;
    #pragma unroll 8
    for (int r = 0; r < CR; ++r) s += base[r * Ec];
    psum[(size_t)bid * Ec + e] = s;
}

__global__ __launch_bounds__(64) void cumsum_p2(float* __restrict__ psum)
{
    int bh = blockIdx.x;
    int e = threadIdx.x;
    float off = 0.f;
    for (int c = 0; c < CH; ++c) {
        size_t idx = (size_t)(bh * CH + c) * Ec + e;
        float tv = psum[idx];
        psum[idx] = off;
        off += tv;
    }
}

__global__ __launch_bounds__(64) void cumsum_p3(
    const float* __restrict__ vp, const float* __restrict__ psum,
    float* __restrict__ out)
{
    int bid = blockIdx.x;
    int e = threadIdx.x;
    int bh = bid >> 6, ch = bid & 63;
    const float* base = vp  + (size_t)bh * LEc + (ch * CR) * Ec + e;
    float*       ob   = out + (size_t)bh * LEc + (ch * CR) * Ec + e;
    float run = psum[(size_t)bid * Ec + e];
    #pragma unroll 8
    for (int r = 0; r < CR; ++r) { run += base[r * Ec]; ob[r * Ec] = run; }
}

// ---------------------------------------------------------------------------
// Kernel 7: flash-style attention update. One block per (bh, u),
// bh = blockIdx.x & 31 so a bh's 40 blocks share one XCD's L2.
// ---------------------------------------------------------------------------
constexpr int TR = 64;   // tile rows

__global__ __launch_bounds__(256) void attn_update(
    const float* __restrict__ qp, const float* __restrict__ kp,
    const float* __restrict__ vp, const int* __restrict__ mtop,
    float* __restrict__ out)
{
    __shared__ float tile[TR][Ec + 1];
    __shared__ float sc[Lc];
    __shared__ float qs[Ec];
    __shared__ float red[256];

    int bh = blockIdx.x & 31, u = blockIdx.x >> 5;
    int t = threadIdx.x;
    int lsel = mtop[bh * Uc + u];
    const float* kb = kp + (size_t)bh * LEc;
    const float* vb = vp + (size_t)bh * LEc;
    if (t < Ec) qs[t] = qp[(size_t)bh * LEc + lsel * Ec + t];

    int ntiles = (lsel + TR) / TR;

    // ---- phase 1: scores ----
    const int r4 = t >> 2;
    const int qd = t & 3;
    float lmax = -FLT_MAX;
    for (int tt = 0; tt < ntiles; ++tt) {
        int l0 = tt * TR;
        __syncthreads();
        #pragma unroll
        for (int i = 0; i < 4; ++i) {
            int f = i * 256 + t;
            int row = f >> 4, cg = f & 15;
            float4 d = *(const float4*)(kb + (size_t)(l0 + row) * Ec + cg * 4);
            tile[row][cg * 4 + 0] = d.x;
            tile[row][cg * 4 + 1] = d.y;
            tile[row][cg * 4 + 2] = d.z;
            tile[row][cg * 4 + 3] = d.w;
        }
        __syncthreads();
        int l = l0 + r4;
        float dot = 0.f;
        #pragma unroll
        for (int i = 0; i < 16; ++i)
            dot = fmaf(tile[r4][qd * 16 + i], qs[qd * 16 + i], dot);
        dot += __shfl_xor(dot, 1);
        dot += __shfl_xor(dot, 2);
        dot *= 0.125f;
        if (l <= lsel) {
            if (qd == 0) sc[l] = dot;
            lmax = fmaxf(lmax, dot);
        }
    }
    red[t] = lmax;
    __syncthreads();
    for (int s = 128; s > 0; s >>= 1) {
        if (t < s) red[t] = fmaxf(red[t], red[t + s]);
        __syncthreads();
    }
    float mx = red[0];
    __syncthreads();

    // ---- phase 2: exp + sum ----
    float lsum = 0.f;
    for (int l = t; l <= lsel; l += 256) {
        float ex = __expf(sc[l] - mx);
        sc[l] = ex;
        lsum += ex;
    }
    red[t] = lsum;
    __syncthreads();
    for (int s = 128; s > 0; s >>= 1) {
        if (t < s) red[t] += red[t + s];
        __syncthreads();
    }
    float inv = 1.0f / red[0];

    // ---- phase 3: PV ----
    int e = t & 63, part = t >> 6;
    float acc = 0.f;
    for (int tt = 0; tt < ntiles; ++tt) {
        int l0 = tt * TR;
        __syncthreads();
        #pragma unroll
        for (int i = 0; i < 4; ++i) {
            int f = i * 256 + t;
            int row = f >> 4, cg = f & 15;
            float4 d = *(const float4*)(vb + (size_t)(l0 + row) * Ec + cg * 4);
            tile[row][cg * 4 + 0] = d.x;
            tile[row][cg * 4 + 1] = d.y;
            tile[row][cg * 4 + 2] = d.z;
            tile[row][cg * 4 + 3] = d.w;
        }
        __syncthreads();
        int rmax = min(TR, lsel + 1 - l0);
        for (int r = part; r < rmax; r += 4)
            acc = fmaf(sc[l0 + r], tile[r][e], acc);
    }
    __syncthreads();
    red[part * Ec + e] = acc;
    __syncthreads();
    if (t < Ec) {
        float c = (red[t] + red[Ec + t] + red[2 * Ec + t] + red[3 * Ec + t]) * inv;
        out[(size_t)bh * LEc + lsel * Ec + t] = c;
    }
}

// ---------------------------------------------------------------------------
extern "C" void kernel_launch(void* const* d_in, const int* in_sizes, int n_in,
                              void* d_out, int out_size, void* d_ws, size_t ws_size,
                              hipStream_t stream)
{
    const float* q   = (const float*)d_in[0];
    const float* k   = (const float*)d_in[1];
    const float* v   = (const float*)d_in[2];
    const float* Wq  = (const float*)d_in[3];
    const float* Wk  = (const float*)d_in[4];
    const float* Wv  = (const float*)d_in[5];
    const int*   ksi = (const int*)d_in[6];
    float* out = (float*)d_out;

    // workspace layout
    float* wsf  = (float*)d_ws;
    float* qp   = wsf;                            // 4,194,304 f
    float* kp   = qp + (size_t)Mrows * Dc;        // 4,194,304 f
    float* vp   = kp + (size_t)Mrows * Dc;        // 4,194,304 f
    float* psum = vp + (size_t)Mrows * Dc;        // 131,072 f
    float* m_ws = psum + (size_t)BHc * CH * Ec;   // 65,536 f
    int*   mtop = (int*)(m_ws + (size_t)BHc * Lc);      // 1,280 i
    short* qhi = (short*)(mtop + BHc * Uc);
    short* qlo = qhi + (size_t)Mrows * Dc;
    short* khi = qlo + (size_t)Mrows * Dc;
    short* klo = khi + (size_t)Mrows * Dc;
    short* vhi = klo + (size_t)Mrows * Dc;
    short* Bq  = vhi + (size_t)Mrows * Dc;        // 512*1536
    short* Bk  = Bq + (size_t)Dc * 1536;          // 512*1536
    short* Bv  = Bk + (size_t)Dc * 1536;          // 512*512

    split_inputs<<<3 * (Mrows * Dc / 4) / 256, 256, 0, stream>>>(
        q, k, v, qhi, qlo, khi, klo, vhi);
    wprep<<<dim3(8, 8, 3), 256, 0, stream>>>(Wq, Wk, Wv, Bq, Bk, Bv);

    dim3 g1(Mrows / 128, Dc / 128, 3);
    gemm_mfma<<<g1, 256, 0, stream>>>(qhi, qlo, khi, klo, vhi, Bq, Bk, Bv,
                                      qp, kp, vp);

    compute_m<<<(BHc * Lc) / 4, 256, 0, stream>>>(qp, kp, ksi, m_ws);

    topk40<<<BHc, 256, 0, stream>>>(m_ws, mtop);

    cumsum_p1<<<BHc * CH, 64, 0, stream>>>(vp, psum);
    cumsum_p2<<<BHc, 64, 0, stream>>>(psum);
    cumsum_p3<<<BHc * CH, 64, 0, stream>>>(vp, psum, out);

    attn_update<<<BHc * Uc, 256, 0, stream>>>(qp, kp, vp, mtop, out);
}

// Round 7
// 266.364 us; speedup vs baseline: 4.8327x; 1.1636x over previous
//
#include <hip/hip_runtime.h>
#include <hip/hip_bf16.h>
#include <float.h>

// Problem constants
constexpr int Bc = 4;
constexpr int Lc = 2048;
constexpr int Dc = 512;
constexpr int Hc = 8;
constexpr int Ec = 64;
constexpr int Sc = 40;   // sample_k
constexpr int Uc = 40;   // u_q (top-k queries)
constexpr int LEc = Lc * Ec;      // 131072
constexpr int BHc = Bc * Hc;      // 32
constexpr int Mrows = Bc * Lc;    // 8192 rows per GEMM

typedef __attribute__((ext_vector_type(8))) short s16x8;
typedef __attribute__((ext_vector_type(4))) float f32x4;
typedef unsigned int u32;

// round-to-nearest-even f32 -> bf16 (bit pattern in a short)
__device__ __forceinline__ short f2bf(float x) {
    unsigned u = __float_as_uint(x);
    unsigned r = (u + 0x7fffu + ((u >> 16) & 1u)) >> 16;
    return (short)r;
}
__device__ __forceinline__ float bf2f(short s) {
    return __uint_as_float(((unsigned)(unsigned short)s) << 16);
}
__device__ __forceinline__ uint4 pack8(const short* s) {
    uint4 r;
    r.x = (unsigned)(unsigned short)s[0] | ((unsigned)(unsigned short)s[1] << 16);
    r.y = (unsigned)(unsigned short)s[2] | ((unsigned)(unsigned short)s[3] << 16);
    r.z = (unsigned)(unsigned short)s[4] | ((unsigned)(unsigned short)s[5] << 16);
    r.w = (unsigned)(unsigned short)s[6] | ((unsigned)(unsigned short)s[7] << 16);
    return r;
}

// direct global->LDS DMA, 16 B per lane (dest = wave-uniform base + lane*16)
__device__ __forceinline__ void gld_lds16(const short* g, short* l) {
    __builtin_amdgcn_global_load_lds(
        (const __attribute__((address_space(1))) u32*)g,
        (__attribute__((address_space(3))) u32*)l, 16, 0, 0);
}

// ---------------------------------------------------------------------------
// Kernel 0a: split q,k -> (hi,lo) bf16; v -> hi bf16.  Pure memory pass.
// ---------------------------------------------------------------------------
__global__ __launch_bounds__(256) void split_inputs(
    const float* __restrict__ q, const float* __restrict__ k, const float* __restrict__ v,
    short* __restrict__ qhi, short* __restrict__ qlo,
    short* __restrict__ khi, short* __restrict__ klo, short* __restrict__ vhi)
{
    int tid = blockIdx.x * 256 + threadIdx.x;
    int z  = tid >> 20;                 // 2^20 float4 per tensor
    int i4 = tid & ((1 << 20) - 1);
    const float* src = (z == 0) ? q : (z == 1) ? k : v;
    float4 d = ((const float4*)src)[i4];
    short h0 = f2bf(d.x), h1 = f2bf(d.y), h2 = f2bf(d.z), h3 = f2bf(d.w);
    short4 hh = make_short4(h0, h1, h2, h3);
    if (z == 2) { ((short4*)vhi)[i4] = hh; return; }
    short4 ll = make_short4(f2bf(d.x - bf2f(h0)), f2bf(d.y - bf2f(h1)),
                            f2bf(d.z - bf2f(h2)), f2bf(d.w - bf2f(h3)));
    if (z == 0) { ((short4*)qhi)[i4] = hh; ((short4*)qlo)[i4] = ll; }
    else        { ((short4*)khi)[i4] = hh; ((short4*)klo)[i4] = ll; }
}

// ---------------------------------------------------------------------------
// Kernel 0b: W prep — transpose + K-extended split layout.
// z<2: Bx[n][0:512]=hi, [512:1024]=lo, [1024:1536]=hi
// z=2: Bv[n][0:512]=hi
// ---------------------------------------------------------------------------
__global__ __launch_bounds__(256) void wprep(
    const float* __restrict__ Wq, const float* __restrict__ Wk,
    const float* __restrict__ Wv,
    short* __restrict__ Bq, short* __restrict__ Bk, short* __restrict__ Bv)
{
    __shared__ float tile[64][65];
    int z = blockIdx.z;
    const float* W = (z == 0) ? Wq : (z == 1) ? Wk : Wv;
    int k0 = blockIdx.x * 64, n0 = blockIdx.y * 64;
    int t = threadIdx.x;
    #pragma unroll
    for (int i = 0; i < 4; ++i) {
        int c = i * 256 + t, row = c >> 4, qq = c & 15;
        float4 d = *(const float4*)(W + (size_t)(k0 + row) * Dc + n0 + qq * 4);
        tile[row][qq * 4 + 0] = d.x; tile[row][qq * 4 + 1] = d.y;
        tile[row][qq * 4 + 2] = d.z; tile[row][qq * 4 + 3] = d.w;
    }
    __syncthreads();
    int n = t >> 2, ks = (t & 3) * 16;
    short hs[16], ls[16];
    #pragma unroll
    for (int j = 0; j < 16; ++j) {
        float x = tile[ks + j][n];
        short h = f2bf(x);
        hs[j] = h;
        ls[j] = f2bf(x - bf2f(h));
    }
    if (z < 2) {
        short* Bx = (z == 0) ? Bq : Bk;
        size_t b = (size_t)(n0 + n) * 1536 + k0 + ks;
        *(uint4*)(Bx + b)            = pack8(hs);
        *(uint4*)(Bx + b + 8)        = pack8(hs + 8);
        *(uint4*)(Bx + b + 512)      = pack8(ls);
        *(uint4*)(Bx + b + 520)      = pack8(ls + 8);
        *(uint4*)(Bx + b + 1024)     = pack8(hs);
        *(uint4*)(Bx + b + 1032)     = pack8(hs + 8);
    } else {
        size_t b = (size_t)(n0 + n) * 512 + k0 + ks;
        *(uint4*)(Bv + b)     = pack8(hs);
        *(uint4*)(Bv + b + 8) = pack8(hs + 8);
    }
}

// ---------------------------------------------------------------------------
// Kernel 1: projection GEMMs, m97 structure (global_load_lds staging).
// ---------------------------------------------------------------------------
__global__ __launch_bounds__(256) void gemm_mfma(
    const short* __restrict__ qhi, const short* __restrict__ qlo,
    const short* __restrict__ khi, const short* __restrict__ klo,
    const short* __restrict__ vhi,
    const short* __restrict__ Bq, const short* __restrict__ Bk,
    const short* __restrict__ Bv,
    float* __restrict__ qp, float* __restrict__ kp, float* __restrict__ vp)
{
    int z = blockIdx.z;
    const short* Ahi = (z == 0) ? qhi : (z == 1) ? khi : vhi;
    const short* Alo = (z == 0) ? qlo : (z == 1) ? klo : vhi;  // unused for z==2
    const short* Bx  = (z == 0) ? Bq  : (z == 1) ? Bk  : Bv;
    float* O = (z == 0) ? qp : (z == 1) ? kp : vp;
    const int Ktot = (z == 2) ? 512 : 1536;

    __shared__ short As[128 * 64];
    __shared__ short Bs[128 * 64];

    const int t = threadIdx.x;
    const int lane = t & 63, w = t >> 6;
    const int wm = w >> 1, wn = w & 1;
    const int row0 = blockIdx.x * 128, col0 = blockIdx.y * 128;
    const int kg = lane >> 4, fr = lane & 15;
    const int lrow = lane >> 3, lcol = (lane & 7) * 8;   // staging: 8 rows x 128B

    f32x4 acc[4][4];
    #pragma unroll
    for (int i = 0; i < 4; ++i)
        #pragma unroll
        for (int j = 0; j < 4; ++j)
            acc[i][j] = (f32x4){0.f, 0.f, 0.f, 0.f};

    for (int k0 = 0; k0 < Ktot; k0 += 64) {
        int seg = k0 >> 9, ks = k0 & 511;
        const short* Asrc = (seg == 2) ? Alo : Ahi;
        __syncthreads();
        #pragma unroll
        for (int i = 0; i < 4; ++i) {
            int r = w * 32 + i * 8;
            gld_lds16(Asrc + (size_t)(row0 + r + lrow) * 512 + ks + lcol,
                      &As[r * 64]);
        }
        #pragma unroll
        for (int i = 0; i < 4; ++i) {
            int r = w * 32 + i * 8;
            gld_lds16(Bx + (size_t)(col0 + r + lrow) * Ktot + k0 + lcol,
                      &Bs[r * 64]);
        }
        __syncthreads();

        #pragma unroll
        for (int kk = 0; kk < 2; ++kk) {
            s16x8 a[4];
            #pragma unroll
            for (int mi = 0; mi < 4; ++mi)
                a[mi] = *(const s16x8*)&As[(wm * 64 + mi * 16 + fr) * 64 + kk * 32 + kg * 8];
            #pragma unroll
            for (int ni = 0; ni < 4; ++ni) {
                s16x8 b = *(const s16x8*)&Bs[(wn * 64 + ni * 16 + fr) * 64 + kk * 32 + kg * 8];
                #pragma unroll
                for (int mi = 0; mi < 4; ++mi)
                    acc[mi][ni] = __builtin_amdgcn_mfma_f32_16x16x32_bf16(a[mi], b, acc[mi][ni], 0, 0, 0);
            }
        }
    }

    #pragma unroll
    for (int mi = 0; mi < 4; ++mi) {
        #pragma unroll
        for (int ni = 0; ni < 4; ++ni) {
            int row = row0 + wm * 64 + mi * 16 + (lane >> 4) * 4;
            int col = col0 + wn * 64 + ni * 16 + (lane & 15);
            #pragma unroll
            for (int r4 = 0; r4 < 4; ++r4)
                O[(size_t)(row + r4) * Dc + col] = acc[mi][ni][r4];
        }
    }
}

// ---------------------------------------------------------------------------
// Kernel 2: sampled scores -> m[bh, l] = max_s(dot) - sum_s(dot)/L
// One wave per (bh, l); LANE = SAMPLE.
// ---------------------------------------------------------------------------
__global__ __launch_bounds__(256) void compute_m(
    const float* __restrict__ qp, const float* __restrict__ kp,
    const int* __restrict__ ksi, float* __restrict__ m_out)
{
    __shared__ float qsh[4][Ec];
    int w    = threadIdx.x >> 6;
    int lane = threadIdx.x & 63;
    int wid  = blockIdx.x * 4 + w;
    int l  = wid & (Lc - 1);
    int bh = wid >> 11;          // Lc = 2048 = 2^11
    const float* kbase = kp + (size_t)bh * LEc;

    qsh[w][lane] = qp[(size_t)bh * LEc + l * Ec + lane];
    int j = (lane < Sc) ? ksi[l * Sc + lane] : 0;
    __syncthreads();

    float dot = 0.f;
    if (lane < Sc) {
        const float4* krow = (const float4*)(kbase + (size_t)j * Ec);
        const float4* qrow = (const float4*)&qsh[w][0];
        #pragma unroll
        for (int i = 0; i < 16; ++i) {
            float4 kv = krow[i];
            float4 qv = qrow[i];
            dot += kv.x * qv.x + kv.y * qv.y + kv.z * qv.z + kv.w * qv.w;
        }
    }
    float dmax = (lane < Sc) ? dot : -FLT_MAX;
    float dsum = (lane < Sc) ? dot : 0.f;
    #pragma unroll
    for (int o = 1; o < 64; o <<= 1) {
        dmax = fmaxf(dmax, __shfl_xor(dmax, o));
        dsum += __shfl_xor(dsum, o);
    }
    if (lane == 0) m_out[bh * Lc + l] = dmax - dsum * (1.0f / Lc);
}

// ---------------------------------------------------------------------------
// Kernel 3: top-40 indices per (bh). Wave-parallel extract-max.
// Tie -> lower idx (matches jax.lax.top_k).
// ---------------------------------------------------------------------------
__global__ __launch_bounds__(256) void topk40(
    const float* __restrict__ m_in, int* __restrict__ mtop)
{
    __shared__ float vals[Lc];
    __shared__ float wv[4];
    __shared__ int   wi[4];
    int bh = blockIdx.x, t = threadIdx.x;
    int lane = t & 63, w = t >> 6;
    for (int i = t; i < Lc; i += 256) vals[i] = m_in[bh * Lc + i];
    __syncthreads();
    for (int it = 0; it < Uc; ++it) {
        float lv = -FLT_MAX; int li = 0x7fffffff;
        #pragma unroll
        for (int rep = 0; rep < Lc / 256; ++rep) {
            int i = rep * 256 + t;
            float v = vals[i];
            if (v > lv) { lv = v; li = i; }
        }
        #pragma unroll
        for (int o = 1; o < 64; o <<= 1) {
            float ov = __shfl_xor(lv, o);
            int   oi = __shfl_xor(li, o);
            if (ov > lv || (ov == lv && oi < li)) { lv = ov; li = oi; }
        }
        if (lane == 0) { wv[w] = lv; wi[w] = li; }
        __syncthreads();
        if (t == 0) {
            float Bv = wv[0]; int Bi = wi[0];
            #pragma unroll
            for (int j = 1; j < 4; ++j) {
                if (wv[j] > Bv || (wv[j] == Bv && wi[j] < Bi)) { Bv = wv[j]; Bi = wi[j]; }
            }
            mtop[bh * Uc + it] = Bi;
            vals[Bi] = -FLT_MAX;
        }
        __syncthreads();
    }
}

// ---------------------------------------------------------------------------
// Kernels 4-6: chunked inclusive cumsum of vp along l, per (bh, e) column.
// ---------------------------------------------------------------------------
constexpr int CH = 64;  // chunks
constexpr int CR = 32;  // rows per chunk

__global__ __launch_bounds__(64) void cumsum_p1(
    const float* __restrict__ vp, float* __restrict__ psum)
{
    int bid = blockIdx.x;
    int e = threadIdx.x;
    int bh = bid >> 6, ch = bid & 63;
    const float* base = vp + (size_t)bh * LEc + (ch * CR) * Ec + e;
    float s = 0.f;
    #pragma unroll 8
    for (int r = 0; r < CR; ++r) s += base[r * Ec];
    psum[(size_t)bid * Ec + e] = s;
}

__global__ __launch_bounds__(64) void cumsum_p2(float* __restrict__ psum)
{
    int bh = blockIdx.x;
    int e = threadIdx.x;
    float off = 0.f;
    for (int c = 0; c < CH; ++c) {
        size_t idx = (size_t)(bh * CH + c) * Ec + e;
        float tv = psum[idx];
        psum[idx] = off;
        off += tv;
    }
}

__global__ __launch_bounds__(64) void cumsum_p3(
    const float* __restrict__ vp, const float* __restrict__ psum,
    float* __restrict__ out)
{
    int bid = blockIdx.x;
    int e = threadIdx.x;
    int bh = bid >> 6, ch = bid & 63;
    const float* base = vp  + (size_t)bh * LEc + (ch * CR) * Ec + e;
    float*       ob   = out + (size_t)bh * LEc + (ch * CR) * Ec + e;
    float run = psum[(size_t)bid * Ec + e];
    #pragma unroll 8
    for (int r = 0; r < CR; ++r) { run += base[r * Ec]; ob[r * Ec] = run; }
}

// ---------------------------------------------------------------------------
// Kernel 7a: chunked flash attention partials with u-reuse.
// grid = (bh, chunk of 128 rows) = 32*16 blocks, 512 threads (8 waves).
// Each block stages its K/V chunk ONCE and serves all 40 u's (5 per wave).
// Scores: lane=row, K-row in regs, q via LDS broadcast. PV: lane=e,
// V value reused across the wave's 5 u's. Online-softmax partial
// (m, l, acc[64]) per (chunk, u), combined by kernel 7b.
// ---------------------------------------------------------------------------
constexpr int ACH = 16;     // attn chunks
constexpr int AROWS = 128;  // rows per chunk

__global__ __launch_bounds__(512) void attn_partial(
    const float* __restrict__ qp, const float* __restrict__ kp,
    const float* __restrict__ vp, const int* __restrict__ mtop,
    float* __restrict__ pm, float* __restrict__ pl, float* __restrict__ pacc)
{
    __shared__ float Kt[64][68];     // stride 68: float4-aligned rows
    __shared__ float Vt[64][68];
    __shared__ float qsh[40][64];
    __shared__ float p_lds[64][45];  // stride 45: odd -> 2-way banks on col writes
    __shared__ int   lsel_sh[40];

    int bh = blockIdx.x & 31, ch = blockIdx.x >> 5;
    int t = threadIdx.x, w = t >> 6, lane = t & 63;
    const float* kb = kp + (size_t)bh * LEc;
    const float* vb = vp + (size_t)bh * LEc;

    if (t < Uc) lsel_sh[t] = mtop[bh * Uc + t];
    __syncthreads();
    for (int i = t; i < Uc * Ec; i += 512) {
        int u = i >> 6, e = i & 63;
        qsh[u][e] = qp[(size_t)bh * LEc + lsel_sh[u] * Ec + e];
    }
    // qsh visible to all after the staging barrier below

    const int u0 = w * 5;
    float acc[5]  = {0.f, 0.f, 0.f, 0.f, 0.f};
    float lreg[5] = {0.f, 0.f, 0.f, 0.f, 0.f};
    float mreg[5];
    #pragma unroll
    for (int j = 0; j < 5; ++j) mreg[j] = -FLT_MAX;

    for (int tt = 0; tt < AROWS / 64; ++tt) {
        int l0 = ch * AROWS + tt * 64;
        __syncthreads();   // prev-tile reads done (and qsh written, first iter)
        #pragma unroll
        for (int i = 0; i < 2; ++i) {
            int f = i * 512 + t, row = f >> 4, cg = f & 15;
            *(float4*)&Kt[row][cg * 4] = *(const float4*)(kb + (size_t)(l0 + row) * Ec + cg * 4);
            *(float4*)&Vt[row][cg * 4] = *(const float4*)(vb + (size_t)(l0 + row) * Ec + cg * 4);
        }
        __syncthreads();

        int gl = l0 + lane;
        float4 kr[16];
        #pragma unroll
        for (int i = 0; i < 16; ++i) kr[i] = *(const float4*)&Kt[lane][i * 4];

        bool act[5];
        #pragma unroll
        for (int j = 0; j < 5; ++j) {
            int u = u0 + j, ls = lsel_sh[u];
            act[j] = (l0 <= ls);            // wave-uniform
            if (!act[j]) continue;
            float s = -FLT_MAX;
            if (gl <= ls) {
                float dot = 0.f;
                #pragma unroll
                for (int i = 0; i < 16; ++i) {
                    float4 qv = *(const float4*)&qsh[u][i * 4];   // broadcast
                    dot += kr[i].x * qv.x + kr[i].y * qv.y + kr[i].z * qv.z + kr[i].w * qv.w;
                }
                s = dot * 0.125f;   // 1/sqrt(64)
            }
            float tmax = s;
            #pragma unroll
            for (int o = 1; o < 64; o <<= 1) tmax = fmaxf(tmax, __shfl_xor(tmax, o));
            float m_new = fmaxf(mreg[j], tmax);
            float p = (gl <= ls) ? __expf(s - m_new) : 0.f;
            p_lds[lane][u] = p;
            float ps = p;
            #pragma unroll
            for (int o = 1; o < 64; o <<= 1) ps += __shfl_xor(ps, o);
            float coef = __expf(mreg[j] - m_new);   // exp(0)=1 when unchanged
            lreg[j] = lreg[j] * coef + ps;
            acc[j] *= coef;
            mreg[j] = m_new;
        }

        // PV: lane = e. p_lds written by this wave only (own u columns);
        // compiler orders the within-wave LDS write->read via lgkmcnt.
        for (int row = 0; row < 64; ++row) {
            float vv = Vt[row][lane];
            #pragma unroll
            for (int j = 0; j < 5; ++j)
                if (act[j]) acc[j] = fmaf(p_lds[row][u0 + j], vv, acc[j]);
        }
    }

    #pragma unroll
    for (int j = 0; j < 5; ++j) {
        size_t idx = ((size_t)bh * ACH + ch) * Uc + u0 + j;
        if (lane == 0) { pm[idx] = mreg[j]; pl[idx] = lreg[j]; }
        pacc[idx * Ec + lane] = acc[j];
    }
}

// ---------------------------------------------------------------------------
// Kernel 7b: combine the 16 chunk-partials per (bh, u); write out row.
// One wave per (bh, u); lane = e.
// ---------------------------------------------------------------------------
__global__ __launch_bounds__(256) void attn_combine(
    const float* __restrict__ pm, const float* __restrict__ pl,
    const float* __restrict__ pacc, const int* __restrict__ mtop,
    float* __restrict__ out)
{
    int wid = blockIdx.x * 4 + (threadIdx.x >> 6);
    int lane = threadIdx.x & 63;
    int bh = wid / Uc, u = wid % Uc;
    float m = -FLT_MAX;
    for (int i = 0; i < ACH; ++i)
        m = fmaxf(m, pm[((size_t)bh * ACH + i) * Uc + u]);
    float l = 0.f, a = 0.f;
    for (int i = 0; i < ACH; ++i) {
        size_t idx = ((size_t)bh * ACH + i) * Uc + u;
        float wgt = __expf(pm[idx] - m);   // exp(-inf)=0 for empty chunks
        l += wgt * pl[idx];
        a += wgt * pacc[idx * Ec + lane];
    }
    int lsel = mtop[bh * Uc + u];
    out[(size_t)bh * LEc + lsel * Ec + lane] = a / l;
}

// ---------------------------------------------------------------------------
extern "C" void kernel_launch(void* const* d_in, const int* in_sizes, int n_in,
                              void* d_out, int out_size, void* d_ws, size_t ws_size,
                              hipStream_t stream)
{
    const float* q   = (const float*)d_in[0];
    const float* k   = (const float*)d_in[1];
    const float* v   = (const float*)d_in[2];
    const float* Wq  = (const float*)d_in[3];
    const float* Wk  = (const float*)d_in[4];
    const float* Wv  = (const float*)d_in[5];
    const int*   ksi = (const int*)d_in[6];
    float* out = (float*)d_out;

    // workspace layout
    float* wsf  = (float*)d_ws;
    float* qp   = wsf;                            // 4,194,304 f
    float* kp   = qp + (size_t)Mrows * Dc;        // 4,194,304 f
    float* vp   = kp + (size_t)Mrows * Dc;        // 4,194,304 f
    float* psum = vp + (size_t)Mrows * Dc;        // 131,072 f
    float* m_ws = psum + (size_t)BHc * CH * Ec;   // 65,536 f
    int*   mtop = (int*)(m_ws + (size_t)BHc * Lc);      // 1,280 i
    short* qhi = (short*)(mtop + BHc * Uc);
    short* qlo = qhi + (size_t)Mrows * Dc;
    short* khi = qlo + (size_t)Mrows * Dc;
    short* klo = khi + (size_t)Mrows * Dc;
    short* vhi = klo + (size_t)Mrows * Dc;
    short* Bq  = vhi + (size_t)Mrows * Dc;        // 512*1536
    short* Bk  = Bq + (size_t)Dc * 1536;          // 512*1536
    short* Bv  = Bk + (size_t)Dc * 1536;          // 512*512
    float* pm  = (float*)(Bv + (size_t)Dc * 512); // 32*16*40
    float* pl  = pm + (size_t)BHc * ACH * Uc;     // 32*16*40
    float* pacc = pl + (size_t)BHc * ACH * Uc;    // 32*16*40*64

    split_inputs<<<3 * (Mrows * Dc / 4) / 256, 256, 0, stream>>>(
        q, k, v, qhi, qlo, khi, klo, vhi);
    wprep<<<dim3(8, 8, 3), 256, 0, stream>>>(Wq, Wk, Wv, Bq, Bk, Bv);

    dim3 g1(Mrows / 128, Dc / 128, 3);
    gemm_mfma<<<g1, 256, 0, stream>>>(qhi, qlo, khi, klo, vhi, Bq, Bk, Bv,
                                      qp, kp, vp);

    compute_m<<<(BHc * Lc) / 4, 256, 0, stream>>>(qp, kp, ksi, m_ws);

    topk40<<<BHc, 256, 0, stream>>>(m_ws, mtop);

    attn_partial<<<BHc * ACH, 512, 0, stream>>>(qp, kp, vp, mtop, pm, pl, pacc);

    cumsum_p1<<<BHc * CH, 64, 0, stream>>>(vp, psum);
    cumsum_p2<<<BHc, 64, 0, stream>>>(psum);
    cumsum_p3<<<BHc * CH, 64, 0, stream>>>(vp, psum, out);

    attn_combine<<<BHc * Uc / 4, 256, 0, stream>>>(pm, pl, pacc, mtop, out);
}

// Round 8
// 261.741 us; speedup vs baseline: 4.9181x; 1.0177x over previous
//
#include <hip/hip_runtime.h>
#include <hip/hip_bf16.h>
#include <float.h>

// Problem constants
constexpr int Bc = 4;
constexpr int Lc = 2048;
constexpr int Dc = 512;
constexpr int Hc = 8;
constexpr int Ec = 64;
constexpr int Sc = 40;   // sample_k
constexpr int Uc = 40;   // u_q (top-k queries)
constexpr int LEc = Lc * Ec;      // 131072
constexpr int BHc = Bc * Hc;      // 32
constexpr int Mrows = Bc * Lc;    // 8192 rows per GEMM

typedef __attribute__((ext_vector_type(8))) short s16x8;
typedef __attribute__((ext_vector_type(4))) float f32x4;
typedef unsigned int u32;

// round-to-nearest-even f32 -> bf16 (bit pattern in a short)
__device__ __forceinline__ short f2bf(float x) {
    unsigned u = __float_as_uint(x);
    unsigned r = (u + 0x7fffu + ((u >> 16) & 1u)) >> 16;
    return (short)r;
}
__device__ __forceinline__ float bf2f(short s) {
    return __uint_as_float(((unsigned)(unsigned short)s) << 16);
}
__device__ __forceinline__ uint4 pack8(const short* s) {
    uint4 r;
    r.x = (unsigned)(unsigned short)s[0] | ((unsigned)(unsigned short)s[1] << 16);
    r.y = (unsigned)(unsigned short)s[2] | ((unsigned)(unsigned short)s[3] << 16);
    r.z = (unsigned)(unsigned short)s[4] | ((unsigned)(unsigned short)s[5] << 16);
    r.w = (unsigned)(unsigned short)s[6] | ((unsigned)(unsigned short)s[7] << 16);
    return r;
}

// direct global->LDS DMA, 16 B per lane (dest = wave-uniform base + lane*16)
__device__ __forceinline__ void gld_lds16(const short* g, short* l) {
    __builtin_amdgcn_global_load_lds(
        (const __attribute__((address_space(1))) u32*)g,
        (__attribute__((address_space(3))) u32*)l, 16, 0, 0);
}

// ---------------------------------------------------------------------------
// Kernel 0a: split q,k -> (hi,lo) bf16; v -> hi bf16.  Pure memory pass.
// ---------------------------------------------------------------------------
__global__ __launch_bounds__(256) void split_inputs(
    const float* __restrict__ q, const float* __restrict__ k, const float* __restrict__ v,
    short* __restrict__ qhi, short* __restrict__ qlo,
    short* __restrict__ khi, short* __restrict__ klo, short* __restrict__ vhi)
{
    int tid = blockIdx.x * 256 + threadIdx.x;
    int z  = tid >> 20;                 // 2^20 float4 per tensor
    int i4 = tid & ((1 << 20) - 1);
    const float* src = (z == 0) ? q : (z == 1) ? k : v;
    float4 d = ((const float4*)src)[i4];
    short h0 = f2bf(d.x), h1 = f2bf(d.y), h2 = f2bf(d.z), h3 = f2bf(d.w);
    short4 hh = make_short4(h0, h1, h2, h3);
    if (z == 2) { ((short4*)vhi)[i4] = hh; return; }
    short4 ll = make_short4(f2bf(d.x - bf2f(h0)), f2bf(d.y - bf2f(h1)),
                            f2bf(d.z - bf2f(h2)), f2bf(d.w - bf2f(h3)));
    if (z == 0) { ((short4*)qhi)[i4] = hh; ((short4*)qlo)[i4] = ll; }
    else        { ((short4*)khi)[i4] = hh; ((short4*)klo)[i4] = ll; }
}

// ---------------------------------------------------------------------------
// Kernel 0b: W prep — transpose + K-extended split layout.
// z<2: Bx[n][0:512]=hi, [512:1024]=lo, [1024:1536]=hi
// z=2: Bv[n][0:512]=hi
// ---------------------------------------------------------------------------
__global__ __launch_bounds__(256) void wprep(
    const float* __restrict__ Wq, const float* __restrict__ Wk,
    const float* __restrict__ Wv,
    short* __restrict__ Bq, short* __restrict__ Bk, short* __restrict__ Bv)
{
    __shared__ float tile[64][65];
    int z = blockIdx.z;
    const float* W = (z == 0) ? Wq : (z == 1) ? Wk : Wv;
    int k0 = blockIdx.x * 64, n0 = blockIdx.y * 64;
    int t = threadIdx.x;
    #pragma unroll
    for (int i = 0; i < 4; ++i) {
        int c = i * 256 + t, row = c >> 4, qq = c & 15;
        float4 d = *(const float4*)(W + (size_t)(k0 + row) * Dc + n0 + qq * 4);
        tile[row][qq * 4 + 0] = d.x; tile[row][qq * 4 + 1] = d.y;
        tile[row][qq * 4 + 2] = d.z; tile[row][qq * 4 + 3] = d.w;
    }
    __syncthreads();
    int n = t >> 2, ks = (t & 3) * 16;
    short hs[16], ls[16];
    #pragma unroll
    for (int j = 0; j < 16; ++j) {
        float x = tile[ks + j][n];
        short h = f2bf(x);
        hs[j] = h;
        ls[j] = f2bf(x - bf2f(h));
    }
    if (z < 2) {
        short* Bx = (z == 0) ? Bq : Bk;
        size_t b = (size_t)(n0 + n) * 1536 + k0 + ks;
        *(uint4*)(Bx + b)            = pack8(hs);
        *(uint4*)(Bx + b + 8)        = pack8(hs + 8);
        *(uint4*)(Bx + b + 512)      = pack8(ls);
        *(uint4*)(Bx + b + 520)      = pack8(ls + 8);
        *(uint4*)(Bx + b + 1024)     = pack8(hs);
        *(uint4*)(Bx + b + 1032)     = pack8(hs + 8);
    } else {
        size_t b = (size_t)(n0 + n) * 512 + k0 + ks;
        *(uint4*)(Bv + b)     = pack8(hs);
        *(uint4*)(Bv + b + 8) = pack8(hs + 8);
    }
}

// ---------------------------------------------------------------------------
// Kernel 1: projection GEMMs, m97 structure (global_load_lds staging).
// ---------------------------------------------------------------------------
__global__ __launch_bounds__(256) void gemm_mfma(
    const short* __restrict__ qhi, const short* __restrict__ qlo,
    const short* __restrict__ khi, const short* __restrict__ klo,
    const short* __restrict__ vhi,
    const short* __restrict__ Bq, const short* __restrict__ Bk,
    const short* __restrict__ Bv,
    float* __restrict__ qp, float* __restrict__ kp, float* __restrict__ vp)
{
    int z = blockIdx.z;
    const short* Ahi = (z == 0) ? qhi : (z == 1) ? khi : vhi;
    const short* Alo = (z == 0) ? qlo : (z == 1) ? klo : vhi;  // unused for z==2
    const short* Bx  = (z == 0) ? Bq  : (z == 1) ? Bk  : Bv;
    float* O = (z == 0) ? qp : (z == 1) ? kp : vp;
    const int Ktot = (z == 2) ? 512 : 1536;

    __shared__ short As[128 * 64];
    __shared__ short Bs[128 * 64];

    const int t = threadIdx.x;
    const int lane = t & 63, w = t >> 6;
    const int wm = w >> 1, wn = w & 1;
    const int row0 = blockIdx.x * 128, col0 = blockIdx.y * 128;
    const int kg = lane >> 4, fr = lane & 15;
    const int lrow = lane >> 3, lcol = (lane & 7) * 8;   // staging: 8 rows x 128B

    f32x4 acc[4][4];
    #pragma unroll
    for (int i = 0; i < 4; ++i)
        #pragma unroll
        for (int j = 0; j < 4; ++j)
            acc[i][j] = (f32x4){0.f, 0.f, 0.f, 0.f};

    for (int k0 = 0; k0 < Ktot; k0 += 64) {
        int seg = k0 >> 9, ks = k0 & 511;
        const short* Asrc = (seg == 2) ? Alo : Ahi;
        __syncthreads();
        #pragma unroll
        for (int i = 0; i < 4; ++i) {
            int r = w * 32 + i * 8;
            gld_lds16(Asrc + (size_t)(row0 + r + lrow) * 512 + ks + lcol,
                      &As[r * 64]);
        }
        #pragma unroll
        for (int i = 0; i < 4; ++i) {
            int r = w * 32 + i * 8;
            gld_lds16(Bx + (size_t)(col0 + r + lrow) * Ktot + k0 + lcol,
                      &Bs[r * 64]);
        }
        __syncthreads();

        #pragma unroll
        for (int kk = 0; kk < 2; ++kk) {
            s16x8 a[4];
            #pragma unroll
            for (int mi = 0; mi < 4; ++mi)
                a[mi] = *(const s16x8*)&As[(wm * 64 + mi * 16 + fr) * 64 + kk * 32 + kg * 8];
            #pragma unroll
            for (int ni = 0; ni < 4; ++ni) {
                s16x8 b = *(const s16x8*)&Bs[(wn * 64 + ni * 16 + fr) * 64 + kk * 32 + kg * 8];
                #pragma unroll
                for (int mi = 0; mi < 4; ++mi)
                    acc[mi][ni] = __builtin_amdgcn_mfma_f32_16x16x32_bf16(a[mi], b, acc[mi][ni], 0, 0, 0);
            }
        }
    }

    #pragma unroll
    for (int mi = 0; mi < 4; ++mi) {
        #pragma unroll
        for (int ni = 0; ni < 4; ++ni) {
            int row = row0 + wm * 64 + mi * 16 + (lane >> 4) * 4;
            int col = col0 + wn * 64 + ni * 16 + (lane & 15);
            #pragma unroll
            for (int r4 = 0; r4 < 4; ++r4)
                O[(size_t)(row + r4) * Dc + col] = acc[mi][ni][r4];
        }
    }
}

// ---------------------------------------------------------------------------
// Kernel 2: sampled scores -> m[bh, l] = max_s(dot) - sum_s(dot)/L
// One wave per (bh, l); LANE = SAMPLE.
// XCD-aware swizzle: xcd = blockIdx&7 owns bh = xcd*4 + (blockIdx>>3)/512,
// so each XCD's gather working set (4 x 512 KB kp slices) fits its 4MB L2.
// ---------------------------------------------------------------------------
__global__ __launch_bounds__(256) void compute_m(
    const float* __restrict__ qp, const float* __restrict__ kp,
    const int* __restrict__ ksi, float* __restrict__ m_out)
{
    __shared__ float qsh[4][Ec];
    int w    = threadIdx.x >> 6;
    int lane = threadIdx.x & 63;
    int xcd  = blockIdx.x & 7;
    int i    = blockIdx.x >> 3;            // 0..2047
    int bh   = (xcd << 2) | (i >> 9);      // 4 bh per XCD
    int l    = (i & 511) * 4 + w;
    const float* kbase = kp + (size_t)bh * LEc;

    qsh[w][lane] = qp[(size_t)bh * LEc + l * Ec + lane];
    int j = (lane < Sc) ? ksi[l * Sc + lane] : 0;
    __syncthreads();

    float dot = 0.f;
    if (lane < Sc) {
        const float4* krow = (const float4*)(kbase + (size_t)j * Ec);
        const float4* qrow = (const float4*)&qsh[w][0];
        #pragma unroll
        for (int i2 = 0; i2 < 16; ++i2) {
            float4 kv = krow[i2];
            float4 qv = qrow[i2];
            dot += kv.x * qv.x + kv.y * qv.y + kv.z * qv.z + kv.w * qv.w;
        }
    }
    float dmax = (lane < Sc) ? dot : -FLT_MAX;
    float dsum = (lane < Sc) ? dot : 0.f;
    #pragma unroll
    for (int o = 1; o < 64; o <<= 1) {
        dmax = fmaxf(dmax, __shfl_xor(dmax, o));
        dsum += __shfl_xor(dsum, o);
    }
    if (lane == 0) m_out[bh * Lc + l] = dmax - dsum * (1.0f / Lc);
}

// ---------------------------------------------------------------------------
// Kernel 3: top-40 indices per (bh). Wave-parallel extract-max.
// Tie -> lower idx (matches jax.lax.top_k).
// ---------------------------------------------------------------------------
__global__ __launch_bounds__(256) void topk40(
    const float* __restrict__ m_in, int* __restrict__ mtop)
{
    __shared__ float vals[Lc];
    __shared__ float wv[4];
    __shared__ int   wi[4];
    int bh = blockIdx.x, t = threadIdx.x;
    int lane = t & 63, w = t >> 6;
    for (int i = t; i < Lc; i += 256) vals[i] = m_in[bh * Lc + i];
    __syncthreads();
    for (int it = 0; it < Uc; ++it) {
        float lv = -FLT_MAX; int li = 0x7fffffff;
        #pragma unroll
        for (int rep = 0; rep < Lc / 256; ++rep) {
            int i = rep * 256 + t;
            float v = vals[i];
            if (v > lv) { lv = v; li = i; }
        }
        #pragma unroll
        for (int o = 1; o < 64; o <<= 1) {
            float ov = __shfl_xor(lv, o);
            int   oi = __shfl_xor(li, o);
            if (ov > lv || (ov == lv && oi < li)) { lv = ov; li = oi; }
        }
        if (lane == 0) { wv[w] = lv; wi[w] = li; }
        __syncthreads();
        if (t == 0) {
            float Bv = wv[0]; int Bi = wi[0];
            #pragma unroll
            for (int j = 1; j < 4; ++j) {
                if (wv[j] > Bv || (wv[j] == Bv && wi[j] < Bi)) { Bv = wv[j]; Bi = wi[j]; }
            }
            mtop[bh * Uc + it] = Bi;
            vals[Bi] = -FLT_MAX;
        }
        __syncthreads();
    }
}

// ---------------------------------------------------------------------------
// Kernels 4-6: chunked inclusive cumsum of vp along l, per (bh, e) column.
// ---------------------------------------------------------------------------
constexpr int CH = 64;  // chunks
constexpr int CR = 32;  // rows per chunk

__global__ __launch_bounds__(64) void cumsum_p1(
    const float* __restrict__ vp, float* __restrict__ psum)
{
    int bid = blockIdx.x;
    int e = threadIdx.x;
    int bh = bid >> 6, ch = bid & 63;
    const float* base = vp + (size_t)bh * LEc + (ch * CR) * Ec + e;
    float s = 0.f;
    #pragma unroll 8
    for (int r = 0; r < CR; ++r) s += base[r * Ec];
    psum[(size_t)bid * Ec + e] = s;
}

__global__ __launch_bounds__(64) void cumsum_p2(float* __restrict__ psum)
{
    int bh = blockIdx.x;
    int e = threadIdx.x;
    float off = 0.f;
    for (int c = 0; c < CH; ++c) {
        size_t idx = (size_t)(bh * CH + c) * Ec + e;
        float tv = psum[idx];
        psum[idx] = off;
        off += tv;
    }
}

__global__ __launch_bounds__(64) void cumsum_p3(
    const float* __restrict__ vp, const float* __restrict__ psum,
    float* __restrict__ out)
{
    int bid = blockIdx.x;
    int e = threadIdx.x;
    int bh = bid >> 6, ch = bid & 63;
    const float* base = vp  + (size_t)bh * LEc + (ch * CR) * Ec + e;
    float*       ob   = out + (size_t)bh * LEc + (ch * CR) * Ec + e;
    float run = psum[(size_t)bid * Ec + e];
    #pragma unroll 8
    for (int r = 0; r < CR; ++r) { run += base[r * Ec]; ob[r * Ec] = run; }
}

// ---------------------------------------------------------------------------
// Kernel 7a: chunked flash attention partials with u-reuse.
// grid = (bh, chunk of 128 rows) = 32*16 blocks, 512 threads (8 waves).
// ---------------------------------------------------------------------------
constexpr int ACH = 16;     // attn chunks
constexpr int AROWS = 128;  // rows per chunk

__global__ __launch_bounds__(512) void attn_partial(
    const float* __restrict__ qp, const float* __restrict__ kp,
    const float* __restrict__ vp, const int* __restrict__ mtop,
    float* __restrict__ pm, float* __restrict__ pl, float* __restrict__ pacc)
{
    __shared__ float Kt[64][68];     // stride 68: float4-aligned rows
    __shared__ float Vt[64][68];
    __shared__ float qsh[40][64];
    __shared__ float p_lds[64][45];  // stride 45: odd -> 2-way banks on col writes
    __shared__ int   lsel_sh[40];

    int bh = blockIdx.x & 31, ch = blockIdx.x >> 5;
    int t = threadIdx.x, w = t >> 6, lane = t & 63;
    const float* kb = kp + (size_t)bh * LEc;
    const float* vb = vp + (size_t)bh * LEc;

    if (t < Uc) lsel_sh[t] = mtop[bh * Uc + t];
    __syncthreads();
    for (int i = t; i < Uc * Ec; i += 512) {
        int u = i >> 6, e = i & 63;
        qsh[u][e] = qp[(size_t)bh * LEc + lsel_sh[u] * Ec + e];
    }

    const int u0 = w * 5;
    float acc[5]  = {0.f, 0.f, 0.f, 0.f, 0.f};
    float lreg[5] = {0.f, 0.f, 0.f, 0.f, 0.f};
    float mreg[5];
    #pragma unroll
    for (int j = 0; j < 5; ++j) mreg[j] = -FLT_MAX;

    for (int tt = 0; tt < AROWS / 64; ++tt) {
        int l0 = ch * AROWS + tt * 64;
        __syncthreads();   // prev-tile reads done (and qsh written, first iter)
        #pragma unroll
        for (int i = 0; i < 2; ++i) {
            int f = i * 512 + t, row = f >> 4, cg = f & 15;
            *(float4*)&Kt[row][cg * 4] = *(const float4*)(kb + (size_t)(l0 + row) * Ec + cg * 4);
            *(float4*)&Vt[row][cg * 4] = *(const float4*)(vb + (size_t)(l0 + row) * Ec + cg * 4);
        }
        __syncthreads();

        int gl = l0 + lane;
        float4 kr[16];
        #pragma unroll
        for (int i = 0; i < 16; ++i) kr[i] = *(const float4*)&Kt[lane][i * 4];

        bool act[5];
        #pragma unroll
        for (int j = 0; j < 5; ++j) {
            int u = u0 + j, ls = lsel_sh[u];
            act[j] = (l0 <= ls);            // wave-uniform
            if (!act[j]) continue;
            float s = -FLT_MAX;
            if (gl <= ls) {
                float dot = 0.f;
                #pragma unroll
                for (int i = 0; i < 16; ++i) {
                    float4 qv = *(const float4*)&qsh[u][i * 4];   // broadcast
                    dot += kr[i].x * qv.x + kr[i].y * qv.y + kr[i].z * qv.z + kr[i].w * qv.w;
                }
                s = dot * 0.125f;   // 1/sqrt(64)
            }
            float tmax = s;
            #pragma unroll
            for (int o = 1; o < 64; o <<= 1) tmax = fmaxf(tmax, __shfl_xor(tmax, o));
            float m_new = fmaxf(mreg[j], tmax);
            float p = (gl <= ls) ? __expf(s - m_new) : 0.f;
            p_lds[lane][u] = p;
            float ps = p;
            #pragma unroll
            for (int o = 1; o < 64; o <<= 1) ps += __shfl_xor(ps, o);
            float coef = __expf(mreg[j] - m_new);   // exp(0)=1 when unchanged
            lreg[j] = lreg[j] * coef + ps;
            acc[j] *= coef;
            mreg[j] = m_new;
        }

        // PV: lane = e.
        for (int row = 0; row < 64; ++row) {
            float vv = Vt[row][lane];
            #pragma unroll
            for (int j = 0; j < 5; ++j)
                if (act[j]) acc[j] = fmaf(p_lds[row][u0 + j], vv, acc[j]);
        }
    }

    #pragma unroll
    for (int j = 0; j < 5; ++j) {
        size_t idx = ((size_t)bh * ACH + ch) * Uc + u0 + j;
        if (lane == 0) { pm[idx] = mreg[j]; pl[idx] = lreg[j]; }
        pacc[idx * Ec + lane] = acc[j];
    }
}

// ---------------------------------------------------------------------------
// Kernel 7b: combine the 16 chunk-partials per (bh, u); write out row.
// ---------------------------------------------------------------------------
__global__ __launch_bounds__(256) void attn_combine(
    const float* __restrict__ pm, const float* __restrict__ pl,
    const float* __restrict__ pacc, const int* __restrict__ mtop,
    float* __restrict__ out)
{
    int wid = blockIdx.x * 4 + (threadIdx.x >> 6);
    int lane = threadIdx.x & 63;
    int bh = wid / Uc, u = wid % Uc;
    float m = -FLT_MAX;
    for (int i = 0; i < ACH; ++i)
        m = fmaxf(m, pm[((size_t)bh * ACH + i) * Uc + u]);
    float l = 0.f, a = 0.f;
    for (int i = 0; i < ACH; ++i) {
        size_t idx = ((size_t)bh * ACH + i) * Uc + u;
        float wgt = __expf(pm[idx] - m);   // exp(-inf)=0 for empty chunks
        l += wgt * pl[idx];
        a += wgt * pacc[idx * Ec + lane];
    }
    int lsel = mtop[bh * Uc + u];
    out[(size_t)bh * LEc + lsel * Ec + lane] = a / l;
}

// ---------------------------------------------------------------------------
extern "C" void kernel_launch(void* const* d_in, const int* in_sizes, int n_in,
                              void* d_out, int out_size, void* d_ws, size_t ws_size,
                              hipStream_t stream)
{
    const float* q   = (const float*)d_in[0];
    const float* k   = (const float*)d_in[1];
    const float* v   = (const float*)d_in[2];
    const float* Wq  = (const float*)d_in[3];
    const float* Wk  = (const float*)d_in[4];
    const float* Wv  = (const float*)d_in[5];
    const int*   ksi = (const int*)d_in[6];
    float* out = (float*)d_out;

    // workspace layout
    float* wsf  = (float*)d_ws;
    float* qp   = wsf;                            // 4,194,304 f
    float* kp   = qp + (size_t)Mrows * Dc;        // 4,194,304 f
    float* vp   = kp + (size_t)Mrows * Dc;        // 4,194,304 f
    float* psum = vp + (size_t)Mrows * Dc;        // 131,072 f
    float* m_ws = psum + (size_t)BHc * CH * Ec;   // 65,536 f
    int*   mtop = (int*)(m_ws + (size_t)BHc * Lc);      // 1,280 i
    short* qhi = (short*)(mtop + BHc * Uc);
    short* qlo = qhi + (size_t)Mrows * Dc;
    short* khi = qlo + (size_t)Mrows * Dc;
    short* klo = khi + (size_t)Mrows * Dc;
    short* vhi = klo + (size_t)Mrows * Dc;
    short* Bq  = vhi + (size_t)Mrows * Dc;        // 512*1536
    short* Bk  = Bq + (size_t)Dc * 1536;          // 512*1536
    short* Bv  = Bk + (size_t)Dc * 1536;          // 512*512
    float* pm  = (float*)(Bv + (size_t)Dc * 512); // 32*16*40
    float* pl  = pm + (size_t)BHc * ACH * Uc;     // 32*16*40
    float* pacc = pl + (size_t)BHc * ACH * Uc;    // 32*16*40*64

    split_inputs<<<3 * (Mrows * Dc / 4) / 256, 256, 0, stream>>>(
        q, k, v, qhi, qlo, khi, klo, vhi);
    wprep<<<dim3(8, 8, 3), 256, 0, stream>>>(Wq, Wk, Wv, Bq, Bk, Bv);

    dim3 g1(Mrows / 128, Dc / 128, 3);
    gemm_mfma<<<g1, 256, 0, stream>>>(qhi, qlo, khi, klo, vhi, Bq, Bk, Bv,
                                      qp, kp, vp);

    compute_m<<<(BHc * Lc) / 4, 256, 0, stream>>>(qp, kp, ksi, m_ws);

    topk40<<<BHc, 256, 0, stream>>>(m_ws, mtop);

    attn_partial<<<BHc * ACH, 512, 0, stream>>>(qp, kp, vp, mtop, pm, pl, pacc);

    cumsum_p1<<<BHc * CH, 64, 0, stream>>>(vp, psum);
    cumsum_p2<<<BHc, 64, 0, stream>>>(psum);
    cumsum_p3<<<BHc * CH, 64, 0, stream>>>(vp, psum, out);

    attn_combine<<<BHc * Uc / 4, 256, 0, stream>>>(pm, pl, pacc, mtop, out);
}

// Round 9
// 207.744 us; speedup vs baseline: 6.1964x; 1.2599x over previous
//
#include <hip/hip_runtime.h>
#include <hip/hip_bf16.h>
#include <float.h>

// Problem constants
constexpr int Bc = 4;
constexpr int Lc = 2048;
constexpr int Dc = 512;
constexpr int Hc = 8;
constexpr int Ec = 64;
constexpr int Sc = 40;   // sample_k
constexpr int Uc = 40;   // u_q (top-k queries)
constexpr int LEc = Lc * Ec;      // 131072
constexpr int BHc = Bc * Hc;      // 32
constexpr int Mrows = Bc * Lc;    // 8192 rows per GEMM

typedef __attribute__((ext_vector_type(8))) short s16x8;
typedef __attribute__((ext_vector_type(4))) float f32x4;
typedef unsigned int u32;

// round-to-nearest-even f32 -> bf16 (bit pattern in a short)
__device__ __forceinline__ short f2bf(float x) {
    unsigned u = __float_as_uint(x);
    unsigned r = (u + 0x7fffu + ((u >> 16) & 1u)) >> 16;
    return (short)r;
}
__device__ __forceinline__ float bf2f(short s) {
    return __uint_as_float(((unsigned)(unsigned short)s) << 16);
}
__device__ __forceinline__ uint4 pack8(const short* s) {
    uint4 r;
    r.x = (unsigned)(unsigned short)s[0] | ((unsigned)(unsigned short)s[1] << 16);
    r.y = (unsigned)(unsigned short)s[2] | ((unsigned)(unsigned short)s[3] << 16);
    r.z = (unsigned)(unsigned short)s[4] | ((unsigned)(unsigned short)s[5] << 16);
    r.w = (unsigned)(unsigned short)s[6] | ((unsigned)(unsigned short)s[7] << 16);
    return r;
}

// direct global->LDS DMA, 16 B per lane (dest = wave-uniform base + lane*16)
__device__ __forceinline__ void gld_lds16(const short* g, short* l) {
    __builtin_amdgcn_global_load_lds(
        (const __attribute__((address_space(1))) u32*)g,
        (__attribute__((address_space(3))) u32*)l, 16, 0, 0);
}

// ---------------------------------------------------------------------------
// Kernel 0a: split q,k -> (hi,lo) bf16; v -> hi bf16.  Pure memory pass.
// ---------------------------------------------------------------------------
__global__ __launch_bounds__(256) void split_inputs(
    const float* __restrict__ q, const float* __restrict__ k, const float* __restrict__ v,
    short* __restrict__ qhi, short* __restrict__ qlo,
    short* __restrict__ khi, short* __restrict__ klo, short* __restrict__ vhi)
{
    int tid = blockIdx.x * 256 + threadIdx.x;
    int z  = tid >> 20;                 // 2^20 float4 per tensor
    int i4 = tid & ((1 << 20) - 1);
    const float* src = (z == 0) ? q : (z == 1) ? k : v;
    float4 d = ((const float4*)src)[i4];
    short h0 = f2bf(d.x), h1 = f2bf(d.y), h2 = f2bf(d.z), h3 = f2bf(d.w);
    short4 hh = make_short4(h0, h1, h2, h3);
    if (z == 2) { ((short4*)vhi)[i4] = hh; return; }
    short4 ll = make_short4(f2bf(d.x - bf2f(h0)), f2bf(d.y - bf2f(h1)),
                            f2bf(d.z - bf2f(h2)), f2bf(d.w - bf2f(h3)));
    if (z == 0) { ((short4*)qhi)[i4] = hh; ((short4*)qlo)[i4] = ll; }
    else        { ((short4*)khi)[i4] = hh; ((short4*)klo)[i4] = ll; }
}

// ---------------------------------------------------------------------------
// Kernel 0b: W prep — transpose + K-extended split layout.
// z<2: Bx[n][0:512]=hi, [512:1024]=lo, [1024:1536]=hi
// z=2: Bv[n][0:512]=hi
// ---------------------------------------------------------------------------
__global__ __launch_bounds__(256) void wprep(
    const float* __restrict__ Wq, const float* __restrict__ Wk,
    const float* __restrict__ Wv,
    short* __restrict__ Bq, short* __restrict__ Bk, short* __restrict__ Bv)
{
    __shared__ float tile[64][65];
    int z = blockIdx.z;
    const float* W = (z == 0) ? Wq : (z == 1) ? Wk : Wv;
    int k0 = blockIdx.x * 64, n0 = blockIdx.y * 64;
    int t = threadIdx.x;
    #pragma unroll
    for (int i = 0; i < 4; ++i) {
        int c = i * 256 + t, row = c >> 4, qq = c & 15;
        float4 d = *(const float4*)(W + (size_t)(k0 + row) * Dc + n0 + qq * 4);
        tile[row][qq * 4 + 0] = d.x; tile[row][qq * 4 + 1] = d.y;
        tile[row][qq * 4 + 2] = d.z; tile[row][qq * 4 + 3] = d.w;
    }
    __syncthreads();
    int n = t >> 2, ks = (t & 3) * 16;
    short hs[16], ls[16];
    #pragma unroll
    for (int j = 0; j < 16; ++j) {
        float x = tile[ks + j][n];
        short h = f2bf(x);
        hs[j] = h;
        ls[j] = f2bf(x - bf2f(h));
    }
    if (z < 2) {
        short* Bx = (z == 0) ? Bq : Bk;
        size_t b = (size_t)(n0 + n) * 1536 + k0 + ks;
        *(uint4*)(Bx + b)            = pack8(hs);
        *(uint4*)(Bx + b + 8)        = pack8(hs + 8);
        *(uint4*)(Bx + b + 512)      = pack8(ls);
        *(uint4*)(Bx + b + 520)      = pack8(ls + 8);
        *(uint4*)(Bx + b + 1024)     = pack8(hs);
        *(uint4*)(Bx + b + 1032)     = pack8(hs + 8);
    } else {
        size_t b = (size_t)(n0 + n) * 512 + k0 + ks;
        *(uint4*)(Bv + b)     = pack8(hs);
        *(uint4*)(Bv + b + 8) = pack8(hs + 8);
    }
}

// ---------------------------------------------------------------------------
// Kernel 1: projection GEMMs, m97 structure (global_load_lds staging).
// ---------------------------------------------------------------------------
__global__ __launch_bounds__(256) void gemm_mfma(
    const short* __restrict__ qhi, const short* __restrict__ qlo,
    const short* __restrict__ khi, const short* __restrict__ klo,
    const short* __restrict__ vhi,
    const short* __restrict__ Bq, const short* __restrict__ Bk,
    const short* __restrict__ Bv,
    float* __restrict__ qp, float* __restrict__ kp, float* __restrict__ vp)
{
    int z = blockIdx.z;
    const short* Ahi = (z == 0) ? qhi : (z == 1) ? khi : vhi;
    const short* Alo = (z == 0) ? qlo : (z == 1) ? klo : vhi;  // unused for z==2
    const short* Bx  = (z == 0) ? Bq  : (z == 1) ? Bk  : Bv;
    float* O = (z == 0) ? qp : (z == 1) ? kp : vp;
    const int Ktot = (z == 2) ? 512 : 1536;

    __shared__ short As[128 * 64];
    __shared__ short Bs[128 * 64];

    const int t = threadIdx.x;
    const int lane = t & 63, w = t >> 6;
    const int wm = w >> 1, wn = w & 1;
    const int row0 = blockIdx.x * 128, col0 = blockIdx.y * 128;
    const int kg = lane >> 4, fr = lane & 15;
    const int lrow = lane >> 3, lcol = (lane & 7) * 8;   // staging: 8 rows x 128B

    f32x4 acc[4][4];
    #pragma unroll
    for (int i = 0; i < 4; ++i)
        #pragma unroll
        for (int j = 0; j < 4; ++j)
            acc[i][j] = (f32x4){0.f, 0.f, 0.f, 0.f};

    for (int k0 = 0; k0 < Ktot; k0 += 64) {
        int seg = k0 >> 9, ks = k0 & 511;
        const short* Asrc = (seg == 2) ? Alo : Ahi;
        __syncthreads();
        #pragma unroll
        for (int i = 0; i < 4; ++i) {
            int r = w * 32 + i * 8;
            gld_lds16(Asrc + (size_t)(row0 + r + lrow) * 512 + ks + lcol,
                      &As[r * 64]);
        }
        #pragma unroll
        for (int i = 0; i < 4; ++i) {
            int r = w * 32 + i * 8;
            gld_lds16(Bx + (size_t)(col0 + r + lrow) * Ktot + k0 + lcol,
                      &Bs[r * 64]);
        }
        __syncthreads();

        #pragma unroll
        for (int kk = 0; kk < 2; ++kk) {
            s16x8 a[4];
            #pragma unroll
            for (int mi = 0; mi < 4; ++mi)
                a[mi] = *(const s16x8*)&As[(wm * 64 + mi * 16 + fr) * 64 + kk * 32 + kg * 8];
            #pragma unroll
            for (int ni = 0; ni < 4; ++ni) {
                s16x8 b = *(const s16x8*)&Bs[(wn * 64 + ni * 16 + fr) * 64 + kk * 32 + kg * 8];
                #pragma unroll
                for (int mi = 0; mi < 4; ++mi)
                    acc[mi][ni] = __builtin_amdgcn_mfma_f32_16x16x32_bf16(a[mi], b, acc[mi][ni], 0, 0, 0);
            }
        }
    }

    #pragma unroll
    for (int mi = 0; mi < 4; ++mi) {
        #pragma unroll
        for (int ni = 0; ni < 4; ++ni) {
            int row = row0 + wm * 64 + mi * 16 + (lane >> 4) * 4;
            int col = col0 + wn * 64 + ni * 16 + (lane & 15);
            #pragma unroll
            for (int r4 = 0; r4 < 4; ++r4)
                O[(size_t)(row + r4) * Dc + col] = acc[mi][ni][r4];
        }
    }
}

// ---------------------------------------------------------------------------
// Kernel 2: sampled scores -> m[bh, l] = max_s(dot) - sum_s(dot)/L
// One wave per (bh, l). GROUP-COALESCED gather: 4 lanes per sampled K-row,
// lane c reads float4 (4*ii + c) -> one 64B line per group per instruction
// (coalesced to a single line-request; each line fetched exactly once).
// 16 rows per iteration x 3 iterations covers 40 samples.
// XCD-aware swizzle keeps each XCD's kp slice in its private L2.
// ---------------------------------------------------------------------------
__global__ __launch_bounds__(256) void compute_m(
    const float* __restrict__ qp, const float* __restrict__ kp,
    const int* __restrict__ ksi, float* __restrict__ m_out)
{
    __shared__ float qsh[4][Ec];
    __shared__ int   jsh[4][Sc];
    int w    = threadIdx.x >> 6;
    int lane = threadIdx.x & 63;
    int xcd  = blockIdx.x & 7;
    int i    = blockIdx.x >> 3;            // 0..2047
    int bh   = (xcd << 2) | (i >> 9);      // 4 bh per XCD
    int l    = (i & 511) * 4 + w;
    const float* kbase = kp + (size_t)bh * LEc;

    qsh[w][lane] = qp[(size_t)bh * LEc + l * Ec + lane];
    if (lane < Sc) jsh[w][lane] = ksi[l * Sc + lane];
    __syncthreads();

    const int g = lane >> 2;   // group 0..15 (one sampled row each)
    const int c = lane & 3;    // lane-in-group (one 64B line slice each)

    float mx = -FLT_MAX, sm = 0.f;
    #pragma unroll
    for (int it = 0; it < 3; ++it) {
        int s = it * 16 + g;
        bool valid = (s < Sc);
        float partial = 0.f;
        if (valid) {
            int j = jsh[w][s];
            const float4* krow = (const float4*)(kbase + (size_t)j * Ec);
            #pragma unroll
            for (int ii = 0; ii < 4; ++ii) {
                float4 kv = krow[ii * 4 + c];                       // line ii, coalesced x4 lanes
                float4 qv = *(const float4*)&qsh[w][ii * 16 + c * 4]; // <=2-way LDS (free)
                partial += kv.x * qv.x + kv.y * qv.y + kv.z * qv.z + kv.w * qv.w;
            }
        }
        // 4-lane butterfly: all lanes of a group get the row's dot
        partial += __shfl_xor(partial, 1);
        partial += __shfl_xor(partial, 2);
        float vmax = valid ? partial : -FLT_MAX;
        float vsum = (valid && c == 0) ? partial : 0.f;
        #pragma unroll
        for (int o = 4; o < 64; o <<= 1) {
            vmax = fmaxf(vmax, __shfl_xor(vmax, o));
            vsum += __shfl_xor(vsum, o);
        }
        mx = fmaxf(mx, vmax);
        sm += vsum;
    }
    if (lane == 0) m_out[bh * Lc + l] = mx - sm * (1.0f / Lc);
}

// ---------------------------------------------------------------------------
// Kernel 3: top-40 indices per (bh). Wave-parallel extract-max.
// Tie -> lower idx (matches jax.lax.top_k).
// ---------------------------------------------------------------------------
__global__ __launch_bounds__(256) void topk40(
    const float* __restrict__ m_in, int* __restrict__ mtop)
{
    __shared__ float vals[Lc];
    __shared__ float wv[4];
    __shared__ int   wi[4];
    int bh = blockIdx.x, t = threadIdx.x;
    int lane = t & 63, w = t >> 6;
    for (int i = t; i < Lc; i += 256) vals[i] = m_in[bh * Lc + i];
    __syncthreads();
    for (int it = 0; it < Uc; ++it) {
        float lv = -FLT_MAX; int li = 0x7fffffff;
        #pragma unroll
        for (int rep = 0; rep < Lc / 256; ++rep) {
            int i = rep * 256 + t;
            float v = vals[i];
            if (v > lv) { lv = v; li = i; }
        }
        #pragma unroll
        for (int o = 1; o < 64; o <<= 1) {
            float ov = __shfl_xor(lv, o);
            int   oi = __shfl_xor(li, o);
            if (ov > lv || (ov == lv && oi < li)) { lv = ov; li = oi; }
        }
        if (lane == 0) { wv[w] = lv; wi[w] = li; }
        __syncthreads();
        if (t == 0) {
            float Bv = wv[0]; int Bi = wi[0];
            #pragma unroll
            for (int j = 1; j < 4; ++j) {
                if (wv[j] > Bv || (wv[j] == Bv && wi[j] < Bi)) { Bv = wv[j]; Bi = wi[j]; }
            }
            mtop[bh * Uc + it] = Bi;
            vals[Bi] = -FLT_MAX;
        }
        __syncthreads();
    }
}

// ---------------------------------------------------------------------------
// Kernels 4-6: chunked inclusive cumsum of vp along l, per (bh, e) column.
// ---------------------------------------------------------------------------
constexpr int CH = 64;  // chunks
constexpr int CR = 32;  // rows per chunk

__global__ __launch_bounds__(64) void cumsum_p1(
    const float* __restrict__ vp, float* __restrict__ psum)
{
    int bid = blockIdx.x;
    int e = threadIdx.x;
    int bh = bid >> 6, ch = bid & 63;
    const float* base = vp + (size_t)bh * LEc + (ch * CR) * Ec + e;
    float s = 0.f;
    #pragma unroll 8
    for (int r = 0; r < CR; ++r) s += base[r * Ec];
    psum[(size_t)bid * Ec + e] = s;
}

__global__ __launch_bounds__(64) void cumsum_p2(float* __restrict__ psum)
{
    int bh = blockIdx.x;
    int e = threadIdx.x;
    float off = 0.f;
    for (int c = 0; c < CH; ++c) {
        size_t idx = (size_t)(bh * CH + c) * Ec + e;
        float tv = psum[idx];
        psum[idx] = off;
        off += tv;
    }
}

__global__ __launch_bounds__(64) void cumsum_p3(
    const float* __restrict__ vp, const float* __restrict__ psum,
    float* __restrict__ out)
{
    int bid = blockIdx.x;
    int e = threadIdx.x;
    int bh = bid >> 6, ch = bid & 63;
    const float* base = vp  + (size_t)bh * LEc + (ch * CR) * Ec + e;
    float*       ob   = out + (size_t)bh * LEc + (ch * CR) * Ec + e;
    float run = psum[(size_t)bid * Ec + e];
    #pragma unroll 8
    for (int r = 0; r < CR; ++r) { run += base[r * Ec]; ob[r * Ec] = run; }
}

// ---------------------------------------------------------------------------
// Kernel 7a: chunked flash attention partials with u-reuse.
// grid = (bh, chunk of 128 rows) = 32*16 blocks, 512 threads (8 waves).
// ---------------------------------------------------------------------------
constexpr int ACH = 16;     // attn chunks
constexpr int AROWS = 128;  // rows per chunk

__global__ __launch_bounds__(512) void attn_partial(
    const float* __restrict__ qp, const float* __restrict__ kp,
    const float* __restrict__ vp, const int* __restrict__ mtop,
    float* __restrict__ pm, float* __restrict__ pl, float* __restrict__ pacc)
{
    __shared__ float Kt[64][68];     // stride 68: float4-aligned rows
    __shared__ float Vt[64][68];
    __shared__ float qsh[40][64];
    __shared__ float p_lds[64][45];  // stride 45: odd -> 2-way banks on col writes
    __shared__ int   lsel_sh[40];

    int bh = blockIdx.x & 31, ch = blockIdx.x >> 5;
    int t = threadIdx.x, w = t >> 6, lane = t & 63;
    const float* kb = kp + (size_t)bh * LEc;
    const float* vb = vp + (size_t)bh * LEc;

    if (t < Uc) lsel_sh[t] = mtop[bh * Uc + t];
    __syncthreads();
    for (int i = t; i < Uc * Ec; i += 512) {
        int u = i >> 6, e = i & 63;
        qsh[u][e] = qp[(size_t)bh * LEc + lsel_sh[u] * Ec + e];
    }

    const int u0 = w * 5;
    float acc[5]  = {0.f, 0.f, 0.f, 0.f, 0.f};
    float lreg[5] = {0.f, 0.f, 0.f, 0.f, 0.f};
    float mreg[5];
    #pragma unroll
    for (int j = 0; j < 5; ++j) mreg[j] = -FLT_MAX;

    for (int tt = 0; tt < AROWS / 64; ++tt) {
        int l0 = ch * AROWS + tt * 64;
        __syncthreads();   // prev-tile reads done (and qsh written, first iter)
        #pragma unroll
        for (int i = 0; i < 2; ++i) {
            int f = i * 512 + t, row = f >> 4, cg = f & 15;
            *(float4*)&Kt[row][cg * 4] = *(const float4*)(kb + (size_t)(l0 + row) * Ec + cg * 4);
            *(float4*)&Vt[row][cg * 4] = *(const float4*)(vb + (size_t)(l0 + row) * Ec + cg * 4);
        }
        __syncthreads();

        int gl = l0 + lane;
        float4 kr[16];
        #pragma unroll
        for (int i = 0; i < 16; ++i) kr[i] = *(const float4*)&Kt[lane][i * 4];

        bool act[5];
        #pragma unroll
        for (int j = 0; j < 5; ++j) {
            int u = u0 + j, ls = lsel_sh[u];
            act[j] = (l0 <= ls);            // wave-uniform
            if (!act[j]) continue;
            float s = -FLT_MAX;
            if (gl <= ls) {
                float dot = 0.f;
                #pragma unroll
                for (int i = 0; i < 16; ++i) {
                    float4 qv = *(const float4*)&qsh[u][i * 4];   // broadcast
                    dot += kr[i].x * qv.x + kr[i].y * qv.y + kr[i].z * qv.z + kr[i].w * qv.w;
                }
                s = dot * 0.125f;   // 1/sqrt(64)
            }
            float tmax = s;
            #pragma unroll
            for (int o = 1; o < 64; o <<= 1) tmax = fmaxf(tmax, __shfl_xor(tmax, o));
            float m_new = fmaxf(mreg[j], tmax);
            float p = (gl <= ls) ? __expf(s - m_new) : 0.f;
            p_lds[lane][u] = p;
            float ps = p;
            #pragma unroll
            for (int o = 1; o < 64; o <<= 1) ps += __shfl_xor(ps, o);
            float coef = __expf(mreg[j] - m_new);   // exp(0)=1 when unchanged
            lreg[j] = lreg[j] * coef + ps;
            acc[j] *= coef;
            mreg[j] = m_new;
        }

        // PV: lane = e.
        for (int row = 0; row < 64; ++row) {
            float vv = Vt[row][lane];
            #pragma unroll
            for (int j = 0; j < 5; ++j)
                if (act[j]) acc[j] = fmaf(p_lds[row][u0 + j], vv, acc[j]);
        }
    }

    #pragma unroll
    for (int j = 0; j < 5; ++j) {
        size_t idx = ((size_t)bh * ACH + ch) * Uc + u0 + j;
        if (lane == 0) { pm[idx] = mreg[j]; pl[idx] = lreg[j]; }
        pacc[idx * Ec + lane] = acc[j];
    }
}

// ---------------------------------------------------------------------------
// Kernel 7b: combine the 16 chunk-partials per (bh, u); write out row.
// ---------------------------------------------------------------------------
__global__ __launch_bounds__(256) void attn_combine(
    const float* __restrict__ pm, const float* __restrict__ pl,
    const float* __restrict__ pacc, const int* __restrict__ mtop,
    float* __restrict__ out)
{
    int wid = blockIdx.x * 4 + (threadIdx.x >> 6);
    int lane = threadIdx.x & 63;
    int bh = wid / Uc, u = wid % Uc;
    float m = -FLT_MAX;
    for (int i = 0; i < ACH; ++i)
        m = fmaxf(m, pm[((size_t)bh * ACH + i) * Uc + u]);
    float l = 0.f, a = 0.f;
    for (int i = 0; i < ACH; ++i) {
        size_t idx = ((size_t)bh * ACH + i) * Uc + u;
        float wgt = __expf(pm[idx] - m);   // exp(-inf)=0 for empty chunks
        l += wgt * pl[idx];
        a += wgt * pacc[idx * Ec + lane];
    }
    int lsel = mtop[bh * Uc + u];
    out[(size_t)bh * LEc + lsel * Ec + lane] = a / l;
}

// ---------------------------------------------------------------------------
extern "C" void kernel_launch(void* const* d_in, const int* in_sizes, int n_in,
                              void* d_out, int out_size, void* d_ws, size_t ws_size,
                              hipStream_t stream)
{
    const float* q   = (const float*)d_in[0];
    const float* k   = (const float*)d_in[1];
    const float* v   = (const float*)d_in[2];
    const float* Wq  = (const float*)d_in[3];
    const float* Wk  = (const float*)d_in[4];
    const float* Wv  = (const float*)d_in[5];
    const int*   ksi = (const int*)d_in[6];
    float* out = (float*)d_out;

    // workspace layout
    float* wsf  = (float*)d_ws;
    float* qp   = wsf;                            // 4,194,304 f
    float* kp   = qp + (size_t)Mrows * Dc;        // 4,194,304 f
    float* vp   = kp + (size_t)Mrows * Dc;        // 4,194,304 f
    float* psum = vp + (size_t)Mrows * Dc;        // 131,072 f
    float* m_ws = psum + (size_t)BHc * CH * Ec;   // 65,536 f
    int*   mtop = (int*)(m_ws + (size_t)BHc * Lc);      // 1,280 i
    short* qhi = (short*)(mtop + BHc * Uc);
    short* qlo = qhi + (size_t)Mrows * Dc;
    short* khi = qlo + (size_t)Mrows * Dc;
    short* klo = khi + (size_t)Mrows * Dc;
    short* vhi = klo + (size_t)Mrows * Dc;
    short* Bq  = vhi + (size_t)Mrows * Dc;        // 512*1536
    short* Bk  = Bq + (size_t)Dc * 1536;          // 512*1536
    short* Bv  = Bk + (size_t)Dc * 1536;          // 512*512
    float* pm  = (float*)(Bv + (size_t)Dc * 512); // 32*16*40
    float* pl  = pm + (size_t)BHc * ACH * Uc;     // 32*16*40
    float* pacc = pl + (size_t)BHc * ACH * Uc;    // 32*16*40*64

    split_inputs<<<3 * (Mrows * Dc / 4) / 256, 256, 0, stream>>>(
        q, k, v, qhi, qlo, khi, klo, vhi);
    wprep<<<dim3(8, 8, 3), 256, 0, stream>>>(Wq, Wk, Wv, Bq, Bk, Bv);

    dim3 g1(Mrows / 128, Dc / 128, 3);
    gemm_mfma<<<g1, 256, 0, stream>>>(qhi, qlo, khi, klo, vhi, Bq, Bk, Bv,
                                      qp, kp, vp);

    compute_m<<<(BHc * Lc) / 4, 256, 0, stream>>>(qp, kp, ksi, m_ws);

    topk40<<<BHc, 256, 0, stream>>>(m_ws, mtop);

    attn_partial<<<BHc * ACH, 512, 0, stream>>>(qp, kp, vp, mtop, pm, pl, pacc);

    cumsum_p1<<<BHc * CH, 64, 0, stream>>>(vp, psum);
    cumsum_p2<<<BHc, 64, 0, stream>>>(psum);
    cumsum_p3<<<BHc * CH, 64, 0, stream>>>(vp, psum, out);

    attn_combine<<<BHc * Uc / 4, 256, 0, stream>>>(pm, pl, pacc, mtop, out);
}

// Round 10
// 185.994 us; speedup vs baseline: 6.9210x; 1.1169x over previous
//
#include <hip/hip_runtime.h>
#include <hip/hip_bf16.h>
#include <float.h>

// Problem constants
constexpr int Bc = 4;
constexpr int Lc = 2048;
constexpr int Dc = 512;
constexpr int Hc = 8;
constexpr int Ec = 64;
constexpr int Sc = 40;   // sample_k
constexpr int Uc = 40;   // u_q (top-k queries)
constexpr int LEc = Lc * Ec;      // 131072
constexpr int BHc = Bc * Hc;      // 32
constexpr int Mrows = Bc * Lc;    // 8192 rows per GEMM

typedef __attribute__((ext_vector_type(8))) short s16x8;
typedef __attribute__((ext_vector_type(4))) float f32x4;
typedef unsigned int u32;

// round-to-nearest-even f32 -> bf16 (bit pattern in a short)
__device__ __forceinline__ short f2bf(float x) {
    unsigned u = __float_as_uint(x);
    unsigned r = (u + 0x7fffu + ((u >> 16) & 1u)) >> 16;
    return (short)r;
}
__device__ __forceinline__ float bf2f(short s) {
    return __uint_as_float(((unsigned)(unsigned short)s) << 16);
}
__device__ __forceinline__ uint4 pack8(const short* s) {
    uint4 r;
    r.x = (unsigned)(unsigned short)s[0] | ((unsigned)(unsigned short)s[1] << 16);
    r.y = (unsigned)(unsigned short)s[2] | ((unsigned)(unsigned short)s[3] << 16);
    r.z = (unsigned)(unsigned short)s[4] | ((unsigned)(unsigned short)s[5] << 16);
    r.w = (unsigned)(unsigned short)s[6] | ((unsigned)(unsigned short)s[7] << 16);
    return r;
}

// direct global->LDS DMA, 16 B per lane (dest = wave-uniform base + lane*16)
__device__ __forceinline__ void gld_lds16(const short* g, short* l) {
    __builtin_amdgcn_global_load_lds(
        (const __attribute__((address_space(1))) u32*)g,
        (__attribute__((address_space(3))) u32*)l, 16, 0, 0);
}

// ---------------------------------------------------------------------------
// Kernel 0a: split q,k -> (hi,lo) bf16; v -> hi bf16.
// One thread = 8 consecutive floats = one 16-B output group.
// Groups are stored XOR-swizzled within each 128-B row block:
//   slot = (g & ~7) | ((g ^ row) & 7)
// so that gemm's linear global_load_lds produces a bank-conflict-free LDS
// layout (read side applies the same XOR).  Bit-exact permutation only.
// ---------------------------------------------------------------------------
__global__ __launch_bounds__(256) void split_inputs(
    const float* __restrict__ q, const float* __restrict__ k, const float* __restrict__ v,
    short* __restrict__ qhi, short* __restrict__ qlo,
    short* __restrict__ khi, short* __restrict__ klo, short* __restrict__ vhi)
{
    int tid = blockIdx.x * 256 + threadIdx.x;
    int z   = tid >> 19;                  // 2^19 groups (of 8 floats) per tensor
    int g8  = tid & ((1 << 19) - 1);
    int row = g8 >> 6;                    // 64 groups per 512-float row
    int gin = g8 & 63;
    int slot = (gin & ~7) | ((gin ^ row) & 7);
    const float* src = (z == 0) ? q : (z == 1) ? k : v;
    const float4* s4 = (const float4*)src + (size_t)g8 * 2;
    float4 d0 = s4[0], d1 = s4[1];
    float f[8] = {d0.x, d0.y, d0.z, d0.w, d1.x, d1.y, d1.z, d1.w};
    short hs[8], ls[8];
    #pragma unroll
    for (int i = 0; i < 8; ++i) {
        hs[i] = f2bf(f[i]);
        ls[i] = f2bf(f[i] - bf2f(hs[i]));
    }
    size_t off = (size_t)row * 512 + slot * 8;
    if (z == 2) { *(uint4*)(vhi + off) = pack8(hs); return; }
    if (z == 0) { *(uint4*)(qhi + off) = pack8(hs); *(uint4*)(qlo + off) = pack8(ls); }
    else        { *(uint4*)(khi + off) = pack8(hs); *(uint4*)(klo + off) = pack8(ls); }
}

// ---------------------------------------------------------------------------
// Kernel 0b: W prep — transpose + K-extended split layout, XOR-swizzled groups.
// z<2: Bx[n][0:512]=hi, [512:1024]=lo, [1024:1536]=hi ;  z=2: Bv[n][0:512]=hi
// Group slot within each 128-B block: (G & ~7) | ((G ^ n) & 7).
// ---------------------------------------------------------------------------
__global__ __launch_bounds__(256) void wprep(
    const float* __restrict__ Wq, const float* __restrict__ Wk,
    const float* __restrict__ Wv,
    short* __restrict__ Bq, short* __restrict__ Bk, short* __restrict__ Bv)
{
    __shared__ float tile[64][65];
    int z = blockIdx.z;
    const float* W = (z == 0) ? Wq : (z == 1) ? Wk : Wv;
    int k0 = blockIdx.x * 64, n0 = blockIdx.y * 64;
    int t = threadIdx.x;
    #pragma unroll
    for (int i = 0; i < 4; ++i) {
        int c = i * 256 + t, row = c >> 4, qq = c & 15;
        float4 d = *(const float4*)(W + (size_t)(k0 + row) * Dc + n0 + qq * 4);
        tile[row][qq * 4 + 0] = d.x; tile[row][qq * 4 + 1] = d.y;
        tile[row][qq * 4 + 2] = d.z; tile[row][qq * 4 + 3] = d.w;
    }
    __syncthreads();
    int n = t >> 2, ks = (t & 3) * 16;
    int nglob = n0 + n;
    short hs[16], ls[16];
    #pragma unroll
    for (int j = 0; j < 16; ++j) {
        float x = tile[ks + j][n];
        short h = f2bf(x);
        hs[j] = h;
        ls[j] = f2bf(x - bf2f(h));
    }
    int G0 = (k0 + ks) >> 3;      // even (ks multiple of 16 shorts = 2 groups)
    int s0 = (G0 & ~7) | ((G0 ^ nglob) & 7);
    int s1 = ((G0 + 1) & ~7) | (((G0 + 1) ^ nglob) & 7);
    if (z < 2) {
        short* Bx = (z == 0) ? Bq : Bk;
        size_t rb = (size_t)nglob * 1536;
        *(uint4*)(Bx + rb + s0 * 8)        = pack8(hs);
        *(uint4*)(Bx + rb + s1 * 8)        = pack8(hs + 8);
        *(uint4*)(Bx + rb + 512 + s0 * 8)  = pack8(ls);
        *(uint4*)(Bx + rb + 512 + s1 * 8)  = pack8(ls + 8);
        *(uint4*)(Bx + rb + 1024 + s0 * 8) = pack8(hs);
        *(uint4*)(Bx + rb + 1024 + s1 * 8) = pack8(hs + 8);
    } else {
        size_t rb = (size_t)nglob * 512;
        *(uint4*)(Bv + rb + s0 * 8) = pack8(hs);
        *(uint4*)(Bv + rb + s1 * 8) = pack8(hs + 8);
    }
}

// ---------------------------------------------------------------------------
// Kernel 1: projection GEMMs, m97 structure + swizzled LDS.
// Outer loop over hi/lo segments (branch-free inner K-loop, strength-reduced
// addresses). LDS reads use slot XOR (kk*4+kg)^(fr&7): 8 lanes per 4-bank
// window = LDS BW floor, no excess conflicts.
// ---------------------------------------------------------------------------
__global__ __launch_bounds__(256) void gemm_mfma(
    const short* __restrict__ qhi, const short* __restrict__ qlo,
    const short* __restrict__ khi, const short* __restrict__ klo,
    const short* __restrict__ vhi,
    const short* __restrict__ Bq, const short* __restrict__ Bk,
    const short* __restrict__ Bv,
    float* __restrict__ qp, float* __restrict__ kp, float* __restrict__ vp)
{
    int z = blockIdx.z;
    const short* Ahi = (z == 0) ? qhi : (z == 1) ? khi : vhi;
    const short* Alo = (z == 0) ? qlo : (z == 1) ? klo : vhi;  // unused for z==2
    const short* Bx  = (z == 0) ? Bq  : (z == 1) ? Bk  : Bv;
    float* O = (z == 0) ? qp : (z == 1) ? kp : vp;
    const int Ktot = (z == 2) ? 512 : 1536;
    const int nseg = (z == 2) ? 1 : 3;

    __shared__ short As[128 * 64];
    __shared__ short Bs[128 * 64];

    const int t = threadIdx.x;
    const int lane = t & 63, w = t >> 6;
    const int wm = w >> 1, wn = w & 1;
    const int row0 = blockIdx.x * 128, col0 = blockIdx.y * 128;
    const int kg = lane >> 4, fr = lane & 15;
    const int sx = fr & 7;                               // read-slot XOR
    const int lrow = lane >> 3, lcol = (lane & 7) * 8;   // staging: 8 rows x 128B

    f32x4 acc[4][4];
    #pragma unroll
    for (int i = 0; i < 4; ++i)
        #pragma unroll
        for (int j = 0; j < 4; ++j)
            acc[i][j] = (f32x4){0.f, 0.f, 0.f, 0.f};

    for (int seg = 0; seg < nseg; ++seg) {
        const short* Asrc = ((seg == 2) ? Alo : Ahi)
                          + (size_t)(row0 + lrow) * 512 + lcol;
        const short* Bsrc = Bx + (size_t)(col0 + lrow) * Ktot + seg * 512 + lcol;
        for (int ks = 0; ks < 512; ks += 64) {
            __syncthreads();   // prev iteration's LDS reads done before overwrite
            #pragma unroll
            for (int i = 0; i < 4; ++i) {
                int r = w * 32 + i * 8;
                gld_lds16(Asrc + (size_t)r * 512 + ks, &As[r * 64]);
            }
            #pragma unroll
            for (int i = 0; i < 4; ++i) {
                int r = w * 32 + i * 8;
                gld_lds16(Bsrc + (size_t)r * Ktot + ks, &Bs[r * 64]);
            }
            __syncthreads();   // drains vmcnt before barrier

            #pragma unroll
            for (int kk = 0; kk < 2; ++kk) {
                const int slot = ((kk * 4 + kg) ^ sx) * 8;
                s16x8 a[4];
                #pragma unroll
                for (int mi = 0; mi < 4; ++mi)
                    a[mi] = *(const s16x8*)&As[(wm * 64 + mi * 16 + fr) * 64 + slot];
                #pragma unroll
                for (int ni = 0; ni < 4; ++ni) {
                    s16x8 b = *(const s16x8*)&Bs[(wn * 64 + ni * 16 + fr) * 64 + slot];
                    #pragma unroll
                    for (int mi = 0; mi < 4; ++mi)
                        acc[mi][ni] = __builtin_amdgcn_mfma_f32_16x16x32_bf16(a[mi], b, acc[mi][ni], 0, 0, 0);
                }
            }
        }
    }

    // epilogue: C/D layout col=lane&15, row=(lane>>4)*4+reg
    #pragma unroll
    for (int mi = 0; mi < 4; ++mi) {
        #pragma unroll
        for (int ni = 0; ni < 4; ++ni) {
            int row = row0 + wm * 64 + mi * 16 + (lane >> 4) * 4;
            int col = col0 + wn * 64 + ni * 16 + (lane & 15);
            #pragma unroll
            for (int r4 = 0; r4 < 4; ++r4)
                O[(size_t)(row + r4) * Dc + col] = acc[mi][ni][r4];
        }
    }
}

// ---------------------------------------------------------------------------
// Kernel 2: sampled scores -> m[bh, l] = max_s(dot) - sum_s(dot)/L
// One wave per (bh, l). GROUP-COALESCED gather: 4 lanes per sampled K-row.
// XCD-aware swizzle keeps each XCD's kp slice in its private L2.
// ---------------------------------------------------------------------------
__global__ __launch_bounds__(256) void compute_m(
    const float* __restrict__ qp, const float* __restrict__ kp,
    const int* __restrict__ ksi, float* __restrict__ m_out)
{
    __shared__ float qsh[4][Ec];
    __shared__ int   jsh[4][Sc];
    int w    = threadIdx.x >> 6;
    int lane = threadIdx.x & 63;
    int xcd  = blockIdx.x & 7;
    int i    = blockIdx.x >> 3;            // 0..2047
    int bh   = (xcd << 2) | (i >> 9);      // 4 bh per XCD
    int l    = (i & 511) * 4 + w;
    const float* kbase = kp + (size_t)bh * LEc;

    qsh[w][lane] = qp[(size_t)bh * LEc + l * Ec + lane];
    if (lane < Sc) jsh[w][lane] = ksi[l * Sc + lane];
    __syncthreads();

    const int g = lane >> 2;   // group 0..15 (one sampled row each)
    const int c = lane & 3;    // lane-in-group (one 64B line slice each)

    float mx = -FLT_MAX, sm = 0.f;
    #pragma unroll
    for (int it = 0; it < 3; ++it) {
        int s = it * 16 + g;
        bool valid = (s < Sc);
        float partial = 0.f;
        if (valid) {
            int j = jsh[w][s];
            const float4* krow = (const float4*)(kbase + (size_t)j * Ec);
            #pragma unroll
            for (int ii = 0; ii < 4; ++ii) {
                float4 kv = krow[ii * 4 + c];
                float4 qv = *(const float4*)&qsh[w][ii * 16 + c * 4];
                partial += kv.x * qv.x + kv.y * qv.y + kv.z * qv.z + kv.w * qv.w;
            }
        }
        partial += __shfl_xor(partial, 1);
        partial += __shfl_xor(partial, 2);
        float vmax = valid ? partial : -FLT_MAX;
        float vsum = (valid && c == 0) ? partial : 0.f;
        #pragma unroll
        for (int o = 4; o < 64; o <<= 1) {
            vmax = fmaxf(vmax, __shfl_xor(vmax, o));
            vsum += __shfl_xor(vsum, o);
        }
        mx = fmaxf(mx, vmax);
        sm += vsum;
    }
    if (lane == 0) m_out[bh * Lc + l] = mx - sm * (1.0f / Lc);
}

// ---------------------------------------------------------------------------
// Kernel 3: top-40 indices per (bh). Wave-parallel extract-max.
// Tie -> lower idx (matches jax.lax.top_k).
// ---------------------------------------------------------------------------
__global__ __launch_bounds__(256) void topk40(
    const float* __restrict__ m_in, int* __restrict__ mtop)
{
    __shared__ float vals[Lc];
    __shared__ float wv[4];
    __shared__ int   wi[4];
    int bh = blockIdx.x, t = threadIdx.x;
    int lane = t & 63, w = t >> 6;
    for (int i = t; i < Lc; i += 256) vals[i] = m_in[bh * Lc + i];
    __syncthreads();
    for (int it = 0; it < Uc; ++it) {
        float lv = -FLT_MAX; int li = 0x7fffffff;
        #pragma unroll
        for (int rep = 0; rep < Lc / 256; ++rep) {
            int i = rep * 256 + t;
            float v = vals[i];
            if (v > lv) { lv = v; li = i; }
        }
        #pragma unroll
        for (int o = 1; o < 64; o <<= 1) {
            float ov = __shfl_xor(lv, o);
            int   oi = __shfl_xor(li, o);
            if (ov > lv || (ov == lv && oi < li)) { lv = ov; li = oi; }
        }
        if (lane == 0) { wv[w] = lv; wi[w] = li; }
        __syncthreads();
        if (t == 0) {
            float Bv = wv[0]; int Bi = wi[0];
            #pragma unroll
            for (int j = 1; j < 4; ++j) {
                if (wv[j] > Bv || (wv[j] == Bv && wi[j] < Bi)) { Bv = wv[j]; Bi = wi[j]; }
            }
            mtop[bh * Uc + it] = Bi;
            vals[Bi] = -FLT_MAX;
        }
        __syncthreads();
    }
}

// ---------------------------------------------------------------------------
// Kernels 4-6: chunked inclusive cumsum of vp along l, per (bh, e) column.
// ---------------------------------------------------------------------------
constexpr int CH = 64;  // chunks
constexpr int CR = 32;  // rows per chunk

__global__ __launch_bounds__(64) void cumsum_p1(
    const float* __restrict__ vp, float* __restrict__ psum)
{
    int bid = blockIdx.x;
    int e = threadIdx.x;
    int bh = bid >> 6, ch = bid & 63;
    const float* base = vp + (size_t)bh * LEc + (ch * CR) * Ec + e;
    float s = 0.f;
    #pragma unroll 8
    for (int r = 0; r < CR; ++r) s += base[r * Ec];
    psum[(size_t)bid * Ec + e] = s;
}

__global__ __launch_bounds__(64) void cumsum_p2(float* __restrict__ psum)
{
    int bh = blockIdx.x;
    int e = threadIdx.x;
    float off = 0.f;
    for (int c = 0; c < CH; ++c) {
        size_t idx = (size_t)(bh * CH + c) * Ec + e;
        float tv = psum[idx];
        psum[idx] = off;
        off += tv;
    }
}

__global__ __launch_bounds__(64) void cumsum_p3(
    const float* __restrict__ vp, const float* __restrict__ psum,
    float* __restrict__ out)
{
    int bid = blockIdx.x;
    int e = threadIdx.x;
    int bh = bid >> 6, ch = bid & 63;
    const float* base = vp  + (size_t)bh * LEc + (ch * CR) * Ec + e;
    float*       ob   = out + (size_t)bh * LEc + (ch * CR) * Ec + e;
    float run = psum[(size_t)bid * Ec + e];
    #pragma unroll 8
    for (int r = 0; r < CR; ++r) { run += base[r * Ec]; ob[r * Ec] = run; }
}

// ---------------------------------------------------------------------------
// Kernel 7a: chunked flash attention partials with u-reuse.
// grid = (bh, chunk of 128 rows) = 32*16 blocks, 512 threads (8 waves).
// ---------------------------------------------------------------------------
constexpr int ACH = 16;     // attn chunks
constexpr int AROWS = 128;  // rows per chunk

__global__ __launch_bounds__(512) void attn_partial(
    const float* __restrict__ qp, const float* __restrict__ kp,
    const float* __restrict__ vp, const int* __restrict__ mtop,
    float* __restrict__ pm, float* __restrict__ pl, float* __restrict__ pacc)
{
    __shared__ float Kt[64][68];     // stride 68: float4-aligned rows
    __shared__ float Vt[64][68];
    __shared__ float qsh[40][64];
    __shared__ float p_lds[64][45];  // stride 45: odd -> 2-way banks on col writes
    __shared__ int   lsel_sh[40];

    int bh = blockIdx.x & 31, ch = blockIdx.x >> 5;
    int t = threadIdx.x, w = t >> 6, lane = t & 63;
    const float* kb = kp + (size_t)bh * LEc;
    const float* vb = vp + (size_t)bh * LEc;

    if (t < Uc) lsel_sh[t] = mtop[bh * Uc + t];
    __syncthreads();
    for (int i = t; i < Uc * Ec; i += 512) {
        int u = i >> 6, e = i & 63;
        qsh[u][e] = qp[(size_t)bh * LEc + lsel_sh[u] * Ec + e];
    }

    const int u0 = w * 5;
    float acc[5]  = {0.f, 0.f, 0.f, 0.f, 0.f};
    float lreg[5] = {0.f, 0.f, 0.f, 0.f, 0.f};
    float mreg[5];
    #pragma unroll
    for (int j = 0; j < 5; ++j) mreg[j] = -FLT_MAX;

    for (int tt = 0; tt < AROWS / 64; ++tt) {
        int l0 = ch * AROWS + tt * 64;
        __syncthreads();   // prev-tile reads done (and qsh written, first iter)
        #pragma unroll
        for (int i = 0; i < 2; ++i) {
            int f = i * 512 + t, row = f >> 4, cg = f & 15;
            *(float4*)&Kt[row][cg * 4] = *(const float4*)(kb + (size_t)(l0 + row) * Ec + cg * 4);
            *(float4*)&Vt[row][cg * 4] = *(const float4*)(vb + (size_t)(l0 + row) * Ec + cg * 4);
        }
        __syncthreads();

        int gl = l0 + lane;
        float4 kr[16];
        #pragma unroll
        for (int i = 0; i < 16; ++i) kr[i] = *(const float4*)&Kt[lane][i * 4];

        bool act[5];
        #pragma unroll
        for (int j = 0; j < 5; ++j) {
            int u = u0 + j, ls = lsel_sh[u];
            act[j] = (l0 <= ls);            // wave-uniform
            if (!act[j]) continue;
            float s = -FLT_MAX;
            if (gl <= ls) {
                float dot = 0.f;
                #pragma unroll
                for (int i = 0; i < 16; ++i) {
                    float4 qv = *(const float4*)&qsh[u][i * 4];   // broadcast
                    dot += kr[i].x * qv.x + kr[i].y * qv.y + kr[i].z * qv.z + kr[i].w * qv.w;
                }
                s = dot * 0.125f;   // 1/sqrt(64)
            }
            float tmax = s;
            #pragma unroll
            for (int o = 1; o < 64; o <<= 1) tmax = fmaxf(tmax, __shfl_xor(tmax, o));
            float m_new = fmaxf(mreg[j], tmax);
            float p = (gl <= ls) ? __expf(s - m_new) : 0.f;
            p_lds[lane][u] = p;
            float ps = p;
            #pragma unroll
            for (int o = 1; o < 64; o <<= 1) ps += __shfl_xor(ps, o);
            float coef = __expf(mreg[j] - m_new);   // exp(0)=1 when unchanged
            lreg[j] = lreg[j] * coef + ps;
            acc[j] *= coef;
            mreg[j] = m_new;
        }

        // PV: lane = e.
        for (int row = 0; row < 64; ++row) {
            float vv = Vt[row][lane];
            #pragma unroll
            for (int j = 0; j < 5; ++j)
                if (act[j]) acc[j] = fmaf(p_lds[row][u0 + j], vv, acc[j]);
        }
    }

    #pragma unroll
    for (int j = 0; j < 5; ++j) {
        size_t idx = ((size_t)bh * ACH + ch) * Uc + u0 + j;
        if (lane == 0) { pm[idx] = mreg[j]; pl[idx] = lreg[j]; }
        pacc[idx * Ec + lane] = acc[j];
    }
}

// ---------------------------------------------------------------------------
// Kernel 7b: combine the 16 chunk-partials per (bh, u); write out row.
// ---------------------------------------------------------------------------
__global__ __launch_bounds__(256) void attn_combine(
    const float* __restrict__ pm, const float* __restrict__ pl,
    const float* __restrict__ pacc, const int* __restrict__ mtop,
    float* __restrict__ out)
{
    int wid = blockIdx.x * 4 + (threadIdx.x >> 6);
    int lane = threadIdx.x & 63;
    int bh = wid / Uc, u = wid % Uc;
    float m = -FLT_MAX;
    for (int i = 0; i < ACH; ++i)
        m = fmaxf(m, pm[((size_t)bh * ACH + i) * Uc + u]);
    float l = 0.f, a = 0.f;
    for (int i = 0; i < ACH; ++i) {
        size_t idx = ((size_t)bh * ACH + i) * Uc + u;
        float wgt = __expf(pm[idx] - m);   // exp(-inf)=0 for empty chunks
        l += wgt * pl[idx];
        a += wgt * pacc[idx * Ec + lane];
    }
    int lsel = mtop[bh * Uc + u];
    out[(size_t)bh * LEc + lsel * Ec + lane] = a / l;
}

// ---------------------------------------------------------------------------
extern "C" void kernel_launch(void* const* d_in, const int* in_sizes, int n_in,
                              void* d_out, int out_size, void* d_ws, size_t ws_size,
                              hipStream_t stream)
{
    const float* q   = (const float*)d_in[0];
    const float* k   = (const float*)d_in[1];
    const float* v   = (const float*)d_in[2];
    const float* Wq  = (const float*)d_in[3];
    const float* Wk  = (const float*)d_in[4];
    const float* Wv  = (const float*)d_in[5];
    const int*   ksi = (const int*)d_in[6];
    float* out = (float*)d_out;

    // workspace layout
    float* wsf  = (float*)d_ws;
    float* qp   = wsf;                            // 4,194,304 f
    float* kp   = qp + (size_t)Mrows * Dc;        // 4,194,304 f
    float* vp   = kp + (size_t)Mrows * Dc;        // 4,194,304 f
    float* psum = vp + (size_t)Mrows * Dc;        // 131,072 f
    float* m_ws = psum + (size_t)BHc * CH * Ec;   // 65,536 f
    int*   mtop = (int*)(m_ws + (size_t)BHc * Lc);      // 1,280 i
    short* qhi = (short*)(mtop + BHc * Uc);
    short* qlo = qhi + (size_t)Mrows * Dc;
    short* khi = qlo + (size_t)Mrows * Dc;
    short* klo = khi + (size_t)Mrows * Dc;
    short* vhi = klo + (size_t)Mrows * Dc;
    short* Bq  = vhi + (size_t)Mrows * Dc;        // 512*1536
    short* Bk  = Bq + (size_t)Dc * 1536;          // 512*1536
    short* Bv  = Bk + (size_t)Dc * 1536;          // 512*512
    float* pm  = (float*)(Bv + (size_t)Dc * 512); // 32*16*40
    float* pl  = pm + (size_t)BHc * ACH * Uc;     // 32*16*40
    float* pacc = pl + (size_t)BHc * ACH * Uc;    // 32*16*40*64

    split_inputs<<<3 * (Mrows * Dc / 8) / 256, 256, 0, stream>>>(
        q, k, v, qhi, qlo, khi, klo, vhi);
    wprep<<<dim3(8, 8, 3), 256, 0, stream>>>(Wq, Wk, Wv, Bq, Bk, Bv);

    dim3 g1(Mrows / 128, Dc / 128, 3);
    gemm_mfma<<<g1, 256, 0, stream>>>(qhi, qlo, khi, klo, vhi, Bq, Bk, Bv,
                                      qp, kp, vp);

    compute_m<<<(BHc * Lc) / 4, 256, 0, stream>>>(qp, kp, ksi, m_ws);

    topk40<<<BHc, 256, 0, stream>>>(m_ws, mtop);

    attn_partial<<<BHc * ACH, 512, 0, stream>>>(qp, kp, vp, mtop, pm, pl, pacc);

    cumsum_p1<<<BHc * CH, 64, 0, stream>>>(vp, psum);
    cumsum_p2<<<BHc, 64, 0, stream>>>(psum);
    cumsum_p3<<<BHc * CH, 64, 0, stream>>>(vp, psum, out);

    attn_combine<<<BHc * Uc / 4, 256, 0, stream>>>(pm, pl, pacc, mtop, out);
}